// Round 1
// baseline (1465.726 us; speedup 1.0000x reference)
//
#include <hip/hip_runtime.h>
#include <hip/hip_bf16.h>

// VisualDecoder: B=8,N=4096,D=768,H=12,M=64,L=4,HD=64. In/out f32; compute bf16
// MFMA (f32 accum). R7: 3-slot LDS pipeline with counted vmcnt (loads stay in
// flight across barriers -- T3/T4), raw s_barrier, XCD-chunked block swizzle
// (T1, bijective m204 form) in both GEMMs; 3 blocks/CU for gemm_big.

using bf16 = __hip_bfloat16;
typedef __attribute__((ext_vector_type(8))) __bf16 bf16x8;
typedef __attribute__((ext_vector_type(4))) float f32x4;
typedef unsigned int u32;
typedef __attribute__((ext_vector_type(4))) u32 u32x4;

#define DEVINL __device__ __forceinline__

DEVINL float bf2f(bf16 v) { return __bfloat162float(v); }
DEVINL bf16 f2bf(float v) { return __float2bfloat16(v); }
DEVINL u32 f2bfu(float f) { bf16 h = __float2bfloat16(f); return *(unsigned short*)&h; }
DEVINL float gelu_f(float x) { return 0.5f * x * (1.0f + erff(x * 0.70710678118654752f)); }

// async global->LDS, 16B per lane. LDS dest = wave-uniform base + lane*16 (ours is).
DEVINL void async16(const bf16* g, bf16* l) {
  __builtin_amdgcn_global_load_lds(
      (const __attribute__((address_space(1))) u32*)g,
      (__attribute__((address_space(3))) u32*)l, 16, 0, 0);
}

// XCD-chunked bijective block-id swizzle (m204): dispatch round-robins id%8
// across XCDs; give each XCD a CONTIGUOUS chunk of tiles for L2 panel reuse.
DEVINL u32 xcd_swizzle(u32 id, u32 nwg) {
  u32 q = nwg >> 3, r = nwg & 7;
  u32 xcd = id & 7, pos = id >> 3;
  return xcd * q + (xcd < r ? xcd : r) + pos;
}

// ---------------------------------------------------------------- flat f32 -> bf16
__global__ __launch_bounds__(256) void cvt_f2b(const float* in, bf16* out, long n) {
  const long i = ((long)blockIdx.x * 256 + threadIdx.x) * 8;
  if (i >= n) return;
  float4 a = *(const float4*)(in + i);
  float4 b = *(const float4*)(in + i + 4);
  u32 w[4];
  w[0] = f2bfu(a.x) | (f2bfu(a.y) << 16);
  w[1] = f2bfu(a.z) | (f2bfu(a.w) << 16);
  w[2] = f2bfu(b.x) | (f2bfu(b.y) << 16);
  w[3] = f2bfu(b.z) | (f2bfu(b.w) << 16);
  *(u32x4*)(out + i) = *(u32x4*)w;
}

// ---------------------------------------------------------------- big GEMM
// 128x128 tile, BK=32, 256 thr = 4 waves (2x2 of 64x64). 3-slot LDS pipeline:
// 2 tiles in flight; per-iter wait vmcnt(4) = oldest tile done, raw s_barrier
// (no vmcnt(0) drain -- loads span barriers). Issue tile k+2 right after the
// barrier so its latency hides under MFMA of tile k and k+1.
struct GemmBigP {
  const bf16* A; const bf16* B; bf16* C; const float* bias;
  long sA, sB, sC;
  int lda, ldb, ldc, K;
  int bias_mode; // 0 none, 1 per-col, 2 per-row
};

__global__ __launch_bounds__(256, 3) void gemm_big(GemmBigP p) {
  __shared__ __align__(16) bf16 As[3][128 * 32];
  __shared__ __align__(16) bf16 Bs[3][128 * 32];
  const int tid = threadIdx.x;
  const int wave = tid >> 6, lane = tid & 63;

  const u32 gx = gridDim.x, gy = gridDim.y;
  u32 id = blockIdx.x + gx * (blockIdx.y + gy * blockIdx.z);
  id = xcd_swizzle(id, gx * gy * gridDim.z);
  const int bn = id % gx;
  const u32 t2 = id / gx;
  const int bm = t2 % gy;
  const int bz = t2 / gy;

  const bf16* Ag = p.A + (long)bz * p.sA + (long)bm * 128 * p.lda;
  const bf16* Bg = p.B + (long)bz * p.sB + (long)bn * 128 * p.ldb;

  // 512 16B chunks per matrix; thread stages chunks {tid, tid+256}.
  // chunk c -> LDS byte c*16 (row-major [128][32]); global row c>>2, k (c&3)*8.
  const bf16* ga0 = Ag + ((long)(tid >> 2) * p.lda + (tid & 3) * 8);
  const bf16* ga1 = Ag + ((long)((tid >> 2) + 64) * p.lda + (tid & 3) * 8);
  const bf16* gb0 = Bg + ((long)(tid >> 2) * p.ldb + (tid & 3) * 8);
  const bf16* gb1 = Bg + ((long)((tid >> 2) + 64) * p.ldb + (tid & 3) * 8);

  const int m_in = lane & 15, q = lane >> 4;
  const int wm = (wave & 1) * 64, wn = (wave >> 1) * 64;
  f32x4 acc[4][4] = {};
  const int nk = p.K >> 5;

  // prologue: tiles 0,1 -> slots 0,1 (4 loads each per thread)
  async16(ga0, &As[0][0] + tid * 8);
  async16(ga1, &As[0][0] + 2048 + tid * 8);
  async16(gb0, &Bs[0][0] + tid * 8);
  async16(gb1, &Bs[0][0] + 2048 + tid * 8);
  if (nk > 1) {
    async16(ga0 + 32, &As[1][0] + tid * 8);
    async16(ga1 + 32, &As[1][0] + 2048 + tid * 8);
    async16(gb0 + 32, &Bs[1][0] + tid * 8);
    async16(gb1 + 32, &Bs[1][0] + 2048 + tid * 8);
  }

  int slot = 0;
  for (int k = 0; k < nk; ++k) {
    // oldest in-flight tile (k) complete; never drain to 0 mid-loop (T4)
    if (k + 1 < nk) asm volatile("s_waitcnt vmcnt(4)" ::: "memory");
    else            asm volatile("s_waitcnt vmcnt(0)" ::: "memory");
    __builtin_amdgcn_s_barrier();
    if (k + 2 < nk) {  // issue tile k+2 into slot (k+2)%3; in flight 2 iters
      int ns = slot + 2; if (ns >= 3) ns -= 3;
      const int ko = (k + 2) * 32;
      async16(ga0 + ko, &As[ns][0] + tid * 8);
      async16(ga1 + ko, &As[ns][0] + 2048 + tid * 8);
      async16(gb0 + ko, &Bs[ns][0] + tid * 8);
      async16(gb1 + ko, &Bs[ns][0] + 2048 + tid * 8);
    }
    const bf16* Ac = &As[slot][0];
    const bf16* Bc = &Bs[slot][0];
    bf16x8 af[4], bv[4];
#pragma unroll
    for (int i = 0; i < 4; i++)
      af[i] = *(const bf16x8*)(Ac + (wm + i * 16 + m_in) * 32 + q * 8);
#pragma unroll
    for (int j = 0; j < 4; j++)
      bv[j] = *(const bf16x8*)(Bc + (wn + j * 16 + m_in) * 32 + q * 8);
#pragma unroll
    for (int i = 0; i < 4; i++)
#pragma unroll
      for (int j = 0; j < 4; j++)
        acc[i][j] = __builtin_amdgcn_mfma_f32_16x16x32_bf16(af[i], bv[j], acc[i][j], 0, 0, 0);
    slot = (slot + 1 == 3) ? 0 : slot + 1;
  }

  bf16* Cg = p.C + (long)bz * p.sC;
  const long row0 = (long)bm * 128 + wm + q * 4;
  const long col0 = (long)bn * 128 + wn + m_in;
#pragma unroll
  for (int i = 0; i < 4; i++)
#pragma unroll
    for (int j = 0; j < 4; j++) {
      long r = row0 + i * 16;
      long c = col0 + j * 16;
      float badd = (p.bias_mode == 1) ? p.bias[c] : 0.f;
#pragma unroll
      for (int t = 0; t < 4; t++) {
        float v = acc[i][j][t] + badd;
        if (p.bias_mode == 2) v += p.bias[r + t];
        Cg[(r + t) * p.ldc + c] = f2bf(v);
      }
    }
}

// ---------------------------------------------------------------- small GEMM
// 64x64 tile, BK=32, 3-slot counted-vmcnt pipeline, 2-level batch, XCD swizzle.
struct GemmSmP {
  const bf16* A; const bf16* B; void* C; const float* bias; const float* res;
  long sA1, sA2, sB1, sB2, sC1, sC2, sBias2;
  int nb2, lda, ldb, ldc, K;
  int bias_mode;  // 0 none, 1 per-col
  int out_mode;   // 0 f32 (+res), 1 bf16, 2 gelu->bf16
  float scale;
};

__global__ __launch_bounds__(256, 4) void gemm_sm(GemmSmP p) {
  __shared__ __align__(16) bf16 As[3][64 * 32];
  __shared__ __align__(16) bf16 Bs[3][64 * 32];
  const int tid = threadIdx.x;
  const int wave = tid >> 6, lane = tid & 63;

  const u32 gx = gridDim.x, gy = gridDim.y;
  u32 id = blockIdx.x + gx * (blockIdx.y + gy * blockIdx.z);
  id = xcd_swizzle(id, gx * gy * gridDim.z);
  const int bn = id % gx;
  const u32 t2 = id / gx;
  const int bm = t2 % gy;
  const int bz = t2 / gy;

  const int z1 = bz / p.nb2, z2 = bz - z1 * p.nb2;
  const bf16* Ag = p.A + p.sA1 * z1 + p.sA2 * z2 + (long)bm * 64 * p.lda;
  const bf16* Bg = p.B + p.sB1 * z1 + p.sB2 * z2 + (long)bn * 64 * p.ldb;

  const bf16* gpa = Ag + ((long)(tid >> 2) * p.lda + (tid & 3) * 8);
  const bf16* gpb = Bg + ((long)(tid >> 2) * p.ldb + (tid & 3) * 8);

  const int m_in = lane & 15, q = lane >> 4;
  const int wm = (wave & 1) * 32, wn = (wave >> 1) * 32;
  f32x4 acc[2][2] = {};
  const int nk = p.K >> 5;

  async16(gpa, &As[0][0] + tid * 8);
  async16(gpb, &Bs[0][0] + tid * 8);
  if (nk > 1) {
    async16(gpa + 32, &As[1][0] + tid * 8);
    async16(gpb + 32, &Bs[1][0] + tid * 8);
  }

  int slot = 0;
  for (int k = 0; k < nk; ++k) {
    if (k + 1 < nk) asm volatile("s_waitcnt vmcnt(2)" ::: "memory");
    else            asm volatile("s_waitcnt vmcnt(0)" ::: "memory");
    __builtin_amdgcn_s_barrier();
    if (k + 2 < nk) {
      int ns = slot + 2; if (ns >= 3) ns -= 3;
      const int ko = (k + 2) * 32;
      async16(gpa + ko, &As[ns][0] + tid * 8);
      async16(gpb + ko, &Bs[ns][0] + tid * 8);
    }
    const bf16* Ac = &As[slot][0];
    const bf16* Bc = &Bs[slot][0];
    bf16x8 a0 = *(const bf16x8*)(Ac + (wm + m_in) * 32 + q * 8);
    bf16x8 a1 = *(const bf16x8*)(Ac + (wm + 16 + m_in) * 32 + q * 8);
    bf16x8 b0 = *(const bf16x8*)(Bc + (wn + m_in) * 32 + q * 8);
    bf16x8 b1 = *(const bf16x8*)(Bc + (wn + 16 + m_in) * 32 + q * 8);
    acc[0][0] = __builtin_amdgcn_mfma_f32_16x16x32_bf16(a0, b0, acc[0][0], 0, 0, 0);
    acc[0][1] = __builtin_amdgcn_mfma_f32_16x16x32_bf16(a0, b1, acc[0][1], 0, 0, 0);
    acc[1][0] = __builtin_amdgcn_mfma_f32_16x16x32_bf16(a1, b0, acc[1][0], 0, 0, 0);
    acc[1][1] = __builtin_amdgcn_mfma_f32_16x16x32_bf16(a1, b1, acc[1][1], 0, 0, 0);
    slot = (slot + 1 == 3) ? 0 : slot + 1;
  }

  const long row0 = (long)bm * 64 + wm + q * 4;
  const long col0 = (long)bn * 64 + wn + m_in;
  const float* bias = p.bias + p.sBias2 * z2;
#pragma unroll
  for (int i = 0; i < 2; i++)
#pragma unroll
    for (int j = 0; j < 2; j++) {
      long r = row0 + i * 16;
      long cc = col0 + j * 16;
      float badd = (p.bias_mode == 1) ? bias[cc] : 0.f;
#pragma unroll
      for (int t = 0; t < 4; t++) {
        float v = acc[i][j][t] * p.scale + badd;
        long idx = (r + t) * p.ldc + cc;
        if (p.out_mode == 0) {
          float* Cf = (float*)p.C + p.sC1 * z1 + p.sC2 * z2;
          if (p.res) v += p.res[idx];
          Cf[idx] = v;
        } else {
          bf16* Cb = (bf16*)p.C + p.sC1 * z1 + p.sC2 * z2;
          if (p.out_mode == 2) v = gelu_f(v);
          Cb[idx] = f2bf(v);
        }
      }
    }
}

// ---------------------------------------------------------------- transpose (f32 -> bf16)
struct TrP { const float* in; bf16* out; bf16* outR; int R, C; long sIn, sOut, sOutR; };

__global__ __launch_bounds__(256) void transpose_f2b(TrP p) {
  __shared__ __align__(16) bf16 tile[64][80];
  const int tid = threadIdx.x;
  const int ct = blockIdx.x, rt = blockIdx.y, z = blockIdx.z;
  const float* in = p.in + p.sIn * z + ((long)rt * 64) * p.C + (long)ct * 64;
  bf16* out = p.out + p.sOut * z + ((long)ct * 64) * p.R + (long)rt * 64;
  bf16* outR = p.outR ? p.outR + p.sOutR * z + ((long)rt * 64) * p.C + (long)ct * 64 : nullptr;
  const int r = tid >> 3, c8 = (tid & 7) * 8;
#pragma unroll
  for (int h = 0; h < 2; h++) {
    int rr = r + h * 32;
    float4 a = *(const float4*)(in + (long)rr * p.C + c8);
    float4 b = *(const float4*)(in + (long)rr * p.C + c8 + 4);
    u32 w[4];
    w[0] = f2bfu(a.x) | (f2bfu(a.y) << 16);
    w[1] = f2bfu(a.z) | (f2bfu(a.w) << 16);
    w[2] = f2bfu(b.x) | (f2bfu(b.y) << 16);
    w[3] = f2bfu(b.z) | (f2bfu(b.w) << 16);
    *(u32x4*)&tile[rr][c8] = *(u32x4*)w;
    if (outR) *(u32x4*)(outR + (long)rr * p.C + c8) = *(u32x4*)w;
  }
  __syncthreads();
  const int co = tid >> 3, r8 = (tid & 7) * 8;
#pragma unroll
  for (int h = 0; h < 2; h++) {
    int cc = co + h * 32;
    __align__(16) bf16 tmp[8];
#pragma unroll
    for (int j = 0; j < 8; j++) tmp[j] = tile[r8 + j][cc];
    *(u32x4*)(out + (long)cc * p.R + r8) = *(const u32x4*)tmp;
  }
}

// ---------------------------------------------------------------- softmax (rows of 4096, in-place bf16)
__global__ __launch_bounds__(256) void softmax_rows(bf16* X) {
  const long row = blockIdx.x;
  u32* x = (u32*)(X + row * 4096);
  const int tid = threadIdx.x;
  const int lane = tid & 63, wave = tid >> 6;
  u32 d[8];
  *(u32x4*)&d[0] = ((const u32x4*)x)[tid * 2];
  *(u32x4*)&d[4] = ((const u32x4*)x)[tid * 2 + 1];
  float v[16];
#pragma unroll
  for (int j = 0; j < 8; j++) {
    v[2 * j] = __uint_as_float(d[j] << 16);
    v[2 * j + 1] = __uint_as_float(d[j] & 0xffff0000u);
  }
  float m = v[0];
#pragma unroll
  for (int i = 1; i < 16; i++) m = fmaxf(m, v[i]);
  for (int off = 32; off; off >>= 1) m = fmaxf(m, __shfl_xor(m, off));
  __shared__ float sm1[4], sm2[4];
  if (lane == 0) sm1[wave] = m;
  __syncthreads();
  m = fmaxf(fmaxf(sm1[0], sm1[1]), fmaxf(sm1[2], sm1[3]));
  float s = 0.f;
#pragma unroll
  for (int i = 0; i < 16; i++) { v[i] = __expf(v[i] - m); s += v[i]; }
  for (int off = 32; off; off >>= 1) s += __shfl_xor(s, off);
  if (lane == 0) sm2[wave] = s;
  __syncthreads();
  s = sm2[0] + sm2[1] + sm2[2] + sm2[3];
  const float inv = 1.f / s;
#pragma unroll
  for (int j = 0; j < 8; j++) {
    u32 lo = f2bfu(v[2 * j] * inv);
    u32 hi = f2bfu(v[2 * j + 1] * inv);
    d[j] = lo | (hi << 16);
  }
  ((u32x4*)x)[tid * 2] = *(u32x4*)&d[0];
  ((u32x4*)x)[tid * 2 + 1] = *(u32x4*)&d[4];
}

// ---------------------------------------------------------------- layernorm (rows of 768)
// outputs: outf (f32), and/or outb (bf16), and/or queries = ln + qc (qf f32 + qb16).
__global__ __launch_bounds__(256) void ln_rows(const float* in, const float* g, const float* b,
                                               float* outf, bf16* outb,
                                               const float* qc, float* qf, bf16* qb16) {
  const long row = blockIdx.x;
  const float* x = in + row * 768;
  const int tid = threadIdx.x;
  const int lane = tid & 63, wave = tid >> 6;
  float v0 = x[tid], v1 = x[tid + 256], v2 = x[tid + 512];
  float s = v0 + v1 + v2;
  float s2 = v0 * v0 + v1 * v1 + v2 * v2;
  for (int off = 32; off; off >>= 1) { s += __shfl_xor(s, off); s2 += __shfl_xor(s2, off); }
  __shared__ float sa[4], sb[4];
  if (lane == 0) { sa[wave] = s; sb[wave] = s2; }
  __syncthreads();
  s = sa[0] + sa[1] + sa[2] + sa[3];
  s2 = sb[0] + sb[1] + sb[2] + sb[3];
  const float mean = s * (1.f / 768.f);
  const float var = s2 * (1.f / 768.f) - mean * mean;
  const float rs = rsqrtf(var + 1e-5f);
  float o0 = (v0 - mean) * rs * g[tid] + b[tid];
  float o1 = (v1 - mean) * rs * g[tid + 256] + b[tid + 256];
  float o2 = (v2 - mean) * rs * g[tid + 512] + b[tid + 512];
  if (outf) { float* of = outf + row * 768; of[tid] = o0; of[tid + 256] = o1; of[tid + 512] = o2; }
  if (outb) { bf16* ob = outb + row * 768; ob[tid] = f2bf(o0); ob[tid + 256] = f2bf(o1); ob[tid + 512] = f2bf(o2); }
  if (qc) {
    const float* qr = qc + (row & 63) * 768;
    float u0 = o0 + qr[tid], u1 = o1 + qr[tid + 256], u2 = o2 + qr[tid + 512];
    float* pf = qf + row * 768;
    pf[tid] = u0; pf[tid + 256] = u1; pf[tid + 512] = u2;
    bf16* pb = qb16 + row * 768;
    pb[tid] = f2bf(u0); pb[tid + 256] = f2bf(u1); pb[tid + 512] = f2bf(u2);
  }
}

// ---------------------------------------------------------------- combine split-K partials
// s = sum_{c<nch} in[c*393216+i] (+bias[i%768]) (+res[i]); outputs nullable.
struct CombP { const float* in; int nch; const float* bias; const float* res;
               float* outf; bf16* outb; const float* qc; float* qf; bf16* qb16; };

__global__ __launch_bounds__(256) void combine(CombP p) {
  const long i = (long)blockIdx.x * 256 + threadIdx.x;  // n = 393216
  float s = 0.f;
  for (int c = 0; c < p.nch; c++) s += p.in[(long)c * 393216 + i];
  if (p.bias) s += p.bias[i % 768];
  if (p.res) s += p.res[i];
  if (p.outf) p.outf[i] = s;
  if (p.outb) p.outb[i] = f2bf(s);
  if (p.qc) {
    float v = s + p.qc[i % 49152];
    p.qf[i] = v;
    p.qb16[i] = f2bf(v);
  }
}

// ================================================================ launcher
extern "C" void kernel_launch(void* const* d_in, const int* in_sizes, int n_in,
                              void* d_out, int out_size, void* d_ws, size_t ws_size,
                              hipStream_t stream) {
  (void)in_sizes; (void)n_in; (void)out_size; (void)ws_size;
  const float* tokens   = (const float*)d_in[0];
  const float* selector = (const float*)d_in[1];
  const float* qc  = (const float*)d_in[2];
  const float* qw  = (const float*)d_in[3];
  const float* qb  = (const float*)d_in[4];
  const float* kw  = (const float*)d_in[5];
  const float* kb  = (const float*)d_in[6];
  const float* vw  = (const float*)d_in[7];
  const float* vb  = (const float*)d_in[8];
  const float* hw  = (const float*)d_in[9];
  const float* hb  = (const float*)d_in[10];
  const float* ow  = (const float*)d_in[11];
  const float* ob  = (const float*)d_in[12];
  const float* w1  = (const float*)d_in[13];
  const float* b1  = (const float*)d_in[14];
  const float* w2  = (const float*)d_in[15];
  const float* b2  = (const float*)d_in[16];
  const float* g1  = (const float*)d_in[17];
  const float* be1 = (const float*)d_in[18];
  const float* g2  = (const float*)d_in[19];
  const float* be2 = (const float*)d_in[20];
  float* out = (float*)d_out;

  char* ws = (char*)d_ws;
  size_t off = 0;
  auto alloc = [&](size_t bytes) { char* pp = ws + off; off += (bytes + 255) & ~(size_t)255; return pp; };
  bf16* TOKT  = (bf16*)alloc(50331648);   // tokens^T [B,D,N]; later attention P
  bf16* PBUF  = TOKT;
  bf16* TOKB  = (bf16*)alloc(50331648);   // tokens bf16 [B,N,D]
  bf16* KBUF  = (bf16*)alloc(50331648);   // k [B,N,H,HD]
  bf16* VTB   = (bf16*)alloc(50331648);   // v^T [B,768,N]
  bf16* PLOG  = (bf16*)alloc(4194304);    // pooling logits [B,M,N]
  bf16* SELB  = (bf16*)alloc(98304);      // selector bf16 [M,D]
  bf16* QWT   = (bf16*)alloc(4718592);    // [L,H,HD,D]
  bf16* KWT   = (bf16*)alloc(4718592);
  bf16* VWT   = (bf16*)alloc(4718592);
  bf16* HWT   = (bf16*)alloc(393216);     // [L,H,HD,HD]
  bf16* OWT   = (bf16*)alloc(4718592);    // [L,D,D]
  bf16* W1T   = (bf16*)alloc(18874368);   // [L,3072,768]
  bf16* W2T   = (bf16*)alloc(18874368);   // [L,768,3072]
  bf16* QBUF  = (bf16*)alloc(786432);     // q [B,M,H,HD]
  bf16* OBUF  = (bf16*)alloc(786432);     // attn out [B,H,M,HD]
  bf16* O2BUF = (bf16*)alloc(786432);     // head-mixed concat [B*M,768]
  float* QF   = (float*)alloc(1572864);   // queries f32
  bf16* QB16  = (bf16*)alloc(786432);     // queries bf16
  float* T1   = (float*)alloc(1572864);
  float* X1F  = (float*)alloc(1572864);
  bf16* X1B   = (bf16*)alloc(786432);
  bf16* H1    = (bf16*)alloc(3145728);    // gelu(mlp1) [512,3072]
  float* T2   = (float*)alloc(1572864);
  float* OPART = (float*)alloc(12582912); // split-K partials [<=8][393216]

  auto tr = [&](const float* in, bf16* o, bf16* oR, int R, int C, long s, long sR, int slabs) {
    TrP t{in, o, oR, R, C, s, s, sR};
    transpose_f2b<<<dim3(C / 64, R / 64, slabs), 256, 0, stream>>>(t);
  };
  tr(tokens, TOKT, TOKB, 4096, 768, 3145728, 3145728, 8);
  cvt_f2b<<<24, 256, 0, stream>>>(selector, SELB, 49152);
  tr(qw, QWT, nullptr, 768, 64, 49152, 0, 48);
  tr(kw, KWT, nullptr, 768, 64, 49152, 0, 48);
  tr(vw, VWT, nullptr, 768, 64, 49152, 0, 48);
  tr(hw, HWT, nullptr, 64, 64, 4096, 0, 48);
  tr(ow, OWT, nullptr, 768, 768, 589824, 0, 4);
  tr(w1, W1T, nullptr, 768, 3072, 2359296, 0, 4);
  tr(w2, W2T, nullptr, 3072, 768, 2359296, 0, 4);

  // ---- pooling
  {
    GemmSmP p{}; p.A = SELB; p.B = TOKB; p.C = PLOG;
    p.sB1 = 3145728; p.sC1 = 262144; p.nb2 = 1;
    p.lda = 768; p.ldb = 768; p.ldc = 4096; p.K = 768;
    p.bias_mode = 0; p.out_mode = 1; p.scale = 1.0f;
    gemm_sm<<<dim3(64, 1, 8), 256, 0, stream>>>(p);
  }
  softmax_rows<<<512, 256, 0, stream>>>(PLOG);
  { // x partials = P · tokens (split-K 8 over N)
    GemmSmP p{}; p.A = PLOG; p.B = TOKT; p.C = OPART;
    p.sA1 = 512; p.sA2 = 262144; p.sB1 = 512; p.sB2 = 3145728;
    p.sC1 = 393216; p.sC2 = 49152; p.nb2 = 8;
    p.lda = 4096; p.ldb = 4096; p.ldc = 768; p.K = 512;
    p.bias_mode = 0; p.out_mode = 0; p.scale = 1.0f;
    gemm_sm<<<dim3(12, 1, 64), 256, 0, stream>>>(p);
  }
  { // x -> queries(l=0) = x + qc[0]
    CombP c{}; c.in = OPART; c.nch = 8; c.qc = qc; c.qf = QF; c.qb16 = QB16;
    combine<<<1536, 256, 0, stream>>>(c);
  }

  for (int l = 0; l < 4; l++) {
    { // q = queries · qw^T + qb  -> [B,M,H,HD] bf16
      GemmSmP p{}; p.A = QB16; p.B = QWT + l * 589824; p.C = QBUF; p.bias = qb + l * 768;
      p.nb2 = 1; p.lda = 768; p.ldb = 768; p.ldc = 768; p.K = 768;
      p.bias_mode = 1; p.out_mode = 1; p.scale = 1.0f;
      gemm_sm<<<dim3(12, 8, 1), 256, 0, stream>>>(p);
    }
    { // k = tokens · kw^T + kb -> KBUF [B*N,768]
      GemmBigP p{}; p.A = TOKB; p.B = KWT + l * 589824; p.C = KBUF; p.bias = kb + l * 768;
      p.sA = 0; p.sB = 0; p.sC = 0; p.lda = 768; p.ldb = 768; p.ldc = 768; p.K = 768; p.bias_mode = 1;
      gemm_big<<<dim3(6, 256, 1), 256, 0, stream>>>(p);
    }
    { // v^T = vw^T · tokens^T + vb(row) -> VTB [B,768,N]
      GemmBigP p{}; p.A = VWT + l * 589824; p.B = TOKB; p.C = VTB; p.bias = vb + l * 768;
      p.sA = 0; p.sB = 3145728; p.sC = 3145728; p.lda = 768; p.ldb = 768; p.ldc = 4096; p.K = 768; p.bias_mode = 2;
      gemm_big<<<dim3(32, 6, 8), 256, 0, stream>>>(p);
    }
    { // S = (q·k^T)*scale -> PBUF bf16 [B,H,M,N]   (z = b*12+h)
      GemmSmP p{}; p.A = QBUF; p.B = KBUF; p.C = PBUF;
      p.sA1 = 49152; p.sA2 = 64; p.sB1 = 3145728; p.sB2 = 64; p.sC1 = 3145728; p.sC2 = 262144;
      p.nb2 = 12; p.lda = 768; p.ldb = 768; p.ldc = 4096; p.K = 64;
      p.bias_mode = 0; p.out_mode = 1; p.scale = 0.125f;
      gemm_sm<<<dim3(64, 1, 96), 256, 0, stream>>>(p);
    }
    softmax_rows<<<6144, 256, 0, stream>>>(PBUF);
    { // o partials = P · v (split-K 8)   z = chunk*96 + (b*12+h)
      GemmSmP p{}; p.A = PBUF; p.B = VTB; p.C = OPART;
      p.sA1 = 512; p.sA2 = 262144; p.sB1 = 512; p.sB2 = 262144; p.sC1 = 393216; p.sC2 = 4096;
      p.nb2 = 96; p.lda = 4096; p.ldb = 4096; p.ldc = 64; p.K = 512;
      p.bias_mode = 0; p.out_mode = 0; p.scale = 1.0f;
      gemm_sm<<<dim3(1, 1, 768), 256, 0, stream>>>(p);
    }
    { CombP c{}; c.in = OPART; c.nch = 8; c.outb = OBUF; combine<<<1536, 256, 0, stream>>>(c); }
    { // head-mix   z = b*12+h
      GemmSmP p{}; p.A = OBUF; p.B = HWT + l * 49152; p.C = O2BUF; p.bias = hb + l * 768;
      p.sA1 = 49152; p.sA2 = 4096; p.sB1 = 0; p.sB2 = 4096; p.sC1 = 49152; p.sC2 = 64; p.sBias2 = 64;
      p.nb2 = 12; p.lda = 64; p.ldb = 64; p.ldc = 768; p.K = 64;
      p.bias_mode = 1; p.out_mode = 1; p.scale = 1.0f;
      gemm_sm<<<dim3(1, 1, 96), 256, 0, stream>>>(p);
    }
    { // o-proj partials (split-K 4): o2 · ow^T
      GemmSmP p{}; p.A = O2BUF; p.B = OWT + l * 589824; p.C = OPART;
      p.sA1 = 192; p.sB1 = 192; p.sC1 = 393216; p.nb2 = 1;
      p.lda = 768; p.ldb = 768; p.ldc = 768; p.K = 192;
      p.bias_mode = 0; p.out_mode = 0; p.scale = 1.0f;
      gemm_sm<<<dim3(12, 8, 4), 256, 0, stream>>>(p);
    }
    { CombP c{}; c.in = OPART; c.nch = 4; c.bias = ob + l * 768; c.res = QF; c.outf = T1;
      combine<<<1536, 256, 0, stream>>>(c); }
    ln_rows<<<512, 256, 0, stream>>>(T1, g1 + l * 768, be1 + l * 768, X1F, X1B, nullptr, nullptr, nullptr);
    { // mlp1 = gelu(x1 · w1^T + b1) bf16
      GemmSmP p{}; p.A = X1B; p.B = W1T + l * 2359296; p.C = H1; p.bias = b1 + l * 3072;
      p.nb2 = 1; p.lda = 768; p.ldb = 768; p.ldc = 3072; p.K = 768;
      p.bias_mode = 1; p.out_mode = 2; p.scale = 1.0f;
      gemm_sm<<<dim3(48, 8, 1), 256, 0, stream>>>(p);
    }
    { // mlp2 partials (split-K 8): h1 · w2^T
      GemmSmP p{}; p.A = H1; p.B = W2T + l * 2359296; p.C = OPART;
      p.sA1 = 384; p.sB1 = 384; p.sC1 = 393216; p.nb2 = 1;
      p.lda = 3072; p.ldb = 3072; p.ldc = 768; p.K = 384;
      p.bias_mode = 0; p.out_mode = 0; p.scale = 1.0f;
      gemm_sm<<<dim3(12, 8, 8), 256, 0, stream>>>(p);
    }
    { CombP c{}; c.in = OPART; c.nch = 8; c.bias = b2 + l * 768; c.res = X1F; c.outf = T2;
      combine<<<1536, 256, 0, stream>>>(c); }
    // second LN: for l<3 emit queries(l+1) = ln + qc[l+1]; for l==3 emit final out (f32)
    ln_rows<<<512, 256, 0, stream>>>(T2, g2 + l * 768, be2 + l * 768,
                                     (l == 3) ? out : nullptr, nullptr,
                                     (l < 3) ? (qc + (l + 1) * 49152) : nullptr, QF, QB16);
  }
}

// Round 2
// 1397.030 us; speedup vs baseline: 1.0492x; 1.0492x over previous
//
#include <hip/hip_runtime.h>
#include <hip/hip_bf16.h>

// VisualDecoder: B=8,N=4096,D=768,H=12,M=64,L=4,HD=64. In/out f32; compute bf16
// MFMA (f32 accum). R8: fused K+V projection (gemm_kv): tokens staged once per
// tile, two weight B-tiles, two accumulators; V written transposed straight to
// VTB. 3-slot counted-vmcnt pipeline (T3/T4) + bijective XCD swizzle (T1)
// retained everywhere.

using bf16 = __hip_bfloat16;
typedef __attribute__((ext_vector_type(8))) __bf16 bf16x8;
typedef __attribute__((ext_vector_type(4))) float f32x4;
typedef unsigned int u32;
typedef __attribute__((ext_vector_type(4))) u32 u32x4;

#define DEVINL __device__ __forceinline__

DEVINL float bf2f(bf16 v) { return __bfloat162float(v); }
DEVINL bf16 f2bf(float v) { return __float2bfloat16(v); }
DEVINL u32 f2bfu(float f) { bf16 h = __float2bfloat16(f); return *(unsigned short*)&h; }
DEVINL float gelu_f(float x) { return 0.5f * x * (1.0f + erff(x * 0.70710678118654752f)); }

// async global->LDS, 16B per lane. LDS dest = wave-uniform base + lane*16 (ours is).
DEVINL void async16(const bf16* g, bf16* l) {
  __builtin_amdgcn_global_load_lds(
      (const __attribute__((address_space(1))) u32*)g,
      (__attribute__((address_space(3))) u32*)l, 16, 0, 0);
}

// XCD-chunked bijective block-id swizzle (m204): dispatch round-robins id%8
// across XCDs; give each XCD a CONTIGUOUS chunk of tiles for L2 panel reuse.
DEVINL u32 xcd_swizzle(u32 id, u32 nwg) {
  u32 q = nwg >> 3, r = nwg & 7;
  u32 xcd = id & 7, pos = id >> 3;
  return xcd * q + (xcd < r ? xcd : r) + pos;
}

// ---------------------------------------------------------------- flat f32 -> bf16
__global__ __launch_bounds__(256) void cvt_f2b(const float* in, bf16* out, long n) {
  const long i = ((long)blockIdx.x * 256 + threadIdx.x) * 8;
  if (i >= n) return;
  float4 a = *(const float4*)(in + i);
  float4 b = *(const float4*)(in + i + 4);
  u32 w[4];
  w[0] = f2bfu(a.x) | (f2bfu(a.y) << 16);
  w[1] = f2bfu(a.z) | (f2bfu(a.w) << 16);
  w[2] = f2bfu(b.x) | (f2bfu(b.y) << 16);
  w[3] = f2bfu(b.z) | (f2bfu(b.w) << 16);
  *(u32x4*)(out + i) = *(u32x4*)w;
}

// ---------------------------------------------------------------- fused K+V projection
// C_k[n,e] = sum_d tok[n,d]*KWT[e,d] + kb[e]  -> KBUF [32768,768]
// C_v[n,e] = sum_d tok[n,d]*VWT[e,d] + vb[e]  -> VTB  [8][768][4096] (transposed write)
// 128x128 tile, BK=32, 4 waves; A staged once, two B matrices. 3-slot pipeline,
// 6 async16/tile -> wait vmcnt(6) (tile k done, k+1 in flight). LDS 72KB -> 2 blk/CU.
struct GemmKVP {
  const bf16* A;      // TOKB [32768,768]
  const bf16* Bk;     // KWT layer [768,768]
  const bf16* Bv;     // VWT layer [768,768]
  bf16* Ck;           // KBUF
  bf16* Cv;           // VTB
  const float* biask; // kb[768]
  const float* biasv; // vb[768]
};

__global__ __launch_bounds__(256, 2) void gemm_kv(GemmKVP p) {
  __shared__ __align__(16) bf16 As[3][128 * 32];
  __shared__ __align__(16) bf16 Ks[3][128 * 32];
  __shared__ __align__(16) bf16 Vs[3][128 * 32];
  const int tid = threadIdx.x;
  const int wave = tid >> 6, lane = tid & 63;

  u32 id = blockIdx.x + 6u * blockIdx.y;     // grid (6, 256)
  id = xcd_swizzle(id, 1536);
  const int bn = id % 6;
  const int bm = id / 6;

  const bf16* Ag = p.A + (long)bm * 128 * 768;
  const bf16* Kg = p.Bk + (long)bn * 128 * 768;
  const bf16* Vg = p.Bv + (long)bn * 128 * 768;

  const long ro = (long)(tid >> 2) * 768 + (tid & 3) * 8;
  const long r1 = ro + (long)64 * 768;
  const bf16* ga0 = Ag + ro; const bf16* ga1 = Ag + r1;
  const bf16* gk0 = Kg + ro; const bf16* gk1 = Kg + r1;
  const bf16* gv0 = Vg + ro; const bf16* gv1 = Vg + r1;

  const int m_in = lane & 15, q = lane >> 4;
  const int wm = (wave & 1) * 64, wn = (wave >> 1) * 64;
  f32x4 acck[4][4] = {};
  f32x4 accv[4][4] = {};
  const int nk = 24;  // K=768

  auto stage = [&](int s, int ko) {
    async16(ga0 + ko, &As[s][0] + tid * 8);        // A first: HBM-latency stream
    async16(ga1 + ko, &As[s][0] + 2048 + tid * 8);
    async16(gk0 + ko, &Ks[s][0] + tid * 8);
    async16(gk1 + ko, &Ks[s][0] + 2048 + tid * 8);
    async16(gv0 + ko, &Vs[s][0] + tid * 8);
    async16(gv1 + ko, &Vs[s][0] + 2048 + tid * 8);
  };
  stage(0, 0);
  stage(1, 32);

  int slot = 0;
  for (int k = 0; k < nk; ++k) {
    if (k + 1 < nk) asm volatile("s_waitcnt vmcnt(6)" ::: "memory");
    else            asm volatile("s_waitcnt vmcnt(0)" ::: "memory");
    __builtin_amdgcn_s_barrier();
    if (k + 2 < nk) {
      int ns = slot + 2; if (ns >= 3) ns -= 3;
      stage(ns, (k + 2) * 32);
    }
    const bf16* Ac = &As[slot][0];
    const bf16* Kc = &Ks[slot][0];
    const bf16* Vc = &Vs[slot][0];
    bf16x8 af[4], bfr[4];
#pragma unroll
    for (int i = 0; i < 4; i++)
      af[i] = *(const bf16x8*)(Ac + (wm + i * 16 + m_in) * 32 + q * 8);
#pragma unroll
    for (int j = 0; j < 4; j++)
      bfr[j] = *(const bf16x8*)(Kc + (wn + j * 16 + m_in) * 32 + q * 8);
#pragma unroll
    for (int i = 0; i < 4; i++)
#pragma unroll
      for (int j = 0; j < 4; j++)
        acck[i][j] = __builtin_amdgcn_mfma_f32_16x16x32_bf16(af[i], bfr[j], acck[i][j], 0, 0, 0);
#pragma unroll
    for (int j = 0; j < 4; j++)
      bfr[j] = *(const bf16x8*)(Vc + (wn + j * 16 + m_in) * 32 + q * 8);
#pragma unroll
    for (int i = 0; i < 4; i++)
#pragma unroll
      for (int j = 0; j < 4; j++)
        accv[i][j] = __builtin_amdgcn_mfma_f32_16x16x32_bf16(af[i], bfr[j], accv[i][j], 0, 0, 0);
    slot = (slot + 1 == 3) ? 0 : slot + 1;
  }

  const long row0 = (long)bm * 128 + wm + q * 4;    // global token row n
  const long col0 = (long)bn * 128 + wn + m_in;     // e index
  const int b = (int)(row0 >> 12);                  // 128-row tile within one batch slab
  const int n0 = (int)(row0 & 4095);
  bf16* CvB = p.Cv + (long)b * 3145728;
#pragma unroll
  for (int i = 0; i < 4; i++)
#pragma unroll
    for (int j = 0; j < 4; j++) {
      long r = row0 + i * 16;
      long c = col0 + j * 16;
      float bk_ = p.biask[c];
      float bv_ = p.biasv[c];
#pragma unroll
      for (int t = 0; t < 4; t++)
        p.Ck[(r + t) * 768 + c] = f2bf(acck[i][j][t] + bk_);
      // V: t-consecutive = n-consecutive -> one 8B packed store
      u32 w0 = f2bfu(accv[i][j][0] + bv_) | (f2bfu(accv[i][j][1] + bv_) << 16);
      u32 w1 = f2bfu(accv[i][j][2] + bv_) | (f2bfu(accv[i][j][3] + bv_) << 16);
      uint2 pk; pk.x = w0; pk.y = w1;
      *(uint2*)(CvB + c * 4096 + (n0 + i * 16)) = pk;
    }
}

// ---------------------------------------------------------------- small GEMM
// 64x64 tile, BK=32, 3-slot counted-vmcnt pipeline, 2-level batch, XCD swizzle.
struct GemmSmP {
  const bf16* A; const bf16* B; void* C; const float* bias; const float* res;
  long sA1, sA2, sB1, sB2, sC1, sC2, sBias2;
  int nb2, lda, ldb, ldc, K;
  int bias_mode;  // 0 none, 1 per-col
  int out_mode;   // 0 f32 (+res), 1 bf16, 2 gelu->bf16
  float scale;
};

__global__ __launch_bounds__(256, 4) void gemm_sm(GemmSmP p) {
  __shared__ __align__(16) bf16 As[3][64 * 32];
  __shared__ __align__(16) bf16 Bs[3][64 * 32];
  const int tid = threadIdx.x;
  const int wave = tid >> 6, lane = tid & 63;

  const u32 gx = gridDim.x, gy = gridDim.y;
  u32 id = blockIdx.x + gx * (blockIdx.y + gy * blockIdx.z);
  id = xcd_swizzle(id, gx * gy * gridDim.z);
  const int bn = id % gx;
  const u32 t2 = id / gx;
  const int bm = t2 % gy;
  const int bz = t2 / gy;

  const int z1 = bz / p.nb2, z2 = bz - z1 * p.nb2;
  const bf16* Ag = p.A + p.sA1 * z1 + p.sA2 * z2 + (long)bm * 64 * p.lda;
  const bf16* Bg = p.B + p.sB1 * z1 + p.sB2 * z2 + (long)bn * 64 * p.ldb;

  const bf16* gpa = Ag + ((long)(tid >> 2) * p.lda + (tid & 3) * 8);
  const bf16* gpb = Bg + ((long)(tid >> 2) * p.ldb + (tid & 3) * 8);

  const int m_in = lane & 15, q = lane >> 4;
  const int wm = (wave & 1) * 32, wn = (wave >> 1) * 32;
  f32x4 acc[2][2] = {};
  const int nk = p.K >> 5;

  async16(gpa, &As[0][0] + tid * 8);
  async16(gpb, &Bs[0][0] + tid * 8);
  if (nk > 1) {
    async16(gpa + 32, &As[1][0] + tid * 8);
    async16(gpb + 32, &Bs[1][0] + tid * 8);
  }

  int slot = 0;
  for (int k = 0; k < nk; ++k) {
    if (k + 1 < nk) asm volatile("s_waitcnt vmcnt(2)" ::: "memory");
    else            asm volatile("s_waitcnt vmcnt(0)" ::: "memory");
    __builtin_amdgcn_s_barrier();
    if (k + 2 < nk) {
      int ns = slot + 2; if (ns >= 3) ns -= 3;
      const int ko = (k + 2) * 32;
      async16(gpa + ko, &As[ns][0] + tid * 8);
      async16(gpb + ko, &Bs[ns][0] + tid * 8);
    }
    const bf16* Ac = &As[slot][0];
    const bf16* Bc = &Bs[slot][0];
    bf16x8 a0 = *(const bf16x8*)(Ac + (wm + m_in) * 32 + q * 8);
    bf16x8 a1 = *(const bf16x8*)(Ac + (wm + 16 + m_in) * 32 + q * 8);
    bf16x8 b0 = *(const bf16x8*)(Bc + (wn + m_in) * 32 + q * 8);
    bf16x8 b1 = *(const bf16x8*)(Bc + (wn + 16 + m_in) * 32 + q * 8);
    acc[0][0] = __builtin_amdgcn_mfma_f32_16x16x32_bf16(a0, b0, acc[0][0], 0, 0, 0);
    acc[0][1] = __builtin_amdgcn_mfma_f32_16x16x32_bf16(a0, b1, acc[0][1], 0, 0, 0);
    acc[1][0] = __builtin_amdgcn_mfma_f32_16x16x32_bf16(a1, b0, acc[1][0], 0, 0, 0);
    acc[1][1] = __builtin_amdgcn_mfma_f32_16x16x32_bf16(a1, b1, acc[1][1], 0, 0, 0);
    slot = (slot + 1 == 3) ? 0 : slot + 1;
  }

  const long row0 = (long)bm * 64 + wm + q * 4;
  const long col0 = (long)bn * 64 + wn + m_in;
  const float* bias = p.bias + p.sBias2 * z2;
#pragma unroll
  for (int i = 0; i < 2; i++)
#pragma unroll
    for (int j = 0; j < 2; j++) {
      long r = row0 + i * 16;
      long cc = col0 + j * 16;
      float badd = (p.bias_mode == 1) ? bias[cc] : 0.f;
#pragma unroll
      for (int t = 0; t < 4; t++) {
        float v = acc[i][j][t] * p.scale + badd;
        long idx = (r + t) * p.ldc + cc;
        if (p.out_mode == 0) {
          float* Cf = (float*)p.C + p.sC1 * z1 + p.sC2 * z2;
          if (p.res) v += p.res[idx];
          Cf[idx] = v;
        } else {
          bf16* Cb = (bf16*)p.C + p.sC1 * z1 + p.sC2 * z2;
          if (p.out_mode == 2) v = gelu_f(v);
          Cb[idx] = f2bf(v);
        }
      }
    }
}

// ---------------------------------------------------------------- transpose (f32 -> bf16)
struct TrP { const float* in; bf16* out; bf16* outR; int R, C; long sIn, sOut, sOutR; };

__global__ __launch_bounds__(256) void transpose_f2b(TrP p) {
  __shared__ __align__(16) bf16 tile[64][80];
  const int tid = threadIdx.x;
  const int ct = blockIdx.x, rt = blockIdx.y, z = blockIdx.z;
  const float* in = p.in + p.sIn * z + ((long)rt * 64) * p.C + (long)ct * 64;
  bf16* out = p.out + p.sOut * z + ((long)ct * 64) * p.R + (long)rt * 64;
  bf16* outR = p.outR ? p.outR + p.sOutR * z + ((long)rt * 64) * p.C + (long)ct * 64 : nullptr;
  const int r = tid >> 3, c8 = (tid & 7) * 8;
#pragma unroll
  for (int h = 0; h < 2; h++) {
    int rr = r + h * 32;
    float4 a = *(const float4*)(in + (long)rr * p.C + c8);
    float4 b = *(const float4*)(in + (long)rr * p.C + c8 + 4);
    u32 w[4];
    w[0] = f2bfu(a.x) | (f2bfu(a.y) << 16);
    w[1] = f2bfu(a.z) | (f2bfu(a.w) << 16);
    w[2] = f2bfu(b.x) | (f2bfu(b.y) << 16);
    w[3] = f2bfu(b.z) | (f2bfu(b.w) << 16);
    *(u32x4*)&tile[rr][c8] = *(u32x4*)w;
    if (outR) *(u32x4*)(outR + (long)rr * p.C + c8) = *(u32x4*)w;
  }
  __syncthreads();
  const int co = tid >> 3, r8 = (tid & 7) * 8;
#pragma unroll
  for (int h = 0; h < 2; h++) {
    int cc = co + h * 32;
    __align__(16) bf16 tmp[8];
#pragma unroll
    for (int j = 0; j < 8; j++) tmp[j] = tile[r8 + j][cc];
    *(u32x4*)(out + (long)cc * p.R + r8) = *(const u32x4*)tmp;
  }
}

// ---------------------------------------------------------------- softmax (rows of 4096, in-place bf16)
__global__ __launch_bounds__(256) void softmax_rows(bf16* X) {
  const long row = blockIdx.x;
  u32* x = (u32*)(X + row * 4096);
  const int tid = threadIdx.x;
  const int lane = tid & 63, wave = tid >> 6;
  u32 d[8];
  *(u32x4*)&d[0] = ((const u32x4*)x)[tid * 2];
  *(u32x4*)&d[4] = ((const u32x4*)x)[tid * 2 + 1];
  float v[16];
#pragma unroll
  for (int j = 0; j < 8; j++) {
    v[2 * j] = __uint_as_float(d[j] << 16);
    v[2 * j + 1] = __uint_as_float(d[j] & 0xffff0000u);
  }
  float m = v[0];
#pragma unroll
  for (int i = 1; i < 16; i++) m = fmaxf(m, v[i]);
  for (int off = 32; off; off >>= 1) m = fmaxf(m, __shfl_xor(m, off));
  __shared__ float sm1[4], sm2[4];
  if (lane == 0) sm1[wave] = m;
  __syncthreads();
  m = fmaxf(fmaxf(sm1[0], sm1[1]), fmaxf(sm1[2], sm1[3]));
  float s = 0.f;
#pragma unroll
  for (int i = 0; i < 16; i++) { v[i] = __expf(v[i] - m); s += v[i]; }
  for (int off = 32; off; off >>= 1) s += __shfl_xor(s, off);
  if (lane == 0) sm2[wave] = s;
  __syncthreads();
  s = sm2[0] + sm2[1] + sm2[2] + sm2[3];
  const float inv = 1.f / s;
#pragma unroll
  for (int j = 0; j < 8; j++) {
    u32 lo = f2bfu(v[2 * j] * inv);
    u32 hi = f2bfu(v[2 * j + 1] * inv);
    d[j] = lo | (hi << 16);
  }
  ((u32x4*)x)[tid * 2] = *(u32x4*)&d[0];
  ((u32x4*)x)[tid * 2 + 1] = *(u32x4*)&d[4];
}

// ---------------------------------------------------------------- layernorm (rows of 768)
// outputs: outf (f32), and/or outb (bf16), and/or queries = ln + qc (qf f32 + qb16).
__global__ __launch_bounds__(256) void ln_rows(const float* in, const float* g, const float* b,
                                               float* outf, bf16* outb,
                                               const float* qc, float* qf, bf16* qb16) {
  const long row = blockIdx.x;
  const float* x = in + row * 768;
  const int tid = threadIdx.x;
  const int lane = tid & 63, wave = tid >> 6;
  float v0 = x[tid], v1 = x[tid + 256], v2 = x[tid + 512];
  float s = v0 + v1 + v2;
  float s2 = v0 * v0 + v1 * v1 + v2 * v2;
  for (int off = 32; off; off >>= 1) { s += __shfl_xor(s, off); s2 += __shfl_xor(s2, off); }
  __shared__ float sa[4], sb[4];
  if (lane == 0) { sa[wave] = s; sb[wave] = s2; }
  __syncthreads();
  s = sa[0] + sa[1] + sa[2] + sa[3];
  s2 = sb[0] + sb[1] + sb[2] + sb[3];
  const float mean = s * (1.f / 768.f);
  const float var = s2 * (1.f / 768.f) - mean * mean;
  const float rs = rsqrtf(var + 1e-5f);
  float o0 = (v0 - mean) * rs * g[tid] + b[tid];
  float o1 = (v1 - mean) * rs * g[tid + 256] + b[tid + 256];
  float o2 = (v2 - mean) * rs * g[tid + 512] + b[tid + 512];
  if (outf) { float* of = outf + row * 768; of[tid] = o0; of[tid + 256] = o1; of[tid + 512] = o2; }
  if (outb) { bf16* ob = outb + row * 768; ob[tid] = f2bf(o0); ob[tid + 256] = f2bf(o1); ob[tid + 512] = f2bf(o2); }
  if (qc) {
    const float* qr = qc + (row & 63) * 768;
    float u0 = o0 + qr[tid], u1 = o1 + qr[tid + 256], u2 = o2 + qr[tid + 512];
    float* pf = qf + row * 768;
    pf[tid] = u0; pf[tid + 256] = u1; pf[tid + 512] = u2;
    bf16* pb = qb16 + row * 768;
    pb[tid] = f2bf(u0); pb[tid + 256] = f2bf(u1); pb[tid + 512] = f2bf(u2);
  }
}

// ---------------------------------------------------------------- combine split-K partials
// s = sum_{c<nch} in[c*393216+i] (+bias[i%768]) (+res[i]); outputs nullable.
struct CombP { const float* in; int nch; const float* bias; const float* res;
               float* outf; bf16* outb; const float* qc; float* qf; bf16* qb16; };

__global__ __launch_bounds__(256) void combine(CombP p) {
  const long i = (long)blockIdx.x * 256 + threadIdx.x;  // n = 393216
  float s = 0.f;
  for (int c = 0; c < p.nch; c++) s += p.in[(long)c * 393216 + i];
  if (p.bias) s += p.bias[i % 768];
  if (p.res) s += p.res[i];
  if (p.outf) p.outf[i] = s;
  if (p.outb) p.outb[i] = f2bf(s);
  if (p.qc) {
    float v = s + p.qc[i % 49152];
    p.qf[i] = v;
    p.qb16[i] = f2bf(v);
  }
}

// ================================================================ launcher
extern "C" void kernel_launch(void* const* d_in, const int* in_sizes, int n_in,
                              void* d_out, int out_size, void* d_ws, size_t ws_size,
                              hipStream_t stream) {
  (void)in_sizes; (void)n_in; (void)out_size; (void)ws_size;
  const float* tokens   = (const float*)d_in[0];
  const float* selector = (const float*)d_in[1];
  const float* qc  = (const float*)d_in[2];
  const float* qw  = (const float*)d_in[3];
  const float* qb  = (const float*)d_in[4];
  const float* kw  = (const float*)d_in[5];
  const float* kb  = (const float*)d_in[6];
  const float* vw  = (const float*)d_in[7];
  const float* vb  = (const float*)d_in[8];
  const float* hw  = (const float*)d_in[9];
  const float* hb  = (const float*)d_in[10];
  const float* ow  = (const float*)d_in[11];
  const float* ob  = (const float*)d_in[12];
  const float* w1  = (const float*)d_in[13];
  const float* b1  = (const float*)d_in[14];
  const float* w2  = (const float*)d_in[15];
  const float* b2  = (const float*)d_in[16];
  const float* g1  = (const float*)d_in[17];
  const float* be1 = (const float*)d_in[18];
  const float* g2  = (const float*)d_in[19];
  const float* be2 = (const float*)d_in[20];
  float* out = (float*)d_out;

  char* ws = (char*)d_ws;
  size_t off = 0;
  auto alloc = [&](size_t bytes) { char* pp = ws + off; off += (bytes + 255) & ~(size_t)255; return pp; };
  bf16* TOKT  = (bf16*)alloc(50331648);   // tokens^T [B,D,N]; later attention P
  bf16* PBUF  = TOKT;
  bf16* TOKB  = (bf16*)alloc(50331648);   // tokens bf16 [B,N,D]
  bf16* KBUF  = (bf16*)alloc(50331648);   // k [B,N,H,HD]
  bf16* VTB   = (bf16*)alloc(50331648);   // v^T [B,768,N]
  bf16* PLOG  = (bf16*)alloc(4194304);    // pooling logits [B,M,N]
  bf16* SELB  = (bf16*)alloc(98304);      // selector bf16 [M,D]
  bf16* QWT   = (bf16*)alloc(4718592);    // [L,H,HD,D]
  bf16* KWT   = (bf16*)alloc(4718592);
  bf16* VWT   = (bf16*)alloc(4718592);
  bf16* HWT   = (bf16*)alloc(393216);     // [L,H,HD,HD]
  bf16* OWT   = (bf16*)alloc(4718592);    // [L,D,D]
  bf16* W1T   = (bf16*)alloc(18874368);   // [L,3072,768]
  bf16* W2T   = (bf16*)alloc(18874368);   // [L,768,3072]
  bf16* QBUF  = (bf16*)alloc(786432);     // q [B,M,H,HD]
  bf16* OBUF  = (bf16*)alloc(786432);     // attn out [B,H,M,HD]
  bf16* O2BUF = (bf16*)alloc(786432);     // head-mixed concat [B*M,768]
  float* QF   = (float*)alloc(1572864);   // queries f32
  bf16* QB16  = (bf16*)alloc(786432);     // queries bf16
  float* T1   = (float*)alloc(1572864);
  float* X1F  = (float*)alloc(1572864);
  bf16* X1B   = (bf16*)alloc(786432);
  bf16* H1    = (bf16*)alloc(3145728);    // gelu(mlp1) [512,3072]
  float* T2   = (float*)alloc(1572864);
  float* OPART = (float*)alloc(12582912); // split-K partials [<=8][393216]

  auto tr = [&](const float* in, bf16* o, bf16* oR, int R, int C, long s, long sR, int slabs) {
    TrP t{in, o, oR, R, C, s, s, sR};
    transpose_f2b<<<dim3(C / 64, R / 64, slabs), 256, 0, stream>>>(t);
  };
  tr(tokens, TOKT, TOKB, 4096, 768, 3145728, 3145728, 8);
  cvt_f2b<<<24, 256, 0, stream>>>(selector, SELB, 49152);
  tr(qw, QWT, nullptr, 768, 64, 49152, 0, 48);
  tr(kw, KWT, nullptr, 768, 64, 49152, 0, 48);
  tr(vw, VWT, nullptr, 768, 64, 49152, 0, 48);
  tr(hw, HWT, nullptr, 64, 64, 4096, 0, 48);
  tr(ow, OWT, nullptr, 768, 768, 589824, 0, 4);
  tr(w1, W1T, nullptr, 768, 3072, 2359296, 0, 4);
  tr(w2, W2T, nullptr, 3072, 768, 2359296, 0, 4);

  // ---- pooling
  {
    GemmSmP p{}; p.A = SELB; p.B = TOKB; p.C = PLOG;
    p.sB1 = 3145728; p.sC1 = 262144; p.nb2 = 1;
    p.lda = 768; p.ldb = 768; p.ldc = 4096; p.K = 768;
    p.bias_mode = 0; p.out_mode = 1; p.scale = 1.0f;
    gemm_sm<<<dim3(64, 1, 8), 256, 0, stream>>>(p);
  }
  softmax_rows<<<512, 256, 0, stream>>>(PLOG);
  { // x partials = P · tokens (split-K 8 over N)
    GemmSmP p{}; p.A = PLOG; p.B = TOKT; p.C = OPART;
    p.sA1 = 512; p.sA2 = 262144; p.sB1 = 512; p.sB2 = 3145728;
    p.sC1 = 393216; p.sC2 = 49152; p.nb2 = 8;
    p.lda = 4096; p.ldb = 4096; p.ldc = 768; p.K = 512;
    p.bias_mode = 0; p.out_mode = 0; p.scale = 1.0f;
    gemm_sm<<<dim3(12, 1, 64), 256, 0, stream>>>(p);
  }
  { // x -> queries(l=0) = x + qc[0]
    CombP c{}; c.in = OPART; c.nch = 8; c.qc = qc; c.qf = QF; c.qb16 = QB16;
    combine<<<1536, 256, 0, stream>>>(c);
  }

  for (int l = 0; l < 4; l++) {
    { // q = queries · qw^T + qb  -> [B,M,H,HD] bf16
      GemmSmP p{}; p.A = QB16; p.B = QWT + l * 589824; p.C = QBUF; p.bias = qb + l * 768;
      p.nb2 = 1; p.lda = 768; p.ldb = 768; p.ldc = 768; p.K = 768;
      p.bias_mode = 1; p.out_mode = 1; p.scale = 1.0f;
      gemm_sm<<<dim3(12, 8, 1), 256, 0, stream>>>(p);
    }
    { // fused k,v projection: tokens staged once, both outputs
      GemmKVP p{TOKB, KWT + l * 589824, VWT + l * 589824, KBUF, VTB,
                kb + l * 768, vb + l * 768};
      gemm_kv<<<dim3(6, 256, 1), 256, 0, stream>>>(p);
    }
    { // S = (q·k^T)*scale -> PBUF bf16 [B,H,M,N]   (z = b*12+h)
      GemmSmP p{}; p.A = QBUF; p.B = KBUF; p.C = PBUF;
      p.sA1 = 49152; p.sA2 = 64; p.sB1 = 3145728; p.sB2 = 64; p.sC1 = 3145728; p.sC2 = 262144;
      p.nb2 = 12; p.lda = 768; p.ldb = 768; p.ldc = 4096; p.K = 64;
      p.bias_mode = 0; p.out_mode = 1; p.scale = 0.125f;
      gemm_sm<<<dim3(64, 1, 96), 256, 0, stream>>>(p);
    }
    softmax_rows<<<6144, 256, 0, stream>>>(PBUF);
    { // o partials = P · v (split-K 8)   z = chunk*96 + (b*12+h)
      GemmSmP p{}; p.A = PBUF; p.B = VTB; p.C = OPART;
      p.sA1 = 512; p.sA2 = 262144; p.sB1 = 512; p.sB2 = 262144; p.sC1 = 393216; p.sC2 = 4096;
      p.nb2 = 96; p.lda = 4096; p.ldb = 4096; p.ldc = 64; p.K = 512;
      p.bias_mode = 0; p.out_mode = 0; p.scale = 1.0f;
      gemm_sm<<<dim3(1, 1, 768), 256, 0, stream>>>(p);
    }
    { CombP c{}; c.in = OPART; c.nch = 8; c.outb = OBUF; combine<<<1536, 256, 0, stream>>>(c); }
    { // head-mix   z = b*12+h
      GemmSmP p{}; p.A = OBUF; p.B = HWT + l * 49152; p.C = O2BUF; p.bias = hb + l * 768;
      p.sA1 = 49152; p.sA2 = 4096; p.sB1 = 0; p.sB2 = 4096; p.sC1 = 49152; p.sC2 = 64; p.sBias2 = 64;
      p.nb2 = 12; p.lda = 64; p.ldb = 64; p.ldc = 768; p.K = 64;
      p.bias_mode = 1; p.out_mode = 1; p.scale = 1.0f;
      gemm_sm<<<dim3(1, 1, 96), 256, 0, stream>>>(p);
    }
    { // o-proj partials (split-K 4): o2 · ow^T
      GemmSmP p{}; p.A = O2BUF; p.B = OWT + l * 589824; p.C = OPART;
      p.sA1 = 192; p.sB1 = 192; p.sC1 = 393216; p.nb2 = 1;
      p.lda = 768; p.ldb = 768; p.ldc = 768; p.K = 192;
      p.bias_mode = 0; p.out_mode = 0; p.scale = 1.0f;
      gemm_sm<<<dim3(12, 8, 4), 256, 0, stream>>>(p);
    }
    { CombP c{}; c.in = OPART; c.nch = 4; c.bias = ob + l * 768; c.res = QF; c.outf = T1;
      combine<<<1536, 256, 0, stream>>>(c); }
    ln_rows<<<512, 256, 0, stream>>>(T1, g1 + l * 768, be1 + l * 768, X1F, X1B, nullptr, nullptr, nullptr);
    { // mlp1 = gelu(x1 · w1^T + b1) bf16
      GemmSmP p{}; p.A = X1B; p.B = W1T + l * 2359296; p.C = H1; p.bias = b1 + l * 3072;
      p.nb2 = 1; p.lda = 768; p.ldb = 768; p.ldc = 3072; p.K = 768;
      p.bias_mode = 1; p.out_mode = 2; p.scale = 1.0f;
      gemm_sm<<<dim3(48, 8, 1), 256, 0, stream>>>(p);
    }
    { // mlp2 partials (split-K 8): h1 · w2^T
      GemmSmP p{}; p.A = H1; p.B = W2T + l * 2359296; p.C = OPART;
      p.sA1 = 384; p.sB1 = 384; p.sC1 = 393216; p.nb2 = 1;
      p.lda = 3072; p.ldb = 3072; p.ldc = 768; p.K = 384;
      p.bias_mode = 0; p.out_mode = 0; p.scale = 1.0f;
      gemm_sm<<<dim3(12, 8, 8), 256, 0, stream>>>(p);
    }
    { CombP c{}; c.in = OPART; c.nch = 8; c.bias = b2 + l * 768; c.res = X1F; c.outf = T2;
      combine<<<1536, 256, 0, stream>>>(c); }
    // second LN: for l<3 emit queries(l+1) = ln + qc[l+1]; for l==3 emit final out (f32)
    ln_rows<<<512, 256, 0, stream>>>(T2, g2 + l * 768, be2 + l * 768,
                                     (l == 3) ? out : nullptr, nullptr,
                                     (l < 3) ? (qc + (l + 1) * 49152) : nullptr, QF, QB16);
  }
}

// Round 3
// 1098.855 us; speedup vs baseline: 1.3339x; 1.2714x over previous
//
#include <hip/hip_runtime.h>
#include <hip/hip_bf16.h>

// VisualDecoder: B=8,N=4096,D=768,H=12,M=64,L=4,HD=64. In/out f32; compute bf16
// MFMA (f32 accum). R9: (1) T2 LDS read-swizzle (2-way banks) in gemm_kv/gemm_sm
// via pre-swizzled global_load_lds source + XOR'd ds_read slot; (2) gemm_kv V^T
// epilogue through LDS -> coalesced 16B stores (kills 2x write amplification);
// (3) flash-style fused attention (attn_part + attn_comb) replacing
// S-GEMM/softmax/PV/combine -- S matrix never hits HBM.

using bf16 = __hip_bfloat16;
typedef __attribute__((ext_vector_type(8))) __bf16 bf16x8;
typedef __attribute__((ext_vector_type(4))) float f32x4;
typedef unsigned int u32;
typedef __attribute__((ext_vector_type(4))) u32 u32x4;

#define DEVINL __device__ __forceinline__

DEVINL float bf2f(bf16 v) { return __bfloat162float(v); }
DEVINL bf16 f2bf(float v) { return __float2bfloat16(v); }
DEVINL u32 f2bfu(float f) { bf16 h = __float2bfloat16(f); return *(unsigned short*)&h; }
DEVINL float gelu_f(float x) { return 0.5f * x * (1.0f + erff(x * 0.70710678118654752f)); }

// async global->LDS, 16B per lane. LDS dest = wave-uniform base + lane*16 (ours is).
DEVINL void async16(const bf16* g, bf16* l) {
  __builtin_amdgcn_global_load_lds(
      (const __attribute__((address_space(1))) u32*)g,
      (__attribute__((address_space(3))) u32*)l, 16, 0, 0);
}

// XCD-chunked bijective block-id swizzle (m204).
DEVINL u32 xcd_swizzle(u32 id, u32 nwg) {
  u32 q = nwg >> 3, r = nwg & 7;
  u32 xcd = id & 7, pos = id >> 3;
  return xcd * q + (xcd < r ? xcd : r) + pos;
}

// ---------------------------------------------------------------- flat f32 -> bf16
__global__ __launch_bounds__(256) void cvt_f2b(const float* in, bf16* out, long n) {
  const long i = ((long)blockIdx.x * 256 + threadIdx.x) * 8;
  if (i >= n) return;
  float4 a = *(const float4*)(in + i);
  float4 b = *(const float4*)(in + i + 4);
  u32 w[4];
  w[0] = f2bfu(a.x) | (f2bfu(a.y) << 16);
  w[1] = f2bfu(a.z) | (f2bfu(a.w) << 16);
  w[2] = f2bfu(b.x) | (f2bfu(b.y) << 16);
  w[3] = f2bfu(b.z) | (f2bfu(b.w) << 16);
  *(u32x4*)(out + i) = *(u32x4*)w;
}

// ---------------------------------------------------------------- fused K+V projection
// 128x128 tile, BK=32. 3-slot counted-vmcnt pipeline. LDS tiles [128][32] with
// 16B-slot swizzle: chunk (r,qc) stored at slot r*4 + (qc ^ ((r>>1)&3)).
// K written direct; V^T written via LDS transpose tile -> coalesced stores.
struct GemmKVP {
  const bf16* A;      // TOKB [32768,768]
  const bf16* Bk;     // KWT layer [768,768]
  const bf16* Bv;     // VWT layer [768,768]
  bf16* Ck;           // KBUF
  bf16* Cv;           // VTB
  const float* biask; // kb[768]
  const float* biasv; // vb[768]
};

__global__ __launch_bounds__(256, 2) void gemm_kv(GemmKVP p) {
  __shared__ __align__(16) bf16 SH[36864];  // 72KB: As[3]|Ks[3]|Vs[3] of 4096 each
  bf16* As = SH;
  bf16* Ks = SH + 12288;
  bf16* Vs = SH + 24576;
  const int tid = threadIdx.x;
  const int wave = tid >> 6, lane = tid & 63;

  u32 id = blockIdx.x + 6u * blockIdx.y;     // grid (6, 256)
  id = xcd_swizzle(id, 1536);
  const int bn = id % 6;
  const int bm = id / 6;

  const bf16* Ag = p.A + (long)bm * 128 * 768;
  const bf16* Kg = p.Bk + (long)bn * 128 * 768;
  const bf16* Vg = p.Bv + (long)bn * 128 * 768;

  // staging: thread stages LDS slots {tid, tid+256}; slot sl -> row sl>>2,
  // swizzled col chunk qc = (sl&3) ^ ((sl>>3)&3)  (same for sl and sl+256).
  const int cq = (((tid & 3) ^ ((tid >> 3) & 3))) * 8;
  const long ro = (long)(tid >> 2) * 768 + cq;
  const long r1 = ro + (long)64 * 768;
  const bf16* ga0 = Ag + ro; const bf16* ga1 = Ag + r1;
  const bf16* gk0 = Kg + ro; const bf16* gk1 = Kg + r1;
  const bf16* gv0 = Vg + ro; const bf16* gv1 = Vg + r1;

  const int m_in = lane & 15, q = lane >> 4;
  const int wm = (wave & 1) * 64, wn = (wave >> 1) * 64;
  const int sw3 = (q ^ ((m_in >> 1) & 3)) << 3;  // read slot offset (elems)
  f32x4 acck[4][4] = {};
  f32x4 accv[4][4] = {};
  const int nk = 24;  // K=768

  auto stage = [&](int s, int ko) {
    async16(ga0 + ko, As + s * 4096 + tid * 8);
    async16(ga1 + ko, As + s * 4096 + 2048 + tid * 8);
    async16(gk0 + ko, Ks + s * 4096 + tid * 8);
    async16(gk1 + ko, Ks + s * 4096 + 2048 + tid * 8);
    async16(gv0 + ko, Vs + s * 4096 + tid * 8);
    async16(gv1 + ko, Vs + s * 4096 + 2048 + tid * 8);
  };
  stage(0, 0);
  stage(1, 32);

  int slot = 0;
  for (int k = 0; k < nk; ++k) {
    if (k + 1 < nk) asm volatile("s_waitcnt vmcnt(6)" ::: "memory");
    else            asm volatile("s_waitcnt vmcnt(0)" ::: "memory");
    __builtin_amdgcn_s_barrier();
    if (k + 2 < nk) {
      int ns = slot + 2; if (ns >= 3) ns -= 3;
      stage(ns, (k + 2) * 32);
    }
    const bf16* Ac = As + slot * 4096;
    const bf16* Kc = Ks + slot * 4096;
    const bf16* Vc = Vs + slot * 4096;
    bf16x8 af[4], bfr[4];
#pragma unroll
    for (int i = 0; i < 4; i++)
      af[i] = *(const bf16x8*)(Ac + (wm + i * 16 + m_in) * 32 + sw3);
#pragma unroll
    for (int j = 0; j < 4; j++)
      bfr[j] = *(const bf16x8*)(Kc + (wn + j * 16 + m_in) * 32 + sw3);
#pragma unroll
    for (int i = 0; i < 4; i++)
#pragma unroll
      for (int j = 0; j < 4; j++)
        acck[i][j] = __builtin_amdgcn_mfma_f32_16x16x32_bf16(af[i], bfr[j], acck[i][j], 0, 0, 0);
#pragma unroll
    for (int j = 0; j < 4; j++)
      bfr[j] = *(const bf16x8*)(Vc + (wn + j * 16 + m_in) * 32 + sw3);
#pragma unroll
    for (int i = 0; i < 4; i++)
#pragma unroll
      for (int j = 0; j < 4; j++)
        accv[i][j] = __builtin_amdgcn_mfma_f32_16x16x32_bf16(af[i], bfr[j], accv[i][j], 0, 0, 0);
    slot = (slot + 1 == 3) ? 0 : slot + 1;
  }

  const long row0 = (long)bm * 128 + wm + q * 4;
  const long col0 = (long)bn * 128 + wn + m_in;
  const int bb = (bm * 128) >> 12;
  const int nn0 = (bm * 128) & 4095;
  // ---- K: direct stores
#pragma unroll
  for (int i = 0; i < 4; i++)
#pragma unroll
    for (int j = 0; j < 4; j++) {
      long r = row0 + i * 16;
      long c = col0 + j * 16;
      float bk_ = p.biask[c];
#pragma unroll
      for (int t = 0; t < 4; t++)
        p.Ck[(r + t) * 768 + c] = f2bf(acck[i][j][t] + bk_);
    }
  // ---- V: transpose via LDS, coalesced store
  __syncthreads();  // drain all waves' K-loop LDS reads before reuse
  bf16* VT = SH;    // [128 e][128 n], 16B slots swizzled: phys = slot ^ (e&15)
#pragma unroll
  for (int i = 0; i < 4; i++) {
    const int nb = wm + q * 4 + i * 16;  // n_local base (t in 0..3)
    const int sl = nb >> 3;
    const int of = nb & 7;
#pragma unroll
    for (int j = 0; j < 4; j++) {
      const int e = wn + j * 16 + m_in;
      const float bv_ = p.biasv[bn * 128 + e];
      u32 w0 = f2bfu(accv[i][j][0] + bv_) | (f2bfu(accv[i][j][1] + bv_) << 16);
      u32 w1 = f2bfu(accv[i][j][2] + bv_) | (f2bfu(accv[i][j][3] + bv_) << 16);
      uint2 pk; pk.x = w0; pk.y = w1;
      *(uint2*)(VT + e * 128 + ((sl ^ (e & 15)) << 3) + of) = pk;
    }
  }
  __syncthreads();
  bf16* CvB = p.Cv + (long)bb * 3145728;
#pragma unroll
  for (int k2 = 0; k2 < 8; k2++) {
    int g = tid + k2 * 256;
    int e = g >> 4, sc = g & 15;
    u32x4 vv = *(const u32x4*)(VT + e * 128 + ((sc ^ (e & 15)) << 3));
    *(u32x4*)(CvB + (long)(bn * 128 + e) * 4096 + nn0 + sc * 8) = vv;
  }
}

// ---------------------------------------------------------------- small GEMM
// 64x64 tile, BK=32, 3-slot counted-vmcnt pipeline, 2-level batch, XCD swizzle,
// T2 read-swizzle (pre-swizzled source + XOR'd read slot).
struct GemmSmP {
  const bf16* A; const bf16* B; void* C; const float* bias; const float* res;
  long sA1, sA2, sB1, sB2, sC1, sC2, sBias2;
  int nb2, lda, ldb, ldc, K;
  int bias_mode;  // 0 none, 1 per-col
  int out_mode;   // 0 f32 (+res), 1 bf16, 2 gelu->bf16
  float scale;
};

__global__ __launch_bounds__(256, 4) void gemm_sm(GemmSmP p) {
  __shared__ __align__(16) bf16 As[3][64 * 32];
  __shared__ __align__(16) bf16 Bs[3][64 * 32];
  const int tid = threadIdx.x;
  const int wave = tid >> 6, lane = tid & 63;

  const u32 gx = gridDim.x, gy = gridDim.y;
  u32 id = blockIdx.x + gx * (blockIdx.y + gy * blockIdx.z);
  id = xcd_swizzle(id, gx * gy * gridDim.z);
  const int bn = id % gx;
  const u32 t2 = id / gx;
  const int bm = t2 % gy;
  const int bz = t2 / gy;

  const int z1 = bz / p.nb2, z2 = bz - z1 * p.nb2;
  const bf16* Ag = p.A + p.sA1 * z1 + p.sA2 * z2 + (long)bm * 64 * p.lda;
  const bf16* Bg = p.B + p.sB1 * z1 + p.sB2 * z2 + (long)bn * 64 * p.ldb;

  const int cq = (((tid & 3) ^ ((tid >> 3) & 3))) * 8;
  const bf16* gpa = Ag + ((long)(tid >> 2) * p.lda + cq);
  const bf16* gpb = Bg + ((long)(tid >> 2) * p.ldb + cq);

  const int m_in = lane & 15, q = lane >> 4;
  const int wm = (wave & 1) * 32, wn = (wave >> 1) * 32;
  const int sw3 = (q ^ ((m_in >> 1) & 3)) << 3;
  f32x4 acc[2][2] = {};
  const int nk = p.K >> 5;

  async16(gpa, &As[0][0] + tid * 8);
  async16(gpb, &Bs[0][0] + tid * 8);
  if (nk > 1) {
    async16(gpa + 32, &As[1][0] + tid * 8);
    async16(gpb + 32, &Bs[1][0] + tid * 8);
  }

  int slot = 0;
  for (int k = 0; k < nk; ++k) {
    if (k + 1 < nk) asm volatile("s_waitcnt vmcnt(2)" ::: "memory");
    else            asm volatile("s_waitcnt vmcnt(0)" ::: "memory");
    __builtin_amdgcn_s_barrier();
    if (k + 2 < nk) {
      int ns = slot + 2; if (ns >= 3) ns -= 3;
      const int ko = (k + 2) * 32;
      async16(gpa + ko, &As[ns][0] + tid * 8);
      async16(gpb + ko, &Bs[ns][0] + tid * 8);
    }
    const bf16* Ac = &As[slot][0];
    const bf16* Bc = &Bs[slot][0];
    bf16x8 a0 = *(const bf16x8*)(Ac + (wm + m_in) * 32 + sw3);
    bf16x8 a1 = *(const bf16x8*)(Ac + (wm + 16 + m_in) * 32 + sw3);
    bf16x8 b0 = *(const bf16x8*)(Bc + (wn + m_in) * 32 + sw3);
    bf16x8 b1 = *(const bf16x8*)(Bc + (wn + 16 + m_in) * 32 + sw3);
    acc[0][0] = __builtin_amdgcn_mfma_f32_16x16x32_bf16(a0, b0, acc[0][0], 0, 0, 0);
    acc[0][1] = __builtin_amdgcn_mfma_f32_16x16x32_bf16(a0, b1, acc[0][1], 0, 0, 0);
    acc[1][0] = __builtin_amdgcn_mfma_f32_16x16x32_bf16(a1, b0, acc[1][0], 0, 0, 0);
    acc[1][1] = __builtin_amdgcn_mfma_f32_16x16x32_bf16(a1, b1, acc[1][1], 0, 0, 0);
    slot = (slot + 1 == 3) ? 0 : slot + 1;
  }

  const long row0 = (long)bm * 64 + wm + q * 4;
  const long col0 = (long)bn * 64 + wn + m_in;
  const float* bias = p.bias + p.sBias2 * z2;
#pragma unroll
  for (int i = 0; i < 2; i++)
#pragma unroll
    for (int j = 0; j < 2; j++) {
      long r = row0 + i * 16;
      long cc = col0 + j * 16;
      float badd = (p.bias_mode == 1) ? bias[cc] : 0.f;
#pragma unroll
      for (int t = 0; t < 4; t++) {
        float v = acc[i][j][t] * p.scale + badd;
        long idx = (r + t) * p.ldc + cc;
        if (p.out_mode == 0) {
          float* Cf = (float*)p.C + p.sC1 * z1 + p.sC2 * z2;
          if (p.res) v += p.res[idx];
          Cf[idx] = v;
        } else {
          bf16* Cb = (bf16*)p.C + p.sC1 * z1 + p.sC2 * z2;
          if (p.out_mode == 2) v = gelu_f(v);
          Cb[idx] = f2bf(v);
        }
      }
    }
}

// ---------------------------------------------------------------- flash attention partial
// Block = (z=b*12+h, chunk c of 512 n). 4 waves x 16 q-rows. Online softmax per
// chunk; per-chunk (m,l) + O-partial to global; attn_comb merges 8 chunks.
// LDS 48KB (Q 8 | K dbuf 16 | V dbuf 16 | P 8) -> 3 blocks/CU.
struct AttnP {
  const bf16* Q;   // QBUF [B*M,768], head at h*64
  const bf16* K;   // KBUF [B*N,768], head at h*64
  const bf16* VT;  // VTB [B][768][4096], rows h*64+e
  float* Opart;    // [8][96][64][64]
  float* ML;       // [8][96][2][64]
};

__global__ __launch_bounds__(256, 3) void attn_part(AttnP p) {
  __shared__ __align__(16) bf16 SH[24576];
  bf16* Qs = SH;             // [64][64] swz (16B slots XOR row&7)
  bf16* Ks = SH + 4096;      // 2 bufs of [64][64]
  bf16* Vs = SH + 12288;     // 2 bufs of [64][64]
  bf16* Ps = SH + 20480;     // [64][64] swz
  const int tid = threadIdx.x;
  const int wave = tid >> 6, lane = tid & 63;
  const int z = blockIdx.x, c = blockIdx.y;
  const int b = z / 12, h = z - b * 12;
  const int n0 = c * 512;

  // staging: slot sl -> row sl>>3, phys col chunk qc = (sl&7) ^ (row&7)
  const int sl0 = tid, sl1 = tid + 256;
  const int r0 = sl0 >> 3, r1 = sl1 >> 3;
  const int q0 = (sl0 & 7) ^ (r0 & 7), q1 = (sl1 & 7) ^ (r1 & 7);

  const bf16* Qg = p.Q + ((long)b * 64) * 768 + h * 64;
  const bf16* Kg = p.K + ((long)b * 4096 + n0) * 768 + h * 64;
  const bf16* Vg = p.VT + (long)b * 3145728 + (long)(h * 64) * 4096 + n0;

  async16(Qg + (long)r0 * 768 + q0 * 8, Qs + sl0 * 8);
  async16(Qg + (long)r1 * 768 + q1 * 8, Qs + sl1 * 8);
  auto stageK = [&](int s) {
    bf16* d = Ks + (s & 1) * 4096;
    async16(Kg + (long)(s * 64 + r0) * 768 + q0 * 8, d + sl0 * 8);
    async16(Kg + (long)(s * 64 + r1) * 768 + q1 * 8, d + sl1 * 8);
  };
  auto stageV = [&](int s) {
    bf16* d = Vs + (s & 1) * 4096;
    async16(Vg + (long)r0 * 4096 + s * 64 + q0 * 8, d + sl0 * 8);
    async16(Vg + (long)r1 * 4096 + s * 64 + q1 * 8, d + sl1 * 8);
  };
  stageK(0); stageV(0); stageK(1); stageV(1);

  const int m_in = lane & 15, q = lane >> 4;
  const int wm = wave * 16;

  asm volatile("s_waitcnt vmcnt(8)" ::: "memory");  // Q landed
  __builtin_amdgcn_s_barrier();

  bf16x8 qa[2];
  {
    const int ra = wm + m_in;
#pragma unroll
    for (int kk = 0; kk < 2; kk++)
      qa[kk] = *(const bf16x8*)(Qs + ra * 64 + ((((kk * 4 + q) ^ (ra & 7))) << 3));
  }

  f32x4 accO[4] = {};
  float m_run[4] = {-1e30f, -1e30f, -1e30f, -1e30f};
  float l_run[4] = {0.f, 0.f, 0.f, 0.f};

  for (int s = 0; s < 8; ++s) {
    if (s < 7) asm volatile("s_waitcnt vmcnt(4)" ::: "memory");
    else       asm volatile("s_waitcnt vmcnt(0)" ::: "memory");
    __builtin_amdgcn_s_barrier();
    const bf16* Kc = Ks + (s & 1) * 4096;
    const bf16* Vc = Vs + (s & 1) * 4096;
    // S = Q . K^T  (rows m = wm+q*4+t, cols n = m_in+16j)
    f32x4 accS[4] = {};
#pragma unroll
    for (int kk = 0; kk < 2; kk++) {
#pragma unroll
      for (int j = 0; j < 4; j++) {
        const int rj = j * 16 + m_in;
        bf16x8 kb = *(const bf16x8*)(Kc + rj * 64 + ((((kk * 4 + q) ^ (rj & 7))) << 3));
        accS[j] = __builtin_amdgcn_mfma_f32_16x16x32_bf16(qa[kk], kb, accS[j], 0, 0, 0);
      }
    }
    // online softmax partial (scale 0.125)
    float pe[4][4], osc[4];
#pragma unroll
    for (int t = 0; t < 4; t++) {
      float mx = fmaxf(fmaxf(accS[0][t], accS[1][t]), fmaxf(accS[2][t], accS[3][t])) * 0.125f;
      mx = fmaxf(mx, __shfl_xor(mx, 1));
      mx = fmaxf(mx, __shfl_xor(mx, 2));
      mx = fmaxf(mx, __shfl_xor(mx, 4));
      mx = fmaxf(mx, __shfl_xor(mx, 8));
      const float mnew = fmaxf(m_run[t], mx);
      const float so = __expf(m_run[t] - mnew);
      float rs = 0.f;
#pragma unroll
      for (int j = 0; j < 4; j++) {
        float e = __expf(accS[j][t] * 0.125f - mnew);
        pe[j][t] = e; rs += e;
      }
      rs += __shfl_xor(rs, 1); rs += __shfl_xor(rs, 2);
      rs += __shfl_xor(rs, 4); rs += __shfl_xor(rs, 8);
      l_run[t] = l_run[t] * so + rs;
      m_run[t] = mnew;
      osc[t] = so;
    }
#pragma unroll
    for (int ef = 0; ef < 4; ef++)
#pragma unroll
      for (int t = 0; t < 4; t++) accO[ef][t] *= osc[t];
    // P -> LDS (wave-private rows), swizzled slots
#pragma unroll
    for (int j = 0; j < 4; j++) {
      const int pc = m_in + 16 * j;
#pragma unroll
      for (int t = 0; t < 4; t++) {
        const int pm = wm + q * 4 + t;
        Ps[pm * 64 + (((pc >> 3) ^ (pm & 7)) << 3) + (pc & 7)] = f2bf(pe[j][t]);
      }
    }
    // O += P . V  (B = V^T rows e)
    const int ra = wm + m_in;
#pragma unroll
    for (int kk = 0; kk < 2; kk++) {
      bf16x8 pa = *(const bf16x8*)(Ps + ra * 64 + ((((kk * 4 + q) ^ (ra & 7))) << 3));
#pragma unroll
      for (int ef = 0; ef < 4; ef++) {
        const int rv = ef * 16 + m_in;
        bf16x8 vb = *(const bf16x8*)(Vc + rv * 64 + ((((kk * 4 + q) ^ (rv & 7))) << 3));
        accO[ef] = __builtin_amdgcn_mfma_f32_16x16x32_bf16(pa, vb, accO[ef], 0, 0, 0);
      }
    }
    __builtin_amdgcn_s_barrier();  // all waves done with K(s)/V(s) buffers
    if (s < 6) { stageK(s + 2); stageV(s + 2); }
  }

  float* Og = p.Opart + ((long)c * 96 + z) * 4096;
#pragma unroll
  for (int ef = 0; ef < 4; ef++)
#pragma unroll
    for (int t = 0; t < 4; t++)
      Og[(wm + q * 4 + t) * 64 + ef * 16 + m_in] = accO[ef][t];
  if (m_in == 0) {
    float* ml = p.ML + ((long)c * 96 + z) * 128;
#pragma unroll
    for (int t = 0; t < 4; t++) {
      ml[wm + q * 4 + t] = m_run[t];
      ml[64 + wm + q * 4 + t] = l_run[t];
    }
  }
}

// merge 8 chunk-partials: O = (sum w_c O_c) / (sum w_c l_c), w_c = exp(m_c - m*)
struct AttnC { const float* Opart; const float* ML; bf16* O; };

__global__ __launch_bounds__(256) void attn_comb(AttnC p) {
  const int tid = threadIdx.x;
  const int gidx = blockIdx.x * 4 + (tid >> 6);
  const int lane = tid & 63;
  const int z = gidx >> 6, m = gidx & 63;
  float mv[8];
  float mx = -1e30f;
#pragma unroll
  for (int c = 0; c < 8; c++) {
    mv[c] = p.ML[((long)c * 96 + z) * 128 + m];
    mx = fmaxf(mx, mv[c]);
  }
  float l = 0.f, o = 0.f;
#pragma unroll
  for (int c = 0; c < 8; c++) {
    const float w = __expf(mv[c] - mx);
    l += w * p.ML[((long)c * 96 + z) * 128 + 64 + m];
    o += w * p.Opart[(((long)c * 96 + z) * 64 + m) * 64 + lane];
  }
  p.O[((long)z * 64 + m) * 64 + lane] = f2bf(o / l);
}

// ---------------------------------------------------------------- transpose (f32 -> bf16)
struct TrP { const float* in; bf16* out; bf16* outR; int R, C; long sIn, sOut, sOutR; };

__global__ __launch_bounds__(256) void transpose_f2b(TrP p) {
  __shared__ __align__(16) bf16 tile[64][80];
  const int tid = threadIdx.x;
  const int ct = blockIdx.x, rt = blockIdx.y, z = blockIdx.z;
  const float* in = p.in + p.sIn * z + ((long)rt * 64) * p.C + (long)ct * 64;
  bf16* out = p.out + p.sOut * z + ((long)ct * 64) * p.R + (long)rt * 64;
  bf16* outR = p.outR ? p.outR + p.sOutR * z + ((long)rt * 64) * p.C + (long)ct * 64 : nullptr;
  const int r = tid >> 3, c8 = (tid & 7) * 8;
#pragma unroll
  for (int h = 0; h < 2; h++) {
    int rr = r + h * 32;
    float4 a = *(const float4*)(in + (long)rr * p.C + c8);
    float4 b = *(const float4*)(in + (long)rr * p.C + c8 + 4);
    u32 w[4];
    w[0] = f2bfu(a.x) | (f2bfu(a.y) << 16);
    w[1] = f2bfu(a.z) | (f2bfu(a.w) << 16);
    w[2] = f2bfu(b.x) | (f2bfu(b.y) << 16);
    w[3] = f2bfu(b.z) | (f2bfu(b.w) << 16);
    *(u32x4*)&tile[rr][c8] = *(u32x4*)w;
    if (outR) *(u32x4*)(outR + (long)rr * p.C + c8) = *(u32x4*)w;
  }
  __syncthreads();
  const int co = tid >> 3, r8 = (tid & 7) * 8;
#pragma unroll
  for (int h = 0; h < 2; h++) {
    int cc = co + h * 32;
    __align__(16) bf16 tmp[8];
#pragma unroll
    for (int j = 0; j < 8; j++) tmp[j] = tile[r8 + j][cc];
    *(u32x4*)(out + (long)cc * p.R + r8) = *(const u32x4*)tmp;
  }
}

// ---------------------------------------------------------------- softmax (rows of 4096, in-place bf16)
__global__ __launch_bounds__(256) void softmax_rows(bf16* X) {
  const long row = blockIdx.x;
  u32* x = (u32*)(X + row * 4096);
  const int tid = threadIdx.x;
  const int lane = tid & 63, wave = tid >> 6;
  u32 d[8];
  *(u32x4*)&d[0] = ((const u32x4*)x)[tid * 2];
  *(u32x4*)&d[4] = ((const u32x4*)x)[tid * 2 + 1];
  float v[16];
#pragma unroll
  for (int j = 0; j < 8; j++) {
    v[2 * j] = __uint_as_float(d[j] << 16);
    v[2 * j + 1] = __uint_as_float(d[j] & 0xffff0000u);
  }
  float m = v[0];
#pragma unroll
  for (int i = 1; i < 16; i++) m = fmaxf(m, v[i]);
  for (int off = 32; off; off >>= 1) m = fmaxf(m, __shfl_xor(m, off));
  __shared__ float sm1[4], sm2[4];
  if (lane == 0) sm1[wave] = m;
  __syncthreads();
  m = fmaxf(fmaxf(sm1[0], sm1[1]), fmaxf(sm1[2], sm1[3]));
  float s = 0.f;
#pragma unroll
  for (int i = 0; i < 16; i++) { v[i] = __expf(v[i] - m); s += v[i]; }
  for (int off = 32; off; off >>= 1) s += __shfl_xor(s, off);
  if (lane == 0) sm2[wave] = s;
  __syncthreads();
  s = sm2[0] + sm2[1] + sm2[2] + sm2[3];
  const float inv = 1.f / s;
#pragma unroll
  for (int j = 0; j < 8; j++) {
    u32 lo = f2bfu(v[2 * j] * inv);
    u32 hi = f2bfu(v[2 * j + 1] * inv);
    d[j] = lo | (hi << 16);
  }
  ((u32x4*)x)[tid * 2] = *(u32x4*)&d[0];
  ((u32x4*)x)[tid * 2 + 1] = *(u32x4*)&d[4];
}

// ---------------------------------------------------------------- layernorm (rows of 768)
__global__ __launch_bounds__(256) void ln_rows(const float* in, const float* g, const float* b,
                                               float* outf, bf16* outb,
                                               const float* qc, float* qf, bf16* qb16) {
  const long row = blockIdx.x;
  const float* x = in + row * 768;
  const int tid = threadIdx.x;
  const int lane = tid & 63, wave = tid >> 6;
  float v0 = x[tid], v1 = x[tid + 256], v2 = x[tid + 512];
  float s = v0 + v1 + v2;
  float s2 = v0 * v0 + v1 * v1 + v2 * v2;
  for (int off = 32; off; off >>= 1) { s += __shfl_xor(s, off); s2 += __shfl_xor(s2, off); }
  __shared__ float sa[4], sb[4];
  if (lane == 0) { sa[wave] = s; sb[wave] = s2; }
  __syncthreads();
  s = sa[0] + sa[1] + sa[2] + sa[3];
  s2 = sb[0] + sb[1] + sb[2] + sb[3];
  const float mean = s * (1.f / 768.f);
  const float var = s2 * (1.f / 768.f) - mean * mean;
  const float rs = rsqrtf(var + 1e-5f);
  float o0 = (v0 - mean) * rs * g[tid] + b[tid];
  float o1 = (v1 - mean) * rs * g[tid + 256] + b[tid + 256];
  float o2 = (v2 - mean) * rs * g[tid + 512] + b[tid + 512];
  if (outf) { float* of = outf + row * 768; of[tid] = o0; of[tid + 256] = o1; of[tid + 512] = o2; }
  if (outb) { bf16* ob = outb + row * 768; ob[tid] = f2bf(o0); ob[tid + 256] = f2bf(o1); ob[tid + 512] = f2bf(o2); }
  if (qc) {
    const float* qr = qc + (row & 63) * 768;
    float u0 = o0 + qr[tid], u1 = o1 + qr[tid + 256], u2 = o2 + qr[tid + 512];
    float* pf = qf + row * 768;
    pf[tid] = u0; pf[tid + 256] = u1; pf[tid + 512] = u2;
    bf16* pb = qb16 + row * 768;
    pb[tid] = f2bf(u0); pb[tid + 256] = f2bf(u1); pb[tid + 512] = f2bf(u2);
  }
}

// ---------------------------------------------------------------- combine split-K partials
struct CombP { const float* in; int nch; const float* bias; const float* res;
               float* outf; bf16* outb; const float* qc; float* qf; bf16* qb16; };

__global__ __launch_bounds__(256) void combine(CombP p) {
  const long i = (long)blockIdx.x * 256 + threadIdx.x;  // n = 393216
  float s = 0.f;
  for (int c = 0; c < p.nch; c++) s += p.in[(long)c * 393216 + i];
  if (p.bias) s += p.bias[i % 768];
  if (p.res) s += p.res[i];
  if (p.outf) p.outf[i] = s;
  if (p.outb) p.outb[i] = f2bf(s);
  if (p.qc) {
    float v = s + p.qc[i % 49152];
    p.qf[i] = v;
    p.qb16[i] = f2bf(v);
  }
}

// ================================================================ launcher
extern "C" void kernel_launch(void* const* d_in, const int* in_sizes, int n_in,
                              void* d_out, int out_size, void* d_ws, size_t ws_size,
                              hipStream_t stream) {
  (void)in_sizes; (void)n_in; (void)out_size; (void)ws_size;
  const float* tokens   = (const float*)d_in[0];
  const float* selector = (const float*)d_in[1];
  const float* qc  = (const float*)d_in[2];
  const float* qw  = (const float*)d_in[3];
  const float* qb  = (const float*)d_in[4];
  const float* kw  = (const float*)d_in[5];
  const float* kb  = (const float*)d_in[6];
  const float* vw  = (const float*)d_in[7];
  const float* vb  = (const float*)d_in[8];
  const float* hw  = (const float*)d_in[9];
  const float* hb  = (const float*)d_in[10];
  const float* ow  = (const float*)d_in[11];
  const float* ob  = (const float*)d_in[12];
  const float* w1  = (const float*)d_in[13];
  const float* b1  = (const float*)d_in[14];
  const float* w2  = (const float*)d_in[15];
  const float* b2  = (const float*)d_in[16];
  const float* g1  = (const float*)d_in[17];
  const float* be1 = (const float*)d_in[18];
  const float* g2  = (const float*)d_in[19];
  const float* be2 = (const float*)d_in[20];
  float* out = (float*)d_out;

  char* ws = (char*)d_ws;
  size_t off = 0;
  auto alloc = [&](size_t bytes) { char* pp = ws + off; off += (bytes + 255) & ~(size_t)255; return pp; };
  bf16* TOKT  = (bf16*)alloc(50331648);   // tokens^T [B,D,N]
  bf16* TOKB  = (bf16*)alloc(50331648);   // tokens bf16 [B,N,D]
  bf16* KBUF  = (bf16*)alloc(50331648);   // k [B,N,H,HD]
  bf16* VTB   = (bf16*)alloc(50331648);   // v^T [B,768,N]
  bf16* PLOG  = (bf16*)alloc(4194304);    // pooling logits [B,M,N]
  bf16* SELB  = (bf16*)alloc(98304);      // selector bf16 [M,D]
  bf16* QWT   = (bf16*)alloc(4718592);    // [L,H,HD,D]
  bf16* KWT   = (bf16*)alloc(4718592);
  bf16* VWT   = (bf16*)alloc(4718592);
  bf16* HWT   = (bf16*)alloc(393216);     // [L,H,HD,HD]
  bf16* OWT   = (bf16*)alloc(4718592);    // [L,D,D]
  bf16* W1T   = (bf16*)alloc(18874368);   // [L,3072,768]
  bf16* W2T   = (bf16*)alloc(18874368);   // [L,768,3072]
  bf16* QBUF  = (bf16*)alloc(786432);     // q [B,M,H,HD]
  bf16* OBUF  = (bf16*)alloc(786432);     // attn out [B,H,M,HD]
  bf16* O2BUF = (bf16*)alloc(786432);     // head-mixed concat [B*M,768]
  float* QF   = (float*)alloc(1572864);   // queries f32
  bf16* QB16  = (bf16*)alloc(786432);     // queries bf16
  float* T1   = (float*)alloc(1572864);
  float* X1F  = (float*)alloc(1572864);
  bf16* X1B   = (bf16*)alloc(786432);
  bf16* H1    = (bf16*)alloc(3145728);    // gelu(mlp1) [512,3072]
  float* T2   = (float*)alloc(1572864);
  float* OPART = (float*)alloc(12582912); // split-K partials / flash O-partials
  float* MLB  = (float*)alloc(393216);    // flash (m,l) [8][96][2][64]

  auto tr = [&](const float* in, bf16* o, bf16* oR, int R, int C, long s, long sR, int slabs) {
    TrP t{in, o, oR, R, C, s, s, sR};
    transpose_f2b<<<dim3(C / 64, R / 64, slabs), 256, 0, stream>>>(t);
  };
  tr(tokens, TOKT, TOKB, 4096, 768, 3145728, 3145728, 8);
  cvt_f2b<<<24, 256, 0, stream>>>(selector, SELB, 49152);
  tr(qw, QWT, nullptr, 768, 64, 49152, 0, 48);
  tr(kw, KWT, nullptr, 768, 64, 49152, 0, 48);
  tr(vw, VWT, nullptr, 768, 64, 49152, 0, 48);
  tr(hw, HWT, nullptr, 64, 64, 4096, 0, 48);
  tr(ow, OWT, nullptr, 768, 768, 589824, 0, 4);
  tr(w1, W1T, nullptr, 768, 3072, 2359296, 0, 4);
  tr(w2, W2T, nullptr, 3072, 768, 2359296, 0, 4);

  // ---- pooling
  {
    GemmSmP p{}; p.A = SELB; p.B = TOKB; p.C = PLOG;
    p.sB1 = 3145728; p.sC1 = 262144; p.nb2 = 1;
    p.lda = 768; p.ldb = 768; p.ldc = 4096; p.K = 768;
    p.bias_mode = 0; p.out_mode = 1; p.scale = 1.0f;
    gemm_sm<<<dim3(64, 1, 8), 256, 0, stream>>>(p);
  }
  softmax_rows<<<512, 256, 0, stream>>>(PLOG);
  { // x partials = P · tokens (split-K 8 over N)
    GemmSmP p{}; p.A = PLOG; p.B = TOKT; p.C = OPART;
    p.sA1 = 512; p.sA2 = 262144; p.sB1 = 512; p.sB2 = 3145728;
    p.sC1 = 393216; p.sC2 = 49152; p.nb2 = 8;
    p.lda = 4096; p.ldb = 4096; p.ldc = 768; p.K = 512;
    p.bias_mode = 0; p.out_mode = 0; p.scale = 1.0f;
    gemm_sm<<<dim3(12, 1, 64), 256, 0, stream>>>(p);
  }
  { // x -> queries(l=0) = x + qc[0]
    CombP c{}; c.in = OPART; c.nch = 8; c.qc = qc; c.qf = QF; c.qb16 = QB16;
    combine<<<1536, 256, 0, stream>>>(c);
  }

  for (int l = 0; l < 4; l++) {
    { // q = queries · qw^T + qb  -> [B,M,H,HD] bf16
      GemmSmP p{}; p.A = QB16; p.B = QWT + l * 589824; p.C = QBUF; p.bias = qb + l * 768;
      p.nb2 = 1; p.lda = 768; p.ldb = 768; p.ldc = 768; p.K = 768;
      p.bias_mode = 1; p.out_mode = 1; p.scale = 1.0f;
      gemm_sm<<<dim3(12, 8, 1), 256, 0, stream>>>(p);
    }
    { // fused k,v projection
      GemmKVP p{TOKB, KWT + l * 589824, VWT + l * 589824, KBUF, VTB,
                kb + l * 768, vb + l * 768};
      gemm_kv<<<dim3(6, 256, 1), 256, 0, stream>>>(p);
    }
    { // flash attention partials + merge
      AttnP p{QBUF, KBUF, VTB, OPART, MLB};
      attn_part<<<dim3(96, 8, 1), 256, 0, stream>>>(p);
      AttnC c{OPART, MLB, OBUF};
      attn_comb<<<1536, 256, 0, stream>>>(c);
    }
    { // head-mix   z = b*12+h
      GemmSmP p{}; p.A = OBUF; p.B = HWT + l * 49152; p.C = O2BUF; p.bias = hb + l * 768;
      p.sA1 = 49152; p.sA2 = 4096; p.sB1 = 0; p.sB2 = 4096; p.sC1 = 49152; p.sC2 = 64; p.sBias2 = 64;
      p.nb2 = 12; p.lda = 64; p.ldb = 64; p.ldc = 768; p.K = 64;
      p.bias_mode = 1; p.out_mode = 1; p.scale = 1.0f;
      gemm_sm<<<dim3(1, 1, 96), 256, 0, stream>>>(p);
    }
    { // o-proj partials (split-K 4): o2 · ow^T
      GemmSmP p{}; p.A = O2BUF; p.B = OWT + l * 589824; p.C = OPART;
      p.sA1 = 192; p.sB1 = 192; p.sC1 = 393216; p.nb2 = 1;
      p.lda = 768; p.ldb = 768; p.ldc = 768; p.K = 192;
      p.bias_mode = 0; p.out_mode = 0; p.scale = 1.0f;
      gemm_sm<<<dim3(12, 8, 4), 256, 0, stream>>>(p);
    }
    { CombP c{}; c.in = OPART; c.nch = 4; c.bias = ob + l * 768; c.res = QF; c.outf = T1;
      combine<<<1536, 256, 0, stream>>>(c); }
    ln_rows<<<512, 256, 0, stream>>>(T1, g1 + l * 768, be1 + l * 768, X1F, X1B, nullptr, nullptr, nullptr);
    { // mlp1 = gelu(x1 · w1^T + b1) bf16
      GemmSmP p{}; p.A = X1B; p.B = W1T + l * 2359296; p.C = H1; p.bias = b1 + l * 3072;
      p.nb2 = 1; p.lda = 768; p.ldb = 768; p.ldc = 3072; p.K = 768;
      p.bias_mode = 1; p.out_mode = 2; p.scale = 1.0f;
      gemm_sm<<<dim3(48, 8, 1), 256, 0, stream>>>(p);
    }
    { // mlp2 partials (split-K 8): h1 · w2^T
      GemmSmP p{}; p.A = H1; p.B = W2T + l * 2359296; p.C = OPART;
      p.sA1 = 384; p.sB1 = 384; p.sC1 = 393216; p.nb2 = 1;
      p.lda = 3072; p.ldb = 3072; p.ldc = 768; p.K = 384;
      p.bias_mode = 0; p.out_mode = 0; p.scale = 1.0f;
      gemm_sm<<<dim3(12, 8, 8), 256, 0, stream>>>(p);
    }
    { CombP c{}; c.in = OPART; c.nch = 8; c.bias = b2 + l * 768; c.res = X1F; c.outf = T2;
      combine<<<1536, 256, 0, stream>>>(c); }
    ln_rows<<<512, 256, 0, stream>>>(T2, g2 + l * 768, be2 + l * 768,
                                     (l == 3) ? out : nullptr, nullptr,
                                     (l < 3) ? (qc + (l + 1) * 49152) : nullptr, QF, QB16);
  }
}

// Round 4
// 1074.550 us; speedup vs baseline: 1.3640x; 1.0226x over previous
//
#include <hip/hip_runtime.h>
#include <hip/hip_bf16.h>

// VisualDecoder: B=8,N=4096,D=768,H=12,M=64,L=4,HD=64. In/out f32; compute bf16
// MFMA (f32 accum). R10: (1) gemm_kv asymmetric pipeline: A(tokens) 4 LDS slots
// (3 tiles in flight, covers HBM latency), K/V weights 3 slots; steady wait
// stays vmcnt(6). (2) attn_comb fused into head-mix (attn_hm). (3) combine+LN
// fused (comb_ln). Flash attention + T2 swizzles retained from R9.

using bf16 = __hip_bfloat16;
typedef __attribute__((ext_vector_type(8))) __bf16 bf16x8;
typedef __attribute__((ext_vector_type(4))) float f32x4;
typedef unsigned int u32;
typedef __attribute__((ext_vector_type(4))) u32 u32x4;

#define DEVINL __device__ __forceinline__

DEVINL float bf2f(bf16 v) { return __bfloat162float(v); }
DEVINL bf16 f2bf(float v) { return __float2bfloat16(v); }
DEVINL u32 f2bfu(float f) { bf16 h = __float2bfloat16(f); return *(unsigned short*)&h; }
DEVINL float gelu_f(float x) { return 0.5f * x * (1.0f + erff(x * 0.70710678118654752f)); }

// async global->LDS, 16B per lane. LDS dest = wave-uniform base + lane*16 (ours is).
DEVINL void async16(const bf16* g, bf16* l) {
  __builtin_amdgcn_global_load_lds(
      (const __attribute__((address_space(1))) u32*)g,
      (__attribute__((address_space(3))) u32*)l, 16, 0, 0);
}

// XCD-chunked bijective block-id swizzle (m204).
DEVINL u32 xcd_swizzle(u32 id, u32 nwg) {
  u32 q = nwg >> 3, r = nwg & 7;
  u32 xcd = id & 7, pos = id >> 3;
  return xcd * q + (xcd < r ? xcd : r) + pos;
}

// ---------------------------------------------------------------- flat f32 -> bf16
__global__ __launch_bounds__(256) void cvt_f2b(const float* in, bf16* out, long n) {
  const long i = ((long)blockIdx.x * 256 + threadIdx.x) * 8;
  if (i >= n) return;
  float4 a = *(const float4*)(in + i);
  float4 b = *(const float4*)(in + i + 4);
  u32 w[4];
  w[0] = f2bfu(a.x) | (f2bfu(a.y) << 16);
  w[1] = f2bfu(a.z) | (f2bfu(a.w) << 16);
  w[2] = f2bfu(b.x) | (f2bfu(b.y) << 16);
  w[3] = f2bfu(b.z) | (f2bfu(b.w) << 16);
  *(u32x4*)(out + i) = *(u32x4*)w;
}

// ---------------------------------------------------------------- fused K+V projection
// 128x128 tile, BK=32. Asymmetric pipeline: A 4 slots (3 tiles in flight),
// K/V 3 slots (2 tiles). Per step: wait vmcnt(6) [tail 4,0], barrier, issue
// A(k+3), KV(k+2). LDS 80KB -> 2 blocks/CU. T2 16B-slot read swizzle.
// K written direct; V^T written via LDS transpose tile -> coalesced stores.
struct GemmKVP {
  const bf16* A;      // TOKB [32768,768]
  const bf16* Bk;     // KWT layer [768,768]
  const bf16* Bv;     // VWT layer [768,768]
  bf16* Ck;           // KBUF
  bf16* Cv;           // VTB
  const float* biask; // kb[768]
  const float* biasv; // vb[768]
};

__global__ __launch_bounds__(256, 2) void gemm_kv(GemmKVP p) {
  __shared__ __align__(16) bf16 SH[40960];  // 80KB: As[4] | Ks[3] | Vs[3] of 4096
  bf16* As = SH;
  bf16* Ks = SH + 16384;
  bf16* Vs = SH + 28672;
  const int tid = threadIdx.x;
  const int wave = tid >> 6, lane = tid & 63;

  u32 id = blockIdx.x + 6u * blockIdx.y;     // grid (6, 256)
  id = xcd_swizzle(id, 1536);
  const int bn = id % 6;
  const int bm = id / 6;

  const bf16* Ag = p.A + (long)bm * 128 * 768;
  const bf16* Kg = p.Bk + (long)bn * 128 * 768;
  const bf16* Vg = p.Bv + (long)bn * 128 * 768;

  // staging: thread stages LDS slots {tid, tid+256}; slot sl -> row sl>>2,
  // swizzled col chunk qc = (sl&3) ^ ((sl>>3)&3)  (same for sl and sl+256).
  const int cq = (((tid & 3) ^ ((tid >> 3) & 3))) * 8;
  const long ro = (long)(tid >> 2) * 768 + cq;
  const long r1 = ro + (long)64 * 768;
  const bf16* ga0 = Ag + ro; const bf16* ga1 = Ag + r1;
  const bf16* gk0 = Kg + ro; const bf16* gk1 = Kg + r1;
  const bf16* gv0 = Vg + ro; const bf16* gv1 = Vg + r1;

  const int m_in = lane & 15, q = lane >> 4;
  const int wm = (wave & 1) * 64, wn = (wave >> 1) * 64;
  const int sw3 = (q ^ ((m_in >> 1) & 3)) << 3;  // read slot offset (elems)
  f32x4 acck[4][4] = {};
  f32x4 accv[4][4] = {};
  const int nk = 24;  // K=768

  auto stageA = [&](int s, int ko) {
    async16(ga0 + ko, As + s * 4096 + tid * 8);
    async16(ga1 + ko, As + s * 4096 + 2048 + tid * 8);
  };
  auto stageKV = [&](int s, int ko) {
    async16(gk0 + ko, Ks + s * 4096 + tid * 8);
    async16(gk1 + ko, Ks + s * 4096 + 2048 + tid * 8);
    async16(gv0 + ko, Vs + s * 4096 + tid * 8);
    async16(gv1 + ko, Vs + s * 4096 + 2048 + tid * 8);
  };
  // prologue queue (14 loads): A0 A1 KV0 A2 KV1
  stageA(0, 0); stageA(1, 32); stageKV(0, 0); stageA(2, 64); stageKV(1, 32);

  for (int k = 0; k < nk; ++k) {
    // steady: retire A(k),A(k+1),KV(k); keep A(k+2):2 + KV(k+1):4 in flight
    if (k < nk - 2)       asm volatile("s_waitcnt vmcnt(6)" ::: "memory");
    else if (k == nk - 2) asm volatile("s_waitcnt vmcnt(4)" ::: "memory");
    else                  asm volatile("s_waitcnt vmcnt(0)" ::: "memory");
    __builtin_amdgcn_s_barrier();
    if (k + 3 < nk) stageA((k + 3) & 3, (k + 3) * 32);
    if (k + 2 < nk) stageKV((k + 2) % 3, (k + 2) * 32);
    const bf16* Ac = As + (k & 3) * 4096;
    const bf16* Kc = Ks + (k % 3) * 4096;
    const bf16* Vc = Vs + (k % 3) * 4096;
    bf16x8 af[4], bfr[4];
#pragma unroll
    for (int i = 0; i < 4; i++)
      af[i] = *(const bf16x8*)(Ac + (wm + i * 16 + m_in) * 32 + sw3);
#pragma unroll
    for (int j = 0; j < 4; j++)
      bfr[j] = *(const bf16x8*)(Kc + (wn + j * 16 + m_in) * 32 + sw3);
#pragma unroll
    for (int i = 0; i < 4; i++)
#pragma unroll
      for (int j = 0; j < 4; j++)
        acck[i][j] = __builtin_amdgcn_mfma_f32_16x16x32_bf16(af[i], bfr[j], acck[i][j], 0, 0, 0);
#pragma unroll
    for (int j = 0; j < 4; j++)
      bfr[j] = *(const bf16x8*)(Vc + (wn + j * 16 + m_in) * 32 + sw3);
#pragma unroll
    for (int i = 0; i < 4; i++)
#pragma unroll
      for (int j = 0; j < 4; j++)
        accv[i][j] = __builtin_amdgcn_mfma_f32_16x16x32_bf16(af[i], bfr[j], accv[i][j], 0, 0, 0);
  }

  const long row0 = (long)bm * 128 + wm + q * 4;
  const long col0 = (long)bn * 128 + wn + m_in;
  const int bb = (bm * 128) >> 12;
  const int nn0 = (bm * 128) & 4095;
  // ---- K: direct stores
#pragma unroll
  for (int i = 0; i < 4; i++)
#pragma unroll
    for (int j = 0; j < 4; j++) {
      long r = row0 + i * 16;
      long c = col0 + j * 16;
      float bk_ = p.biask[c];
#pragma unroll
      for (int t = 0; t < 4; t++)
        p.Ck[(r + t) * 768 + c] = f2bf(acck[i][j][t] + bk_);
    }
  // ---- V: transpose via LDS, coalesced store
  __syncthreads();  // drain all waves' K-loop LDS reads before reuse
  bf16* VT = SH;    // [128 e][128 n], 16B slots swizzled: phys = slot ^ (e&15)
#pragma unroll
  for (int i = 0; i < 4; i++) {
    const int nb = wm + q * 4 + i * 16;  // n_local base (t in 0..3)
    const int sl = nb >> 3;
    const int of = nb & 7;
#pragma unroll
    for (int j = 0; j < 4; j++) {
      const int e = wn + j * 16 + m_in;
      const float bv_ = p.biasv[bn * 128 + e];
      u32 w0 = f2bfu(accv[i][j][0] + bv_) | (f2bfu(accv[i][j][1] + bv_) << 16);
      u32 w1 = f2bfu(accv[i][j][2] + bv_) | (f2bfu(accv[i][j][3] + bv_) << 16);
      uint2 pk; pk.x = w0; pk.y = w1;
      *(uint2*)(VT + e * 128 + ((sl ^ (e & 15)) << 3) + of) = pk;
    }
  }
  __syncthreads();
  bf16* CvB = p.Cv + (long)bb * 3145728;
#pragma unroll
  for (int k2 = 0; k2 < 8; k2++) {
    int g = tid + k2 * 256;
    int e = g >> 4, sc = g & 15;
    u32x4 vv = *(const u32x4*)(VT + e * 128 + ((sc ^ (e & 15)) << 3));
    *(u32x4*)(CvB + (long)(bn * 128 + e) * 4096 + nn0 + sc * 8) = vv;
  }
}

// ---------------------------------------------------------------- small GEMM
// 64x64 tile, BK=32, 3-slot counted-vmcnt pipeline, 2-level batch, XCD swizzle,
// T2 read-swizzle (pre-swizzled source + XOR'd read slot).
struct GemmSmP {
  const bf16* A; const bf16* B; void* C; const float* bias; const float* res;
  long sA1, sA2, sB1, sB2, sC1, sC2, sBias2;
  int nb2, lda, ldb, ldc, K;
  int bias_mode;  // 0 none, 1 per-col
  int out_mode;   // 0 f32 (+res), 1 bf16, 2 gelu->bf16
  float scale;
};

__global__ __launch_bounds__(256, 4) void gemm_sm(GemmSmP p) {
  __shared__ __align__(16) bf16 As[3][64 * 32];
  __shared__ __align__(16) bf16 Bs[3][64 * 32];
  const int tid = threadIdx.x;
  const int wave = tid >> 6, lane = tid & 63;

  const u32 gx = gridDim.x, gy = gridDim.y;
  u32 id = blockIdx.x + gx * (blockIdx.y + gy * blockIdx.z);
  id = xcd_swizzle(id, gx * gy * gridDim.z);
  const int bn = id % gx;
  const u32 t2 = id / gx;
  const int bm = t2 % gy;
  const int bz = t2 / gy;

  const int z1 = bz / p.nb2, z2 = bz - z1 * p.nb2;
  const bf16* Ag = p.A + p.sA1 * z1 + p.sA2 * z2 + (long)bm * 64 * p.lda;
  const bf16* Bg = p.B + p.sB1 * z1 + p.sB2 * z2 + (long)bn * 64 * p.ldb;

  const int cq = (((tid & 3) ^ ((tid >> 3) & 3))) * 8;
  const bf16* gpa = Ag + ((long)(tid >> 2) * p.lda + cq);
  const bf16* gpb = Bg + ((long)(tid >> 2) * p.ldb + cq);

  const int m_in = lane & 15, q = lane >> 4;
  const int wm = (wave & 1) * 32, wn = (wave >> 1) * 32;
  const int sw3 = (q ^ ((m_in >> 1) & 3)) << 3;
  f32x4 acc[2][2] = {};
  const int nk = p.K >> 5;

  async16(gpa, &As[0][0] + tid * 8);
  async16(gpb, &Bs[0][0] + tid * 8);
  if (nk > 1) {
    async16(gpa + 32, &As[1][0] + tid * 8);
    async16(gpb + 32, &Bs[1][0] + tid * 8);
  }

  int slot = 0;
  for (int k = 0; k < nk; ++k) {
    if (k + 1 < nk) asm volatile("s_waitcnt vmcnt(2)" ::: "memory");
    else            asm volatile("s_waitcnt vmcnt(0)" ::: "memory");
    __builtin_amdgcn_s_barrier();
    if (k + 2 < nk) {
      int ns = slot + 2; if (ns >= 3) ns -= 3;
      const int ko = (k + 2) * 32;
      async16(gpa + ko, &As[ns][0] + tid * 8);
      async16(gpb + ko, &Bs[ns][0] + tid * 8);
    }
    const bf16* Ac = &As[slot][0];
    const bf16* Bc = &Bs[slot][0];
    bf16x8 a0 = *(const bf16x8*)(Ac + (wm + m_in) * 32 + sw3);
    bf16x8 a1 = *(const bf16x8*)(Ac + (wm + 16 + m_in) * 32 + sw3);
    bf16x8 b0 = *(const bf16x8*)(Bc + (wn + m_in) * 32 + sw3);
    bf16x8 b1 = *(const bf16x8*)(Bc + (wn + 16 + m_in) * 32 + sw3);
    acc[0][0] = __builtin_amdgcn_mfma_f32_16x16x32_bf16(a0, b0, acc[0][0], 0, 0, 0);
    acc[0][1] = __builtin_amdgcn_mfma_f32_16x16x32_bf16(a0, b1, acc[0][1], 0, 0, 0);
    acc[1][0] = __builtin_amdgcn_mfma_f32_16x16x32_bf16(a1, b0, acc[1][0], 0, 0, 0);
    acc[1][1] = __builtin_amdgcn_mfma_f32_16x16x32_bf16(a1, b1, acc[1][1], 0, 0, 0);
    slot = (slot + 1 == 3) ? 0 : slot + 1;
  }

  const long row0 = (long)bm * 64 + wm + q * 4;
  const long col0 = (long)bn * 64 + wn + m_in;
  const float* bias = p.bias + p.sBias2 * z2;
#pragma unroll
  for (int i = 0; i < 2; i++)
#pragma unroll
    for (int j = 0; j < 2; j++) {
      long r = row0 + i * 16;
      long cc = col0 + j * 16;
      float badd = (p.bias_mode == 1) ? bias[cc] : 0.f;
#pragma unroll
      for (int t = 0; t < 4; t++) {
        float v = acc[i][j][t] * p.scale + badd;
        long idx = (r + t) * p.ldc + cc;
        if (p.out_mode == 0) {
          float* Cf = (float*)p.C + p.sC1 * z1 + p.sC2 * z2;
          if (p.res) v += p.res[idx];
          Cf[idx] = v;
        } else {
          bf16* Cb = (bf16*)p.C + p.sC1 * z1 + p.sC2 * z2;
          if (p.out_mode == 2) v = gelu_f(v);
          Cb[idx] = f2bf(v);
        }
      }
    }
}

// ---------------------------------------------------------------- flash attention partial
// Block = (z=b*12+h, chunk c of 512 n). 4 waves x 16 q-rows. Online softmax per
// chunk; per-chunk (m,l) + O-partial to global; attn_hm merges 8 chunks.
struct AttnP {
  const bf16* Q;   // QBUF [B*M,768], head at h*64
  const bf16* K;   // KBUF [B*N,768], head at h*64
  const bf16* VT;  // VTB [B][768][4096], rows h*64+e
  float* Opart;    // [8][96][64][64]
  float* ML;       // [8][96][2][64]
};

__global__ __launch_bounds__(256, 3) void attn_part(AttnP p) {
  __shared__ __align__(16) bf16 SH[24576];
  bf16* Qs = SH;             // [64][64] swz (16B slots XOR row&7)
  bf16* Ks = SH + 4096;      // 2 bufs of [64][64]
  bf16* Vs = SH + 12288;     // 2 bufs of [64][64]
  bf16* Ps = SH + 20480;     // [64][64] swz
  const int tid = threadIdx.x;
  const int wave = tid >> 6, lane = tid & 63;
  const int z = blockIdx.x, c = blockIdx.y;
  const int b = z / 12, h = z - b * 12;
  const int n0 = c * 512;

  // staging: slot sl -> row sl>>3, phys col chunk qc = (sl&7) ^ (row&7)
  const int sl0 = tid, sl1 = tid + 256;
  const int r0 = sl0 >> 3, r1 = sl1 >> 3;
  const int q0 = (sl0 & 7) ^ (r0 & 7), q1 = (sl1 & 7) ^ (r1 & 7);

  const bf16* Qg = p.Q + ((long)b * 64) * 768 + h * 64;
  const bf16* Kg = p.K + ((long)b * 4096 + n0) * 768 + h * 64;
  const bf16* Vg = p.VT + (long)b * 3145728 + (long)(h * 64) * 4096 + n0;

  async16(Qg + (long)r0 * 768 + q0 * 8, Qs + sl0 * 8);
  async16(Qg + (long)r1 * 768 + q1 * 8, Qs + sl1 * 8);
  auto stageK = [&](int s) {
    bf16* d = Ks + (s & 1) * 4096;
    async16(Kg + (long)(s * 64 + r0) * 768 + q0 * 8, d + sl0 * 8);
    async16(Kg + (long)(s * 64 + r1) * 768 + q1 * 8, d + sl1 * 8);
  };
  auto stageV = [&](int s) {
    bf16* d = Vs + (s & 1) * 4096;
    async16(Vg + (long)r0 * 4096 + s * 64 + q0 * 8, d + sl0 * 8);
    async16(Vg + (long)r1 * 4096 + s * 64 + q1 * 8, d + sl1 * 8);
  };
  stageK(0); stageV(0); stageK(1); stageV(1);

  const int m_in = lane & 15, q = lane >> 4;
  const int wm = wave * 16;

  asm volatile("s_waitcnt vmcnt(8)" ::: "memory");  // Q landed
  __builtin_amdgcn_s_barrier();

  bf16x8 qa[2];
  {
    const int ra = wm + m_in;
#pragma unroll
    for (int kk = 0; kk < 2; kk++)
      qa[kk] = *(const bf16x8*)(Qs + ra * 64 + ((((kk * 4 + q) ^ (ra & 7))) << 3));
  }

  f32x4 accO[4] = {};
  float m_run[4] = {-1e30f, -1e30f, -1e30f, -1e30f};
  float l_run[4] = {0.f, 0.f, 0.f, 0.f};

  for (int s = 0; s < 8; ++s) {
    if (s < 7) asm volatile("s_waitcnt vmcnt(4)" ::: "memory");
    else       asm volatile("s_waitcnt vmcnt(0)" ::: "memory");
    __builtin_amdgcn_s_barrier();
    const bf16* Kc = Ks + (s & 1) * 4096;
    const bf16* Vc = Vs + (s & 1) * 4096;
    // S = Q . K^T  (rows m = wm+q*4+t, cols n = m_in+16j)
    f32x4 accS[4] = {};
#pragma unroll
    for (int kk = 0; kk < 2; kk++) {
#pragma unroll
      for (int j = 0; j < 4; j++) {
        const int rj = j * 16 + m_in;
        bf16x8 kb = *(const bf16x8*)(Kc + rj * 64 + ((((kk * 4 + q) ^ (rj & 7))) << 3));
        accS[j] = __builtin_amdgcn_mfma_f32_16x16x32_bf16(qa[kk], kb, accS[j], 0, 0, 0);
      }
    }
    // online softmax partial (scale 0.125)
    float pe[4][4], osc[4];
#pragma unroll
    for (int t = 0; t < 4; t++) {
      float mx = fmaxf(fmaxf(accS[0][t], accS[1][t]), fmaxf(accS[2][t], accS[3][t])) * 0.125f;
      mx = fmaxf(mx, __shfl_xor(mx, 1));
      mx = fmaxf(mx, __shfl_xor(mx, 2));
      mx = fmaxf(mx, __shfl_xor(mx, 4));
      mx = fmaxf(mx, __shfl_xor(mx, 8));
      const float mnew = fmaxf(m_run[t], mx);
      const float so = __expf(m_run[t] - mnew);
      float rs = 0.f;
#pragma unroll
      for (int j = 0; j < 4; j++) {
        float e = __expf(accS[j][t] * 0.125f - mnew);
        pe[j][t] = e; rs += e;
      }
      rs += __shfl_xor(rs, 1); rs += __shfl_xor(rs, 2);
      rs += __shfl_xor(rs, 4); rs += __shfl_xor(rs, 8);
      l_run[t] = l_run[t] * so + rs;
      m_run[t] = mnew;
      osc[t] = so;
    }
#pragma unroll
    for (int ef = 0; ef < 4; ef++)
#pragma unroll
      for (int t = 0; t < 4; t++) accO[ef][t] *= osc[t];
    // P -> LDS (wave-private rows), swizzled slots
#pragma unroll
    for (int j = 0; j < 4; j++) {
      const int pc = m_in + 16 * j;
#pragma unroll
      for (int t = 0; t < 4; t++) {
        const int pm = wm + q * 4 + t;
        Ps[pm * 64 + (((pc >> 3) ^ (pm & 7)) << 3) + (pc & 7)] = f2bf(pe[j][t]);
      }
    }
    // O += P . V  (B = V^T rows e)
    const int ra = wm + m_in;
#pragma unroll
    for (int kk = 0; kk < 2; kk++) {
      bf16x8 pa = *(const bf16x8*)(Ps + ra * 64 + ((((kk * 4 + q) ^ (ra & 7))) << 3));
#pragma unroll
      for (int ef = 0; ef < 4; ef++) {
        const int rv = ef * 16 + m_in;
        bf16x8 vb = *(const bf16x8*)(Vc + rv * 64 + ((((kk * 4 + q) ^ (rv & 7))) << 3));
        accO[ef] = __builtin_amdgcn_mfma_f32_16x16x32_bf16(pa, vb, accO[ef], 0, 0, 0);
      }
    }
    __builtin_amdgcn_s_barrier();  // all waves done with K(s)/V(s) buffers
    if (s < 6) { stageK(s + 2); stageV(s + 2); }
  }

  float* Og = p.Opart + ((long)c * 96 + z) * 4096;
#pragma unroll
  for (int ef = 0; ef < 4; ef++)
#pragma unroll
    for (int t = 0; t < 4; t++)
      Og[(wm + q * 4 + t) * 64 + ef * 16 + m_in] = accO[ef][t];
  if (m_in == 0) {
    float* ml = p.ML + ((long)c * 96 + z) * 128;
#pragma unroll
    for (int t = 0; t < 4; t++) {
      ml[wm + q * 4 + t] = m_run[t];
      ml[64 + wm + q * 4 + t] = l_run[t];
    }
  }
}

// ---------------------------------------------------------------- fused chunk-merge + head-mix
// Block z=b*12+h: O[64,64] = (sum_c w_c Opart_c)/(sum_c w_c l_c), then
// O2[m, h*64+e2] = sum_e O[m][e] * HWT[h][e2][e] + hb[h*64+e2].
struct AttnHMP {
  const float* Opart;  // [8][96][64][64]
  const float* ML;     // [8][96][2][64]
  const bf16* HWT;     // layer base [12][64][64] (rows e2, cols e)
  const float* hb;     // layer base [768]
  bf16* O2;            // [512][768]
};

__global__ __launch_bounds__(256) void attn_hm(AttnHMP p) {
  __shared__ __align__(16) bf16 Os[4096];  // [64 m][64 e], 16B slots XOR (m&7)
  __shared__ __align__(16) bf16 Hs[4096];  // [64 e2][64 e], swizzled
  const int tid = threadIdx.x;
  const int z = blockIdx.x;
  const int b = z / 12, h = z - b * 12;

  // stage H (swizzled like attn staging)
  const int sl0 = tid, sl1 = tid + 256;
  const int r0 = sl0 >> 3, r1 = sl1 >> 3;
  const int q0 = (sl0 & 7) ^ (r0 & 7), q1 = (sl1 & 7) ^ (r1 & 7);
  const bf16* Hg = p.HWT + h * 4096;
  async16(Hg + r0 * 64 + q0 * 8, Hs + sl0 * 8);
  async16(Hg + r1 * 64 + q1 * 8, Hs + sl1 * 8);

  // combine 8 chunk partials: thread owns row m = tid>>2, cols e0..e0+15
  const int m = tid >> 2, e0 = (tid & 3) * 16;
  float mv[8];
  float mx = -1e30f;
#pragma unroll
  for (int c = 0; c < 8; c++) {
    mv[c] = p.ML[((long)c * 96 + z) * 128 + m];
    mx = fmaxf(mx, mv[c]);
  }
  float l = 0.f;
  float o[16] = {};
#pragma unroll
  for (int c = 0; c < 8; c++) {
    const float w = __expf(mv[c] - mx);
    l += w * p.ML[((long)c * 96 + z) * 128 + 64 + m];
    const float* Og = p.Opart + (((long)c * 96 + z) * 64 + m) * 64 + e0;
#pragma unroll
    for (int e = 0; e < 16; e++) o[e] += w * Og[e];
  }
  const float inv = 1.f / l;
#pragma unroll
  for (int half = 0; half < 2; half++) {
    u32 wbuf[4];
#pragma unroll
    for (int j = 0; j < 4; j++)
      wbuf[j] = f2bfu(o[half * 8 + 2 * j] * inv) | (f2bfu(o[half * 8 + 2 * j + 1] * inv) << 16);
    const int sl = (e0 >> 3) + half;
    *(u32x4*)(Os + m * 64 + ((sl ^ (m & 7)) << 3)) = *(u32x4*)wbuf;
  }
  asm volatile("s_waitcnt vmcnt(0)" ::: "memory");
  __syncthreads();

  // GEMM 64x64 K=64
  const int wave = tid >> 6, lane = tid & 63;
  const int m_in = lane & 15, q = lane >> 4;
  const int wm = wave * 16;
  f32x4 acc[4] = {};
#pragma unroll
  for (int kk = 0; kk < 2; kk++) {
    const int ra = wm + m_in;
    bf16x8 a = *(const bf16x8*)(Os + ra * 64 + ((((kk * 4 + q) ^ (ra & 7))) << 3));
#pragma unroll
    for (int j = 0; j < 4; j++) {
      const int rb = j * 16 + m_in;
      bf16x8 bv = *(const bf16x8*)(Hs + rb * 64 + ((((kk * 4 + q) ^ (rb & 7))) << 3));
      acc[j] = __builtin_amdgcn_mfma_f32_16x16x32_bf16(a, bv, acc[j], 0, 0, 0);
    }
  }
  bf16* O2r = p.O2 + ((long)b * 64) * 768 + h * 64;
#pragma unroll
  for (int j = 0; j < 4; j++) {
    const int e2 = j * 16 + m_in;
    const float badd = p.hb[h * 64 + e2];
#pragma unroll
    for (int t = 0; t < 4; t++)
      O2r[(wm + q * 4 + t) * 768 + e2] = f2bf(acc[j][t] + badd);
  }
}

// ---------------------------------------------------------------- transpose (f32 -> bf16)
struct TrP { const float* in; bf16* out; bf16* outR; int R, C; long sIn, sOut, sOutR; };

__global__ __launch_bounds__(256) void transpose_f2b(TrP p) {
  __shared__ __align__(16) bf16 tile[64][80];
  const int tid = threadIdx.x;
  const int ct = blockIdx.x, rt = blockIdx.y, z = blockIdx.z;
  const float* in = p.in + p.sIn * z + ((long)rt * 64) * p.C + (long)ct * 64;
  bf16* out = p.out + p.sOut * z + ((long)ct * 64) * p.R + (long)rt * 64;
  bf16* outR = p.outR ? p.outR + p.sOutR * z + ((long)rt * 64) * p.C + (long)ct * 64 : nullptr;
  const int r = tid >> 3, c8 = (tid & 7) * 8;
#pragma unroll
  for (int h = 0; h < 2; h++) {
    int rr = r + h * 32;
    float4 a = *(const float4*)(in + (long)rr * p.C + c8);
    float4 b = *(const float4*)(in + (long)rr * p.C + c8 + 4);
    u32 w[4];
    w[0] = f2bfu(a.x) | (f2bfu(a.y) << 16);
    w[1] = f2bfu(a.z) | (f2bfu(a.w) << 16);
    w[2] = f2bfu(b.x) | (f2bfu(b.y) << 16);
    w[3] = f2bfu(b.z) | (f2bfu(b.w) << 16);
    *(u32x4*)&tile[rr][c8] = *(u32x4*)w;
    if (outR) *(u32x4*)(outR + (long)rr * p.C + c8) = *(u32x4*)w;
  }
  __syncthreads();
  const int co = tid >> 3, r8 = (tid & 7) * 8;
#pragma unroll
  for (int h = 0; h < 2; h++) {
    int cc = co + h * 32;
    __align__(16) bf16 tmp[8];
#pragma unroll
    for (int j = 0; j < 8; j++) tmp[j] = tile[r8 + j][cc];
    *(u32x4*)(out + (long)cc * p.R + r8) = *(const u32x4*)tmp;
  }
}

// ---------------------------------------------------------------- softmax (rows of 4096, in-place bf16)
__global__ __launch_bounds__(256) void softmax_rows(bf16* X) {
  const long row = blockIdx.x;
  u32* x = (u32*)(X + row * 4096);
  const int tid = threadIdx.x;
  const int lane = tid & 63, wave = tid >> 6;
  u32 d[8];
  *(u32x4*)&d[0] = ((const u32x4*)x)[tid * 2];
  *(u32x4*)&d[4] = ((const u32x4*)x)[tid * 2 + 1];
  float v[16];
#pragma unroll
  for (int j = 0; j < 8; j++) {
    v[2 * j] = __uint_as_float(d[j] << 16);
    v[2 * j + 1] = __uint_as_float(d[j] & 0xffff0000u);
  }
  float m = v[0];
#pragma unroll
  for (int i = 1; i < 16; i++) m = fmaxf(m, v[i]);
  for (int off = 32; off; off >>= 1) m = fmaxf(m, __shfl_xor(m, off));
  __shared__ float sm1[4], sm2[4];
  if (lane == 0) sm1[wave] = m;
  __syncthreads();
  m = fmaxf(fmaxf(sm1[0], sm1[1]), fmaxf(sm1[2], sm1[3]));
  float s = 0.f;
#pragma unroll
  for (int i = 0; i < 16; i++) { v[i] = __expf(v[i] - m); s += v[i]; }
  for (int off = 32; off; off >>= 1) s += __shfl_xor(s, off);
  if (lane == 0) sm2[wave] = s;
  __syncthreads();
  s = sm2[0] + sm2[1] + sm2[2] + sm2[3];
  const float inv = 1.f / s;
#pragma unroll
  for (int j = 0; j < 8; j++) {
    u32 lo = f2bfu(v[2 * j] * inv);
    u32 hi = f2bfu(v[2 * j + 1] * inv);
    d[j] = lo | (hi << 16);
  }
  ((u32x4*)x)[tid * 2] = *(u32x4*)&d[0];
  ((u32x4*)x)[tid * 2 + 1] = *(u32x4*)&d[4];
}

// ---------------------------------------------------------------- layernorm (rows of 768)
__global__ __launch_bounds__(256) void ln_rows(const float* in, const float* g, const float* b,
                                               float* outf, bf16* outb,
                                               const float* qc, float* qf, bf16* qb16) {
  const long row = blockIdx.x;
  const float* x = in + row * 768;
  const int tid = threadIdx.x;
  const int lane = tid & 63, wave = tid >> 6;
  float v0 = x[tid], v1 = x[tid + 256], v2 = x[tid + 512];
  float s = v0 + v1 + v2;
  float s2 = v0 * v0 + v1 * v1 + v2 * v2;
  for (int off = 32; off; off >>= 1) { s += __shfl_xor(s, off); s2 += __shfl_xor(s2, off); }
  __shared__ float sa[4], sb[4];
  if (lane == 0) { sa[wave] = s; sb[wave] = s2; }
  __syncthreads();
  s = sa[0] + sa[1] + sa[2] + sa[3];
  s2 = sb[0] + sb[1] + sb[2] + sb[3];
  const float mean = s * (1.f / 768.f);
  const float var = s2 * (1.f / 768.f) - mean * mean;
  const float rs = rsqrtf(var + 1e-5f);
  float o0 = (v0 - mean) * rs * g[tid] + b[tid];
  float o1 = (v1 - mean) * rs * g[tid + 256] + b[tid + 256];
  float o2 = (v2 - mean) * rs * g[tid + 512] + b[tid + 512];
  if (outf) { float* of = outf + row * 768; of[tid] = o0; of[tid + 256] = o1; of[tid + 512] = o2; }
  if (outb) { bf16* ob = outb + row * 768; ob[tid] = f2bf(o0); ob[tid + 256] = f2bf(o1); ob[tid + 512] = f2bf(o2); }
  if (qc) {
    const float* qr = qc + (row & 63) * 768;
    float u0 = o0 + qr[tid], u1 = o1 + qr[tid + 256], u2 = o2 + qr[tid + 512];
    float* pf = qf + row * 768;
    pf[tid] = u0; pf[tid + 256] = u1; pf[tid + 512] = u2;
    bf16* pb = qb16 + row * 768;
    pb[tid] = f2bf(u0); pb[tid + 256] = f2bf(u1); pb[tid + 512] = f2bf(u2);
  }
}

// ---------------------------------------------------------------- fused split-K combine + layernorm
// per row (768): s = sum_{c<nch} in[c] + bias (+res); LN(s) -> outputs.
struct CombLnP {
  const float* in; int nch; const float* bias; const float* res;
  const float* g; const float* b;
  float* outf; bf16* outb;
  const float* qc; float* qf; bf16* qb16;
};

__global__ __launch_bounds__(256) void comb_ln(CombLnP p) {
  const long row = blockIdx.x;
  const long base = row * 768;
  const int tid = threadIdx.x;
  const int lane = tid & 63, wave = tid >> 6;
  float v0 = 0.f, v1 = 0.f, v2 = 0.f;
  for (int c = 0; c < p.nch; c++) {
    const float* x = p.in + (long)c * 393216 + base;
    v0 += x[tid]; v1 += x[tid + 256]; v2 += x[tid + 512];
  }
  v0 += p.bias[tid]; v1 += p.bias[tid + 256]; v2 += p.bias[tid + 512];
  if (p.res) {
    const float* r = p.res + base;
    v0 += r[tid]; v1 += r[tid + 256]; v2 += r[tid + 512];
  }
  float s = v0 + v1 + v2;
  float s2 = v0 * v0 + v1 * v1 + v2 * v2;
  for (int off = 32; off; off >>= 1) { s += __shfl_xor(s, off); s2 += __shfl_xor(s2, off); }
  __shared__ float sa[4], sb[4];
  if (lane == 0) { sa[wave] = s; sb[wave] = s2; }
  __syncthreads();
  s = sa[0] + sa[1] + sa[2] + sa[3];
  s2 = sb[0] + sb[1] + sb[2] + sb[3];
  const float mean = s * (1.f / 768.f);
  const float var = s2 * (1.f / 768.f) - mean * mean;
  const float rs = rsqrtf(var + 1e-5f);
  float o0 = (v0 - mean) * rs * p.g[tid] + p.b[tid];
  float o1 = (v1 - mean) * rs * p.g[tid + 256] + p.b[tid + 256];
  float o2 = (v2 - mean) * rs * p.g[tid + 512] + p.b[tid + 512];
  if (p.outf) { float* of = p.outf + base; of[tid] = o0; of[tid + 256] = o1; of[tid + 512] = o2; }
  if (p.outb) { bf16* ob = p.outb + base; ob[tid] = f2bf(o0); ob[tid + 256] = f2bf(o1); ob[tid + 512] = f2bf(o2); }
  if (p.qc) {
    const float* qr = p.qc + (row & 63) * 768;
    float u0 = o0 + qr[tid], u1 = o1 + qr[tid + 256], u2 = o2 + qr[tid + 512];
    float* pf = p.qf + base;
    pf[tid] = u0; pf[tid + 256] = u1; pf[tid + 512] = u2;
    bf16* pb = p.qb16 + base;
    pb[tid] = f2bf(u0); pb[tid + 256] = f2bf(u1); pb[tid + 512] = f2bf(u2);
  }
}

// ---------------------------------------------------------------- combine split-K partials (no LN)
struct CombP { const float* in; int nch; const float* bias; const float* res;
               float* outf; bf16* outb; const float* qc; float* qf; bf16* qb16; };

__global__ __launch_bounds__(256) void combine(CombP p) {
  const long i = (long)blockIdx.x * 256 + threadIdx.x;  // n = 393216
  float s = 0.f;
  for (int c = 0; c < p.nch; c++) s += p.in[(long)c * 393216 + i];
  if (p.bias) s += p.bias[i % 768];
  if (p.res) s += p.res[i];
  if (p.outf) p.outf[i] = s;
  if (p.outb) p.outb[i] = f2bf(s);
  if (p.qc) {
    float v = s + p.qc[i % 49152];
    p.qf[i] = v;
    p.qb16[i] = f2bf(v);
  }
}

// ================================================================ launcher
extern "C" void kernel_launch(void* const* d_in, const int* in_sizes, int n_in,
                              void* d_out, int out_size, void* d_ws, size_t ws_size,
                              hipStream_t stream) {
  (void)in_sizes; (void)n_in; (void)out_size; (void)ws_size;
  const float* tokens   = (const float*)d_in[0];
  const float* selector = (const float*)d_in[1];
  const float* qc  = (const float*)d_in[2];
  const float* qw  = (const float*)d_in[3];
  const float* qb  = (const float*)d_in[4];
  const float* kw  = (const float*)d_in[5];
  const float* kb  = (const float*)d_in[6];
  const float* vw  = (const float*)d_in[7];
  const float* vb  = (const float*)d_in[8];
  const float* hw  = (const float*)d_in[9];
  const float* hb  = (const float*)d_in[10];
  const float* ow  = (const float*)d_in[11];
  const float* ob  = (const float*)d_in[12];
  const float* w1  = (const float*)d_in[13];
  const float* b1  = (const float*)d_in[14];
  const float* w2  = (const float*)d_in[15];
  const float* b2  = (const float*)d_in[16];
  const float* g1  = (const float*)d_in[17];
  const float* be1 = (const float*)d_in[18];
  const float* g2  = (const float*)d_in[19];
  const float* be2 = (const float*)d_in[20];
  float* out = (float*)d_out;

  char* ws = (char*)d_ws;
  size_t off = 0;
  auto alloc = [&](size_t bytes) { char* pp = ws + off; off += (bytes + 255) & ~(size_t)255; return pp; };
  bf16* TOKT  = (bf16*)alloc(50331648);   // tokens^T [B,D,N]
  bf16* TOKB  = (bf16*)alloc(50331648);   // tokens bf16 [B,N,D]
  bf16* KBUF  = (bf16*)alloc(50331648);   // k [B,N,H,HD]
  bf16* VTB   = (bf16*)alloc(50331648);   // v^T [B,768,N]
  bf16* PLOG  = (bf16*)alloc(4194304);    // pooling logits [B,M,N]
  bf16* SELB  = (bf16*)alloc(98304);      // selector bf16 [M,D]
  bf16* QWT   = (bf16*)alloc(4718592);    // [L,H,HD,D]
  bf16* KWT   = (bf16*)alloc(4718592);
  bf16* VWT   = (bf16*)alloc(4718592);
  bf16* HWT   = (bf16*)alloc(393216);     // [L,H,HD,HD]
  bf16* OWT   = (bf16*)alloc(4718592);    // [L,D,D]
  bf16* W1T   = (bf16*)alloc(18874368);   // [L,3072,768]
  bf16* W2T   = (bf16*)alloc(18874368);   // [L,768,3072]
  bf16* QBUF  = (bf16*)alloc(786432);     // q [B,M,H,HD]
  bf16* O2BUF = (bf16*)alloc(786432);     // head-mixed concat [B*M,768]
  float* QF   = (float*)alloc(1572864);   // queries f32
  bf16* QB16  = (bf16*)alloc(786432);     // queries bf16
  float* X1F  = (float*)alloc(1572864);
  bf16* X1B   = (bf16*)alloc(786432);
  bf16* H1    = (bf16*)alloc(3145728);    // gelu(mlp1) [512,3072]
  float* OPART = (float*)alloc(12582912); // split-K partials / flash O-partials
  float* MLB  = (float*)alloc(393216);    // flash (m,l) [8][96][2][64]

  auto tr = [&](const float* in, bf16* o, bf16* oR, int R, int C, long s, long sR, int slabs) {
    TrP t{in, o, oR, R, C, s, s, sR};
    transpose_f2b<<<dim3(C / 64, R / 64, slabs), 256, 0, stream>>>(t);
  };
  tr(tokens, TOKT, TOKB, 4096, 768, 3145728, 3145728, 8);
  cvt_f2b<<<24, 256, 0, stream>>>(selector, SELB, 49152);
  tr(qw, QWT, nullptr, 768, 64, 49152, 0, 48);
  tr(kw, KWT, nullptr, 768, 64, 49152, 0, 48);
  tr(vw, VWT, nullptr, 768, 64, 49152, 0, 48);
  tr(hw, HWT, nullptr, 64, 64, 4096, 0, 48);
  tr(ow, OWT, nullptr, 768, 768, 589824, 0, 4);
  tr(w1, W1T, nullptr, 768, 3072, 2359296, 0, 4);
  tr(w2, W2T, nullptr, 3072, 768, 2359296, 0, 4);

  // ---- pooling
  {
    GemmSmP p{}; p.A = SELB; p.B = TOKB; p.C = PLOG;
    p.sB1 = 3145728; p.sC1 = 262144; p.nb2 = 1;
    p.lda = 768; p.ldb = 768; p.ldc = 4096; p.K = 768;
    p.bias_mode = 0; p.out_mode = 1; p.scale = 1.0f;
    gemm_sm<<<dim3(64, 1, 8), 256, 0, stream>>>(p);
  }
  softmax_rows<<<512, 256, 0, stream>>>(PLOG);
  { // x partials = P · tokens (split-K 8 over N)
    GemmSmP p{}; p.A = PLOG; p.B = TOKT; p.C = OPART;
    p.sA1 = 512; p.sA2 = 262144; p.sB1 = 512; p.sB2 = 3145728;
    p.sC1 = 393216; p.sC2 = 49152; p.nb2 = 8;
    p.lda = 4096; p.ldb = 4096; p.ldc = 768; p.K = 512;
    p.bias_mode = 0; p.out_mode = 0; p.scale = 1.0f;
    gemm_sm<<<dim3(12, 1, 64), 256, 0, stream>>>(p);
  }
  { // x -> queries(l=0) = x + qc[0]
    CombP c{}; c.in = OPART; c.nch = 8; c.qc = qc; c.qf = QF; c.qb16 = QB16;
    combine<<<1536, 256, 0, stream>>>(c);
  }

  for (int l = 0; l < 4; l++) {
    { // q = queries · qw^T + qb  -> [B,M,H,HD] bf16
      GemmSmP p{}; p.A = QB16; p.B = QWT + l * 589824; p.C = QBUF; p.bias = qb + l * 768;
      p.nb2 = 1; p.lda = 768; p.ldb = 768; p.ldc = 768; p.K = 768;
      p.bias_mode = 1; p.out_mode = 1; p.scale = 1.0f;
      gemm_sm<<<dim3(12, 8, 1), 256, 0, stream>>>(p);
    }
    { // fused k,v projection
      GemmKVP p{TOKB, KWT + l * 589824, VWT + l * 589824, KBUF, VTB,
                kb + l * 768, vb + l * 768};
      gemm_kv<<<dim3(6, 256, 1), 256, 0, stream>>>(p);
    }
    { // flash attention partials
      AttnP p{QBUF, KBUF, VTB, OPART, MLB};
      attn_part<<<dim3(96, 8, 1), 256, 0, stream>>>(p);
    }
    { // fused chunk-merge + head-mix
      AttnHMP p{OPART, MLB, HWT + l * 49152, hb + l * 768, O2BUF};
      attn_hm<<<96, 256, 0, stream>>>(p);
    }
    { // o-proj partials (split-K 4): o2 · ow^T
      GemmSmP p{}; p.A = O2BUF; p.B = OWT + l * 589824; p.C = OPART;
      p.sA1 = 192; p.sB1 = 192; p.sC1 = 393216; p.nb2 = 1;
      p.lda = 768; p.ldb = 768; p.ldc = 768; p.K = 192;
      p.bias_mode = 0; p.out_mode = 0; p.scale = 1.0f;
      gemm_sm<<<dim3(12, 8, 4), 256, 0, stream>>>(p);
    }
    { // combine(o-proj)+residual+LN1 -> X1F (f32), X1B (bf16)
      CombLnP c{}; c.in = OPART; c.nch = 4; c.bias = ob + l * 768; c.res = QF;
      c.g = g1 + l * 768; c.b = be1 + l * 768; c.outf = X1F; c.outb = X1B;
      comb_ln<<<512, 256, 0, stream>>>(c);
    }
    { // mlp1 = gelu(x1 · w1^T + b1) bf16
      GemmSmP p{}; p.A = X1B; p.B = W1T + l * 2359296; p.C = H1; p.bias = b1 + l * 3072;
      p.nb2 = 1; p.lda = 768; p.ldb = 768; p.ldc = 3072; p.K = 768;
      p.bias_mode = 1; p.out_mode = 2; p.scale = 1.0f;
      gemm_sm<<<dim3(48, 8, 1), 256, 0, stream>>>(p);
    }
    { // mlp2 partials (split-K 8): h1 · w2^T
      GemmSmP p{}; p.A = H1; p.B = W2T + l * 2359296; p.C = OPART;
      p.sA1 = 384; p.sB1 = 384; p.sC1 = 393216; p.nb2 = 1;
      p.lda = 3072; p.ldb = 3072; p.ldc = 768; p.K = 384;
      p.bias_mode = 0; p.out_mode = 0; p.scale = 1.0f;
      gemm_sm<<<dim3(12, 8, 8), 256, 0, stream>>>(p);
    }
    { // combine(mlp2)+residual+LN2; l<3 -> queries(l+1); l==3 -> final out
      CombLnP c{}; c.in = OPART; c.nch = 8; c.bias = b2 + l * 768; c.res = X1F;
      c.g = g2 + l * 768; c.b = be2 + l * 768;
      c.outf = (l == 3) ? out : nullptr;
      c.qc = (l < 3) ? (qc + (l + 1) * 49152) : nullptr;
      c.qf = QF; c.qb16 = QB16;
      comb_ln<<<512, 256, 0, stream>>>(c);
    }
  }
}

// Round 5
// 1057.387 us; speedup vs baseline: 1.3862x; 1.0162x over previous
//
#include <hip/hip_runtime.h>
#include <hip/hip_bf16.h>

// VisualDecoder: B=8,N=4096,D=768,H=12,M=64,L=4,HD=64. In/out f32; compute bf16
// MFMA (f32 accum). R11: gemm_kv rebuilt as 512-thread / 8-wave blocks (each
// wave owns a 64x64 quadrant of the 128x256 K|V output) -> 16 waves/CU (was 8).
// Symmetric 3-slot counted-vmcnt pipeline (vmcnt(3)); asymmetric-depth scheme
// reverted (vmcnt queue is ordered; extra A depth was never realized).
// Flash attention, T2 swizzles, attn_hm / comb_ln fusions retained.

using bf16 = __hip_bfloat16;
typedef __attribute__((ext_vector_type(8))) __bf16 bf16x8;
typedef __attribute__((ext_vector_type(4))) float f32x4;
typedef unsigned int u32;
typedef __attribute__((ext_vector_type(4))) u32 u32x4;

#define DEVINL __device__ __forceinline__

DEVINL float bf2f(bf16 v) { return __bfloat162float(v); }
DEVINL bf16 f2bf(float v) { return __float2bfloat16(v); }
DEVINL u32 f2bfu(float f) { bf16 h = __float2bfloat16(f); return *(unsigned short*)&h; }
DEVINL float gelu_f(float x) { return 0.5f * x * (1.0f + erff(x * 0.70710678118654752f)); }

// async global->LDS, 16B per lane. LDS dest = wave-uniform base + lane*16 (ours is).
DEVINL void async16(const bf16* g, bf16* l) {
  __builtin_amdgcn_global_load_lds(
      (const __attribute__((address_space(1))) u32*)g,
      (__attribute__((address_space(3))) u32*)l, 16, 0, 0);
}

// XCD-chunked bijective block-id swizzle (m204).
DEVINL u32 xcd_swizzle(u32 id, u32 nwg) {
  u32 q = nwg >> 3, r = nwg & 7;
  u32 xcd = id & 7, pos = id >> 3;
  return xcd * q + (xcd < r ? xcd : r) + pos;
}

// ---------------------------------------------------------------- flat f32 -> bf16
__global__ __launch_bounds__(256) void cvt_f2b(const float* in, bf16* out, long n) {
  const long i = ((long)blockIdx.x * 256 + threadIdx.x) * 8;
  if (i >= n) return;
  float4 a = *(const float4*)(in + i);
  float4 b = *(const float4*)(in + i + 4);
  u32 w[4];
  w[0] = f2bfu(a.x) | (f2bfu(a.y) << 16);
  w[1] = f2bfu(a.z) | (f2bfu(a.w) << 16);
  w[2] = f2bfu(b.x) | (f2bfu(b.y) << 16);
  w[3] = f2bfu(b.z) | (f2bfu(b.w) << 16);
  *(u32x4*)(out + i) = *(u32x4*)w;
}

// ---------------------------------------------------------------- fused K+V projection
// 128x128(A) x [128 K | 128 V] per block, BK=32, 512 threads = 8 waves; wave w:
// stream = w>>2 (K/V), wm=(w&1)*64, wn=((w>>2? w&3 : w&3)>>1)*64 -> 64x64 quad.
// 3-slot symmetric pipeline, 1 async16 per stream per thread -> vmcnt(3).
// LDS 72KB -> 2 blocks/CU = 16 waves/CU. T2 16B-slot read swizzle.
// K written direct; V^T through LDS transpose tile -> coalesced stores.
struct GemmKVP {
  const bf16* A;      // TOKB [32768,768]
  const bf16* Bk;     // KWT layer [768,768]
  const bf16* Bv;     // VWT layer [768,768]
  bf16* Ck;           // KBUF
  bf16* Cv;           // VTB
  const float* biask; // kb[768]
  const float* biasv; // vb[768]
};

__global__ __launch_bounds__(512, 4) void gemm_kv(GemmKVP p) {
  __shared__ __align__(16) bf16 SH[36864];  // 72KB: As[3]|Ks[3]|Vs[3] of 4096
  bf16* As = SH;
  bf16* Ks = SH + 12288;
  bf16* Vs = SH + 24576;
  const int tid = threadIdx.x;
  const int wave = tid >> 6, lane = tid & 63;

  u32 id = blockIdx.x + 6u * blockIdx.y;     // grid (6, 256)
  id = xcd_swizzle(id, 1536);
  const int bn = id % 6;
  const int bm = id / 6;

  const bf16* Ag = p.A + (long)bm * 128 * 768;
  const bf16* Kg = p.Bk + (long)bn * 128 * 768;
  const bf16* Vg = p.Bv + (long)bn * 128 * 768;

  // staging (512 thr = full 128x32 tile per call): LDS slot tid (linear),
  // global row tid>>2, swizzled col chunk (tid&3) ^ ((row>>1)&3).
  const int cq = (((tid & 3) ^ ((tid >> 3) & 3))) * 8;
  const long ro = (long)(tid >> 2) * 768 + cq;
  const bf16* ga = Ag + ro;
  const bf16* gk = Kg + ro;
  const bf16* gv = Vg + ro;

  const int m_in = lane & 15, q = lane >> 4;
  const int wstream = wave >> 2;            // 0 = K, 1 = V
  const int wq = wave & 3;
  const int wm = (wq & 1) * 64, wn = (wq >> 1) * 64;
  const int sw3 = (q ^ ((m_in >> 1) & 3)) << 3;  // read slot offset (elems)
  f32x4 acc[4][4] = {};
  const int nk = 24;  // K=768

  auto stage = [&](int s, int ko) {
    async16(ga + ko, As + s * 4096 + tid * 8);
    async16(gk + ko, Ks + s * 4096 + tid * 8);
    async16(gv + ko, Vs + s * 4096 + tid * 8);
  };
  stage(0, 0);
  stage(1, 32);

  for (int k = 0; k < nk; ++k) {
    // retire tile k (oldest 3 loads); keep tile k+1 in flight (T4)
    if (k + 1 < nk) asm volatile("s_waitcnt vmcnt(3)" ::: "memory");
    else            asm volatile("s_waitcnt vmcnt(0)" ::: "memory");
    __builtin_amdgcn_s_barrier();
    if (k + 2 < nk) stage((k + 2) % 3, (k + 2) * 32);
    const bf16* Ac = As + (k % 3) * 4096;
    const bf16* Bc = (wstream == 0 ? Ks : Vs) + (k % 3) * 4096;
    bf16x8 af[4], bfr[4];
#pragma unroll
    for (int i = 0; i < 4; i++)
      af[i] = *(const bf16x8*)(Ac + (wm + i * 16 + m_in) * 32 + sw3);
#pragma unroll
    for (int j = 0; j < 4; j++)
      bfr[j] = *(const bf16x8*)(Bc + (wn + j * 16 + m_in) * 32 + sw3);
#pragma unroll
    for (int i = 0; i < 4; i++)
#pragma unroll
      for (int j = 0; j < 4; j++)
        acc[i][j] = __builtin_amdgcn_mfma_f32_16x16x32_bf16(af[i], bfr[j], acc[i][j], 0, 0, 0);
  }

  const int bb = (bm * 128) >> 12;
  const int nn0 = (bm * 128) & 4095;
  __syncthreads();  // all waves done with K-loop LDS before SH reuse
  if (wstream == 0) {
    // ---- K: direct stores
    const long row0 = (long)bm * 128 + wm + q * 4;
    const long col0 = (long)bn * 128 + wn + m_in;
#pragma unroll
    for (int i = 0; i < 4; i++)
#pragma unroll
      for (int j = 0; j < 4; j++) {
        long r = row0 + i * 16;
        long c = col0 + j * 16;
        float bk_ = p.biask[c];
#pragma unroll
        for (int t = 0; t < 4; t++)
          p.Ck[(r + t) * 768 + c] = f2bf(acc[i][j][t] + bk_);
      }
  } else {
    // ---- V: transpose into LDS tile VT [128 e][128 n], slots XOR (e&15)
    bf16* VT = SH;
#pragma unroll
    for (int i = 0; i < 4; i++) {
      const int nb = wm + q * 4 + i * 16;  // n_local base (t in 0..3)
      const int sl = nb >> 3;
      const int of = nb & 7;
#pragma unroll
      for (int j = 0; j < 4; j++) {
        const int e = wn + j * 16 + m_in;
        const float bv_ = p.biasv[bn * 128 + e];
        u32 w0 = f2bfu(acc[i][j][0] + bv_) | (f2bfu(acc[i][j][1] + bv_) << 16);
        u32 w1 = f2bfu(acc[i][j][2] + bv_) | (f2bfu(acc[i][j][3] + bv_) << 16);
        uint2 pk; pk.x = w0; pk.y = w1;
        *(uint2*)(VT + e * 128 + ((sl ^ (e & 15)) << 3) + of) = pk;
      }
    }
  }
  __syncthreads();
  bf16* CvB = p.Cv + (long)bb * 3145728;
  const bf16* VT = SH;
#pragma unroll
  for (int k2 = 0; k2 < 4; k2++) {
    int g = tid + k2 * 512;
    int e = g >> 4, sc = g & 15;
    u32x4 vv = *(const u32x4*)(VT + e * 128 + ((sc ^ (e & 15)) << 3));
    *(u32x4*)(CvB + (long)(bn * 128 + e) * 4096 + nn0 + sc * 8) = vv;
  }
}

// ---------------------------------------------------------------- small GEMM
// 64x64 tile, BK=32, 3-slot counted-vmcnt pipeline, 2-level batch, XCD swizzle,
// T2 read-swizzle (pre-swizzled source + XOR'd read slot).
struct GemmSmP {
  const bf16* A; const bf16* B; void* C; const float* bias; const float* res;
  long sA1, sA2, sB1, sB2, sC1, sC2, sBias2;
  int nb2, lda, ldb, ldc, K;
  int bias_mode;  // 0 none, 1 per-col
  int out_mode;   // 0 f32 (+res), 1 bf16, 2 gelu->bf16
  float scale;
};

__global__ __launch_bounds__(256, 4) void gemm_sm(GemmSmP p) {
  __shared__ __align__(16) bf16 As[3][64 * 32];
  __shared__ __align__(16) bf16 Bs[3][64 * 32];
  const int tid = threadIdx.x;
  const int wave = tid >> 6, lane = tid & 63;

  const u32 gx = gridDim.x, gy = gridDim.y;
  u32 id = blockIdx.x + gx * (blockIdx.y + gy * blockIdx.z);
  id = xcd_swizzle(id, gx * gy * gridDim.z);
  const int bn = id % gx;
  const u32 t2 = id / gx;
  const int bm = t2 % gy;
  const int bz = t2 / gy;

  const int z1 = bz / p.nb2, z2 = bz - z1 * p.nb2;
  const bf16* Ag = p.A + p.sA1 * z1 + p.sA2 * z2 + (long)bm * 64 * p.lda;
  const bf16* Bg = p.B + p.sB1 * z1 + p.sB2 * z2 + (long)bn * 64 * p.ldb;

  const int cq = (((tid & 3) ^ ((tid >> 3) & 3))) * 8;
  const bf16* gpa = Ag + ((long)(tid >> 2) * p.lda + cq);
  const bf16* gpb = Bg + ((long)(tid >> 2) * p.ldb + cq);

  const int m_in = lane & 15, q = lane >> 4;
  const int wm = (wave & 1) * 32, wn = (wave >> 1) * 32;
  const int sw3 = (q ^ ((m_in >> 1) & 3)) << 3;
  f32x4 acc[2][2] = {};
  const int nk = p.K >> 5;

  async16(gpa, &As[0][0] + tid * 8);
  async16(gpb, &Bs[0][0] + tid * 8);
  if (nk > 1) {
    async16(gpa + 32, &As[1][0] + tid * 8);
    async16(gpb + 32, &Bs[1][0] + tid * 8);
  }

  int slot = 0;
  for (int k = 0; k < nk; ++k) {
    if (k + 1 < nk) asm volatile("s_waitcnt vmcnt(2)" ::: "memory");
    else            asm volatile("s_waitcnt vmcnt(0)" ::: "memory");
    __builtin_amdgcn_s_barrier();
    if (k + 2 < nk) {
      int ns = slot + 2; if (ns >= 3) ns -= 3;
      const int ko = (k + 2) * 32;
      async16(gpa + ko, &As[ns][0] + tid * 8);
      async16(gpb + ko, &Bs[ns][0] + tid * 8);
    }
    const bf16* Ac = &As[slot][0];
    const bf16* Bc = &Bs[slot][0];
    bf16x8 a0 = *(const bf16x8*)(Ac + (wm + m_in) * 32 + sw3);
    bf16x8 a1 = *(const bf16x8*)(Ac + (wm + 16 + m_in) * 32 + sw3);
    bf16x8 b0 = *(const bf16x8*)(Bc + (wn + m_in) * 32 + sw3);
    bf16x8 b1 = *(const bf16x8*)(Bc + (wn + 16 + m_in) * 32 + sw3);
    acc[0][0] = __builtin_amdgcn_mfma_f32_16x16x32_bf16(a0, b0, acc[0][0], 0, 0, 0);
    acc[0][1] = __builtin_amdgcn_mfma_f32_16x16x32_bf16(a0, b1, acc[0][1], 0, 0, 0);
    acc[1][0] = __builtin_amdgcn_mfma_f32_16x16x32_bf16(a1, b0, acc[1][0], 0, 0, 0);
    acc[1][1] = __builtin_amdgcn_mfma_f32_16x16x32_bf16(a1, b1, acc[1][1], 0, 0, 0);
    slot = (slot + 1 == 3) ? 0 : slot + 1;
  }

  const long row0 = (long)bm * 64 + wm + q * 4;
  const long col0 = (long)bn * 64 + wn + m_in;
  const float* bias = p.bias + p.sBias2 * z2;
#pragma unroll
  for (int i = 0; i < 2; i++)
#pragma unroll
    for (int j = 0; j < 2; j++) {
      long r = row0 + i * 16;
      long cc = col0 + j * 16;
      float badd = (p.bias_mode == 1) ? bias[cc] : 0.f;
#pragma unroll
      for (int t = 0; t < 4; t++) {
        float v = acc[i][j][t] * p.scale + badd;
        long idx = (r + t) * p.ldc + cc;
        if (p.out_mode == 0) {
          float* Cf = (float*)p.C + p.sC1 * z1 + p.sC2 * z2;
          if (p.res) v += p.res[idx];
          Cf[idx] = v;
        } else {
          bf16* Cb = (bf16*)p.C + p.sC1 * z1 + p.sC2 * z2;
          if (p.out_mode == 2) v = gelu_f(v);
          Cb[idx] = f2bf(v);
        }
      }
    }
}

// ---------------------------------------------------------------- flash attention partial
// Block = (z=b*12+h, chunk c of 512 n). 4 waves x 16 q-rows. Online softmax per
// chunk; per-chunk (m,l) + O-partial to global; attn_hm merges 8 chunks.
struct AttnP {
  const bf16* Q;   // QBUF [B*M,768], head at h*64
  const bf16* K;   // KBUF [B*N,768], head at h*64
  const bf16* VT;  // VTB [B][768][4096], rows h*64+e
  float* Opart;    // [8][96][64][64]
  float* ML;       // [8][96][2][64]
};

__global__ __launch_bounds__(256, 3) void attn_part(AttnP p) {
  __shared__ __align__(16) bf16 SH[24576];
  bf16* Qs = SH;             // [64][64] swz (16B slots XOR row&7)
  bf16* Ks = SH + 4096;      // 2 bufs of [64][64]
  bf16* Vs = SH + 12288;     // 2 bufs of [64][64]
  bf16* Ps = SH + 20480;     // [64][64] swz
  const int tid = threadIdx.x;
  const int wave = tid >> 6, lane = tid & 63;
  const int z = blockIdx.x, c = blockIdx.y;
  const int b = z / 12, h = z - b * 12;
  const int n0 = c * 512;

  // staging: slot sl -> row sl>>3, phys col chunk qc = (sl&7) ^ (row&7)
  const int sl0 = tid, sl1 = tid + 256;
  const int r0 = sl0 >> 3, r1 = sl1 >> 3;
  const int q0 = (sl0 & 7) ^ (r0 & 7), q1 = (sl1 & 7) ^ (r1 & 7);

  const bf16* Qg = p.Q + ((long)b * 64) * 768 + h * 64;
  const bf16* Kg = p.K + ((long)b * 4096 + n0) * 768 + h * 64;
  const bf16* Vg = p.VT + (long)b * 3145728 + (long)(h * 64) * 4096 + n0;

  async16(Qg + (long)r0 * 768 + q0 * 8, Qs + sl0 * 8);
  async16(Qg + (long)r1 * 768 + q1 * 8, Qs + sl1 * 8);
  auto stageK = [&](int s) {
    bf16* d = Ks + (s & 1) * 4096;
    async16(Kg + (long)(s * 64 + r0) * 768 + q0 * 8, d + sl0 * 8);
    async16(Kg + (long)(s * 64 + r1) * 768 + q1 * 8, d + sl1 * 8);
  };
  auto stageV = [&](int s) {
    bf16* d = Vs + (s & 1) * 4096;
    async16(Vg + (long)r0 * 4096 + s * 64 + q0 * 8, d + sl0 * 8);
    async16(Vg + (long)r1 * 4096 + s * 64 + q1 * 8, d + sl1 * 8);
  };
  stageK(0); stageV(0); stageK(1); stageV(1);

  const int m_in = lane & 15, q = lane >> 4;
  const int wm = wave * 16;

  asm volatile("s_waitcnt vmcnt(8)" ::: "memory");  // Q landed
  __builtin_amdgcn_s_barrier();

  bf16x8 qa[2];
  {
    const int ra = wm + m_in;
#pragma unroll
    for (int kk = 0; kk < 2; kk++)
      qa[kk] = *(const bf16x8*)(Qs + ra * 64 + ((((kk * 4 + q) ^ (ra & 7))) << 3));
  }

  f32x4 accO[4] = {};
  float m_run[4] = {-1e30f, -1e30f, -1e30f, -1e30f};
  float l_run[4] = {0.f, 0.f, 0.f, 0.f};

  for (int s = 0; s < 8; ++s) {
    if (s < 7) asm volatile("s_waitcnt vmcnt(4)" ::: "memory");
    else       asm volatile("s_waitcnt vmcnt(0)" ::: "memory");
    __builtin_amdgcn_s_barrier();
    const bf16* Kc = Ks + (s & 1) * 4096;
    const bf16* Vc = Vs + (s & 1) * 4096;
    // S = Q . K^T  (rows m = wm+q*4+t, cols n = m_in+16j)
    f32x4 accS[4] = {};
#pragma unroll
    for (int kk = 0; kk < 2; kk++) {
#pragma unroll
      for (int j = 0; j < 4; j++) {
        const int rj = j * 16 + m_in;
        bf16x8 kb = *(const bf16x8*)(Kc + rj * 64 + ((((kk * 4 + q) ^ (rj & 7))) << 3));
        accS[j] = __builtin_amdgcn_mfma_f32_16x16x32_bf16(qa[kk], kb, accS[j], 0, 0, 0);
      }
    }
    // online softmax partial (scale 0.125)
    float pe[4][4], osc[4];
#pragma unroll
    for (int t = 0; t < 4; t++) {
      float mx = fmaxf(fmaxf(accS[0][t], accS[1][t]), fmaxf(accS[2][t], accS[3][t])) * 0.125f;
      mx = fmaxf(mx, __shfl_xor(mx, 1));
      mx = fmaxf(mx, __shfl_xor(mx, 2));
      mx = fmaxf(mx, __shfl_xor(mx, 4));
      mx = fmaxf(mx, __shfl_xor(mx, 8));
      const float mnew = fmaxf(m_run[t], mx);
      const float so = __expf(m_run[t] - mnew);
      float rs = 0.f;
#pragma unroll
      for (int j = 0; j < 4; j++) {
        float e = __expf(accS[j][t] * 0.125f - mnew);
        pe[j][t] = e; rs += e;
      }
      rs += __shfl_xor(rs, 1); rs += __shfl_xor(rs, 2);
      rs += __shfl_xor(rs, 4); rs += __shfl_xor(rs, 8);
      l_run[t] = l_run[t] * so + rs;
      m_run[t] = mnew;
      osc[t] = so;
    }
#pragma unroll
    for (int ef = 0; ef < 4; ef++)
#pragma unroll
      for (int t = 0; t < 4; t++) accO[ef][t] *= osc[t];
    // P -> LDS (wave-private rows), swizzled slots
#pragma unroll
    for (int j = 0; j < 4; j++) {
      const int pc = m_in + 16 * j;
#pragma unroll
      for (int t = 0; t < 4; t++) {
        const int pm = wm + q * 4 + t;
        Ps[pm * 64 + (((pc >> 3) ^ (pm & 7)) << 3) + (pc & 7)] = f2bf(pe[j][t]);
      }
    }
    // O += P . V  (B = V^T rows e)
    const int ra = wm + m_in;
#pragma unroll
    for (int kk = 0; kk < 2; kk++) {
      bf16x8 pa = *(const bf16x8*)(Ps + ra * 64 + ((((kk * 4 + q) ^ (ra & 7))) << 3));
#pragma unroll
      for (int ef = 0; ef < 4; ef++) {
        const int rv = ef * 16 + m_in;
        bf16x8 vb = *(const bf16x8*)(Vc + rv * 64 + ((((kk * 4 + q) ^ (rv & 7))) << 3));
        accO[ef] = __builtin_amdgcn_mfma_f32_16x16x32_bf16(pa, vb, accO[ef], 0, 0, 0);
      }
    }
    __builtin_amdgcn_s_barrier();  // all waves done with K(s)/V(s) buffers
    if (s < 6) { stageK(s + 2); stageV(s + 2); }
  }

  float* Og = p.Opart + ((long)c * 96 + z) * 4096;
#pragma unroll
  for (int ef = 0; ef < 4; ef++)
#pragma unroll
    for (int t = 0; t < 4; t++)
      Og[(wm + q * 4 + t) * 64 + ef * 16 + m_in] = accO[ef][t];
  if (m_in == 0) {
    float* ml = p.ML + ((long)c * 96 + z) * 128;
#pragma unroll
    for (int t = 0; t < 4; t++) {
      ml[wm + q * 4 + t] = m_run[t];
      ml[64 + wm + q * 4 + t] = l_run[t];
    }
  }
}

// ---------------------------------------------------------------- fused chunk-merge + head-mix
struct AttnHMP {
  const float* Opart;  // [8][96][64][64]
  const float* ML;     // [8][96][2][64]
  const bf16* HWT;     // layer base [12][64][64] (rows e2, cols e)
  const float* hb;     // layer base [768]
  bf16* O2;            // [512][768]
};

__global__ __launch_bounds__(256) void attn_hm(AttnHMP p) {
  __shared__ __align__(16) bf16 Os[4096];  // [64 m][64 e], 16B slots XOR (m&7)
  __shared__ __align__(16) bf16 Hs[4096];  // [64 e2][64 e], swizzled
  const int tid = threadIdx.x;
  const int z = blockIdx.x;
  const int b = z / 12, h = z - b * 12;

  // stage H (swizzled like attn staging)
  const int sl0 = tid, sl1 = tid + 256;
  const int r0 = sl0 >> 3, r1 = sl1 >> 3;
  const int q0 = (sl0 & 7) ^ (r0 & 7), q1 = (sl1 & 7) ^ (r1 & 7);
  const bf16* Hg = p.HWT + h * 4096;
  async16(Hg + r0 * 64 + q0 * 8, Hs + sl0 * 8);
  async16(Hg + r1 * 64 + q1 * 8, Hs + sl1 * 8);

  // combine 8 chunk partials: thread owns row m = tid>>2, cols e0..e0+15
  const int m = tid >> 2, e0 = (tid & 3) * 16;
  float mv[8];
  float mx = -1e30f;
#pragma unroll
  for (int c = 0; c < 8; c++) {
    mv[c] = p.ML[((long)c * 96 + z) * 128 + m];
    mx = fmaxf(mx, mv[c]);
  }
  float l = 0.f;
  float o[16] = {};
#pragma unroll
  for (int c = 0; c < 8; c++) {
    const float w = __expf(mv[c] - mx);
    l += w * p.ML[((long)c * 96 + z) * 128 + 64 + m];
    const float* Og = p.Opart + (((long)c * 96 + z) * 64 + m) * 64 + e0;
#pragma unroll
    for (int e = 0; e < 16; e++) o[e] += w * Og[e];
  }
  const float inv = 1.f / l;
#pragma unroll
  for (int half = 0; half < 2; half++) {
    u32 wbuf[4];
#pragma unroll
    for (int j = 0; j < 4; j++)
      wbuf[j] = f2bfu(o[half * 8 + 2 * j] * inv) | (f2bfu(o[half * 8 + 2 * j + 1] * inv) << 16);
    const int sl = (e0 >> 3) + half;
    *(u32x4*)(Os + m * 64 + ((sl ^ (m & 7)) << 3)) = *(u32x4*)wbuf;
  }
  asm volatile("s_waitcnt vmcnt(0)" ::: "memory");
  __syncthreads();

  // GEMM 64x64 K=64
  const int wave = tid >> 6, lane = tid & 63;
  const int m_in = lane & 15, q = lane >> 4;
  const int wm = wave * 16;
  f32x4 acc[4] = {};
#pragma unroll
  for (int kk = 0; kk < 2; kk++) {
    const int ra = wm + m_in;
    bf16x8 a = *(const bf16x8*)(Os + ra * 64 + ((((kk * 4 + q) ^ (ra & 7))) << 3));
#pragma unroll
    for (int j = 0; j < 4; j++) {
      const int rb = j * 16 + m_in;
      bf16x8 bv = *(const bf16x8*)(Hs + rb * 64 + ((((kk * 4 + q) ^ (rb & 7))) << 3));
      acc[j] = __builtin_amdgcn_mfma_f32_16x16x32_bf16(a, bv, acc[j], 0, 0, 0);
    }
  }
  bf16* O2r = p.O2 + ((long)b * 64) * 768 + h * 64;
#pragma unroll
  for (int j = 0; j < 4; j++) {
    const int e2 = j * 16 + m_in;
    const float badd = p.hb[h * 64 + e2];
#pragma unroll
    for (int t = 0; t < 4; t++)
      O2r[(wm + q * 4 + t) * 768 + e2] = f2bf(acc[j][t] + badd);
  }
}

// ---------------------------------------------------------------- transpose (f32 -> bf16)
struct TrP { const float* in; bf16* out; bf16* outR; int R, C; long sIn, sOut, sOutR; };

__global__ __launch_bounds__(256) void transpose_f2b(TrP p) {
  __shared__ __align__(16) bf16 tile[64][80];
  const int tid = threadIdx.x;
  const int ct = blockIdx.x, rt = blockIdx.y, z = blockIdx.z;
  const float* in = p.in + p.sIn * z + ((long)rt * 64) * p.C + (long)ct * 64;
  bf16* out = p.out + p.sOut * z + ((long)ct * 64) * p.R + (long)rt * 64;
  bf16* outR = p.outR ? p.outR + p.sOutR * z + ((long)rt * 64) * p.C + (long)ct * 64 : nullptr;
  const int r = tid >> 3, c8 = (tid & 7) * 8;
#pragma unroll
  for (int h = 0; h < 2; h++) {
    int rr = r + h * 32;
    float4 a = *(const float4*)(in + (long)rr * p.C + c8);
    float4 b = *(const float4*)(in + (long)rr * p.C + c8 + 4);
    u32 w[4];
    w[0] = f2bfu(a.x) | (f2bfu(a.y) << 16);
    w[1] = f2bfu(a.z) | (f2bfu(a.w) << 16);
    w[2] = f2bfu(b.x) | (f2bfu(b.y) << 16);
    w[3] = f2bfu(b.z) | (f2bfu(b.w) << 16);
    *(u32x4*)&tile[rr][c8] = *(u32x4*)w;
    if (outR) *(u32x4*)(outR + (long)rr * p.C + c8) = *(u32x4*)w;
  }
  __syncthreads();
  const int co = tid >> 3, r8 = (tid & 7) * 8;
#pragma unroll
  for (int h = 0; h < 2; h++) {
    int cc = co + h * 32;
    __align__(16) bf16 tmp[8];
#pragma unroll
    for (int j = 0; j < 8; j++) tmp[j] = tile[r8 + j][cc];
    *(u32x4*)(out + (long)cc * p.R + r8) = *(const u32x4*)tmp;
  }
}

// ---------------------------------------------------------------- softmax (rows of 4096, in-place bf16)
__global__ __launch_bounds__(256) void softmax_rows(bf16* X) {
  const long row = blockIdx.x;
  u32* x = (u32*)(X + row * 4096);
  const int tid = threadIdx.x;
  const int lane = tid & 63, wave = tid >> 6;
  u32 d[8];
  *(u32x4*)&d[0] = ((const u32x4*)x)[tid * 2];
  *(u32x4*)&d[4] = ((const u32x4*)x)[tid * 2 + 1];
  float v[16];
#pragma unroll
  for (int j = 0; j < 8; j++) {
    v[2 * j] = __uint_as_float(d[j] << 16);
    v[2 * j + 1] = __uint_as_float(d[j] & 0xffff0000u);
  }
  float m = v[0];
#pragma unroll
  for (int i = 1; i < 16; i++) m = fmaxf(m, v[i]);
  for (int off = 32; off; off >>= 1) m = fmaxf(m, __shfl_xor(m, off));
  __shared__ float sm1[4], sm2[4];
  if (lane == 0) sm1[wave] = m;
  __syncthreads();
  m = fmaxf(fmaxf(sm1[0], sm1[1]), fmaxf(sm1[2], sm1[3]));
  float s = 0.f;
#pragma unroll
  for (int i = 0; i < 16; i++) { v[i] = __expf(v[i] - m); s += v[i]; }
  for (int off = 32; off; off >>= 1) s += __shfl_xor(s, off);
  if (lane == 0) sm2[wave] = s;
  __syncthreads();
  s = sm2[0] + sm2[1] + sm2[2] + sm2[3];
  const float inv = 1.f / s;
#pragma unroll
  for (int j = 0; j < 8; j++) {
    u32 lo = f2bfu(v[2 * j] * inv);
    u32 hi = f2bfu(v[2 * j + 1] * inv);
    d[j] = lo | (hi << 16);
  }
  ((u32x4*)x)[tid * 2] = *(u32x4*)&d[0];
  ((u32x4*)x)[tid * 2 + 1] = *(u32x4*)&d[4];
}

// ---------------------------------------------------------------- fused split-K combine + layernorm
struct CombLnP {
  const float* in; int nch; const float* bias; const float* res;
  const float* g; const float* b;
  float* outf; bf16* outb;
  const float* qc; float* qf; bf16* qb16;
};

__global__ __launch_bounds__(256) void comb_ln(CombLnP p) {
  const long row = blockIdx.x;
  const long base = row * 768;
  const int tid = threadIdx.x;
  const int lane = tid & 63, wave = tid >> 6;
  float v0 = 0.f, v1 = 0.f, v2 = 0.f;
  for (int c = 0; c < p.nch; c++) {
    const float* x = p.in + (long)c * 393216 + base;
    v0 += x[tid]; v1 += x[tid + 256]; v2 += x[tid + 512];
  }
  v0 += p.bias[tid]; v1 += p.bias[tid + 256]; v2 += p.bias[tid + 512];
  if (p.res) {
    const float* r = p.res + base;
    v0 += r[tid]; v1 += r[tid + 256]; v2 += r[tid + 512];
  }
  float s = v0 + v1 + v2;
  float s2 = v0 * v0 + v1 * v1 + v2 * v2;
  for (int off = 32; off; off >>= 1) { s += __shfl_xor(s, off); s2 += __shfl_xor(s2, off); }
  __shared__ float sa[4], sb[4];
  if (lane == 0) { sa[wave] = s; sb[wave] = s2; }
  __syncthreads();
  s = sa[0] + sa[1] + sa[2] + sa[3];
  s2 = sb[0] + sb[1] + sb[2] + sb[3];
  const float mean = s * (1.f / 768.f);
  const float var = s2 * (1.f / 768.f) - mean * mean;
  const float rs = rsqrtf(var + 1e-5f);
  float o0 = (v0 - mean) * rs * p.g[tid] + p.b[tid];
  float o1 = (v1 - mean) * rs * p.g[tid + 256] + p.b[tid + 256];
  float o2 = (v2 - mean) * rs * p.g[tid + 512] + p.b[tid + 512];
  if (p.outf) { float* of = p.outf + base; of[tid] = o0; of[tid + 256] = o1; of[tid + 512] = o2; }
  if (p.outb) { bf16* ob = p.outb + base; ob[tid] = f2bf(o0); ob[tid + 256] = f2bf(o1); ob[tid + 512] = f2bf(o2); }
  if (p.qc) {
    const float* qr = p.qc + (row & 63) * 768;
    float u0 = o0 + qr[tid], u1 = o1 + qr[tid + 256], u2 = o2 + qr[tid + 512];
    float* pf = p.qf + base;
    pf[tid] = u0; pf[tid + 256] = u1; pf[tid + 512] = u2;
    bf16* pb = p.qb16 + base;
    pb[tid] = f2bf(u0); pb[tid + 256] = f2bf(u1); pb[tid + 512] = f2bf(u2);
  }
}

// ---------------------------------------------------------------- combine split-K partials (no LN)
struct CombP { const float* in; int nch; const float* bias; const float* res;
               float* outf; bf16* outb; const float* qc; float* qf; bf16* qb16; };

__global__ __launch_bounds__(256) void combine(CombP p) {
  const long i = (long)blockIdx.x * 256 + threadIdx.x;  // n = 393216
  float s = 0.f;
  for (int c = 0; c < p.nch; c++) s += p.in[(long)c * 393216 + i];
  if (p.bias) s += p.bias[i % 768];
  if (p.res) s += p.res[i];
  if (p.outf) p.outf[i] = s;
  if (p.outb) p.outb[i] = f2bf(s);
  if (p.qc) {
    float v = s + p.qc[i % 49152];
    p.qf[i] = v;
    p.qb16[i] = f2bf(v);
  }
}

// ================================================================ launcher
extern "C" void kernel_launch(void* const* d_in, const int* in_sizes, int n_in,
                              void* d_out, int out_size, void* d_ws, size_t ws_size,
                              hipStream_t stream) {
  (void)in_sizes; (void)n_in; (void)out_size; (void)ws_size;
  const float* tokens   = (const float*)d_in[0];
  const float* selector = (const float*)d_in[1];
  const float* qc  = (const float*)d_in[2];
  const float* qw  = (const float*)d_in[3];
  const float* qb  = (const float*)d_in[4];
  const float* kw  = (const float*)d_in[5];
  const float* kb  = (const float*)d_in[6];
  const float* vw  = (const float*)d_in[7];
  const float* vb  = (const float*)d_in[8];
  const float* hw  = (const float*)d_in[9];
  const float* hb  = (const float*)d_in[10];
  const float* ow  = (const float*)d_in[11];
  const float* ob  = (const float*)d_in[12];
  const float* w1  = (const float*)d_in[13];
  const float* b1  = (const float*)d_in[14];
  const float* w2  = (const float*)d_in[15];
  const float* b2  = (const float*)d_in[16];
  const float* g1  = (const float*)d_in[17];
  const float* be1 = (const float*)d_in[18];
  const float* g2  = (const float*)d_in[19];
  const float* be2 = (const float*)d_in[20];
  float* out = (float*)d_out;

  char* ws = (char*)d_ws;
  size_t off = 0;
  auto alloc = [&](size_t bytes) { char* pp = ws + off; off += (bytes + 255) & ~(size_t)255; return pp; };
  bf16* TOKT  = (bf16*)alloc(50331648);   // tokens^T [B,D,N]
  bf16* TOKB  = (bf16*)alloc(50331648);   // tokens bf16 [B,N,D]
  bf16* KBUF  = (bf16*)alloc(50331648);   // k [B,N,H,HD]
  bf16* VTB   = (bf16*)alloc(50331648);   // v^T [B,768,N]
  bf16* PLOG  = (bf16*)alloc(4194304);    // pooling logits [B,M,N]
  bf16* SELB  = (bf16*)alloc(98304);      // selector bf16 [M,D]
  bf16* QWT   = (bf16*)alloc(4718592);    // [L,H,HD,D]
  bf16* KWT   = (bf16*)alloc(4718592);
  bf16* VWT   = (bf16*)alloc(4718592);
  bf16* HWT   = (bf16*)alloc(393216);     // [L,H,HD,HD]
  bf16* OWT   = (bf16*)alloc(4718592);    // [L,D,D]
  bf16* W1T   = (bf16*)alloc(18874368);   // [L,3072,768]
  bf16* W2T   = (bf16*)alloc(18874368);   // [L,768,3072]
  bf16* QBUF  = (bf16*)alloc(786432);     // q [B,M,H,HD]
  bf16* O2BUF = (bf16*)alloc(786432);     // head-mixed concat [B*M,768]
  float* QF   = (float*)alloc(1572864);   // queries f32
  bf16* QB16  = (bf16*)alloc(786432);     // queries bf16
  float* X1F  = (float*)alloc(1572864);
  bf16* X1B   = (bf16*)alloc(786432);
  bf16* H1    = (bf16*)alloc(3145728);    // gelu(mlp1) [512,3072]
  float* OPART = (float*)alloc(12582912); // split-K partials / flash O-partials
  float* MLB  = (float*)alloc(393216);    // flash (m,l) [8][96][2][64]

  auto tr = [&](const float* in, bf16* o, bf16* oR, int R, int C, long s, long sR, int slabs) {
    TrP t{in, o, oR, R, C, s, s, sR};
    transpose_f2b<<<dim3(C / 64, R / 64, slabs), 256, 0, stream>>>(t);
  };
  tr(tokens, TOKT, TOKB, 4096, 768, 3145728, 3145728, 8);
  cvt_f2b<<<24, 256, 0, stream>>>(selector, SELB, 49152);
  tr(qw, QWT, nullptr, 768, 64, 49152, 0, 48);
  tr(kw, KWT, nullptr, 768, 64, 49152, 0, 48);
  tr(vw, VWT, nullptr, 768, 64, 49152, 0, 48);
  tr(hw, HWT, nullptr, 64, 64, 4096, 0, 48);
  tr(ow, OWT, nullptr, 768, 768, 589824, 0, 4);
  tr(w1, W1T, nullptr, 768, 3072, 2359296, 0, 4);
  tr(w2, W2T, nullptr, 3072, 768, 2359296, 0, 4);

  // ---- pooling
  {
    GemmSmP p{}; p.A = SELB; p.B = TOKB; p.C = PLOG;
    p.sB1 = 3145728; p.sC1 = 262144; p.nb2 = 1;
    p.lda = 768; p.ldb = 768; p.ldc = 4096; p.K = 768;
    p.bias_mode = 0; p.out_mode = 1; p.scale = 1.0f;
    gemm_sm<<<dim3(64, 1, 8), 256, 0, stream>>>(p);
  }
  softmax_rows<<<512, 256, 0, stream>>>(PLOG);
  { // x partials = P · tokens (split-K 8 over N)
    GemmSmP p{}; p.A = PLOG; p.B = TOKT; p.C = OPART;
    p.sA1 = 512; p.sA2 = 262144; p.sB1 = 512; p.sB2 = 3145728;
    p.sC1 = 393216; p.sC2 = 49152; p.nb2 = 8;
    p.lda = 4096; p.ldb = 4096; p.ldc = 768; p.K = 512;
    p.bias_mode = 0; p.out_mode = 0; p.scale = 1.0f;
    gemm_sm<<<dim3(12, 1, 64), 256, 0, stream>>>(p);
  }
  { // x -> queries(l=0) = x + qc[0]
    CombP c{}; c.in = OPART; c.nch = 8; c.qc = qc; c.qf = QF; c.qb16 = QB16;
    combine<<<1536, 256, 0, stream>>>(c);
  }

  for (int l = 0; l < 4; l++) {
    { // q = queries · qw^T + qb  -> [B,M,H,HD] bf16
      GemmSmP p{}; p.A = QB16; p.B = QWT + l * 589824; p.C = QBUF; p.bias = qb + l * 768;
      p.nb2 = 1; p.lda = 768; p.ldb = 768; p.ldc = 768; p.K = 768;
      p.bias_mode = 1; p.out_mode = 1; p.scale = 1.0f;
      gemm_sm<<<dim3(12, 8, 1), 256, 0, stream>>>(p);
    }
    { // fused k,v projection (512-thread 8-wave blocks)
      GemmKVP p{TOKB, KWT + l * 589824, VWT + l * 589824, KBUF, VTB,
                kb + l * 768, vb + l * 768};
      gemm_kv<<<dim3(6, 256, 1), 512, 0, stream>>>(p);
    }
    { // flash attention partials
      AttnP p{QBUF, KBUF, VTB, OPART, MLB};
      attn_part<<<dim3(96, 8, 1), 256, 0, stream>>>(p);
    }
    { // fused chunk-merge + head-mix
      AttnHMP p{OPART, MLB, HWT + l * 49152, hb + l * 768, O2BUF};
      attn_hm<<<96, 256, 0, stream>>>(p);
    }
    { // o-proj partials (split-K 4): o2 · ow^T
      GemmSmP p{}; p.A = O2BUF; p.B = OWT + l * 589824; p.C = OPART;
      p.sA1 = 192; p.sB1 = 192; p.sC1 = 393216; p.nb2 = 1;
      p.lda = 768; p.ldb = 768; p.ldc = 768; p.K = 192;
      p.bias_mode = 0; p.out_mode = 0; p.scale = 1.0f;
      gemm_sm<<<dim3(12, 8, 4), 256, 0, stream>>>(p);
    }
    { // combine(o-proj)+residual+LN1 -> X1F (f32), X1B (bf16)
      CombLnP c{}; c.in = OPART; c.nch = 4; c.bias = ob + l * 768; c.res = QF;
      c.g = g1 + l * 768; c.b = be1 + l * 768; c.outf = X1F; c.outb = X1B;
      comb_ln<<<512, 256, 0, stream>>>(c);
    }
    { // mlp1 = gelu(x1 · w1^T + b1) bf16
      GemmSmP p{}; p.A = X1B; p.B = W1T + l * 2359296; p.C = H1; p.bias = b1 + l * 3072;
      p.nb2 = 1; p.lda = 768; p.ldb = 768; p.ldc = 3072; p.K = 768;
      p.bias_mode = 1; p.out_mode = 2; p.scale = 1.0f;
      gemm_sm<<<dim3(48, 8, 1), 256, 0, stream>>>(p);
    }
    { // mlp2 partials (split-K 8): h1 · w2^T
      GemmSmP p{}; p.A = H1; p.B = W2T + l * 2359296; p.C = OPART;
      p.sA1 = 384; p.sB1 = 384; p.sC1 = 393216; p.nb2 = 1;
      p.lda = 3072; p.ldb = 3072; p.ldc = 768; p.K = 384;
      p.bias_mode = 0; p.out_mode = 0; p.scale = 1.0f;
      gemm_sm<<<dim3(12, 8, 8), 256, 0, stream>>>(p);
    }
    { // combine(mlp2)+residual+LN2; l<3 -> queries(l+1); l==3 -> final out
      CombLnP c{}; c.in = OPART; c.nch = 8; c.bias = b2 + l * 768; c.res = X1F;
      c.g = g2 + l * 768; c.b = be2 + l * 768;
      c.outf = (l == 3) ? out : nullptr;
      c.qc = (l < 3) ? (qc + (l + 1) * 49152) : nullptr;
      c.qf = QF; c.qb16 = QB16;
      comb_ln<<<512, 256, 0, stream>>>(c);
    }
  }
}

// Round 6
// 1033.650 us; speedup vs baseline: 1.4180x; 1.0230x over previous
//
#include <hip/hip_runtime.h>
#include <hip/hip_bf16.h>

// VisualDecoder: B=8,N=4096,D=768,H=12,M=64,L=4,HD=64. In/out f32; compute bf16
// MFMA (f32 accum). R12: (1) q-projection merged into gemm_kv as extra blocks
// (id>=1536: A=QB16, B=QWT, K-style store to QBUF) -- removes a serial 96-block
// dispatch per layer; (2) s_setprio(1) around attn_part MFMA clusters (T5,
// independent-block regime per m191); (3) qw/kw/vw transposes in one launch.
// gemm_kv schedule itself unchanged from R11 (512-thr, 3-slot vmcnt(3)).

using bf16 = __hip_bfloat16;
typedef __attribute__((ext_vector_type(8))) __bf16 bf16x8;
typedef __attribute__((ext_vector_type(4))) float f32x4;
typedef unsigned int u32;
typedef __attribute__((ext_vector_type(4))) u32 u32x4;

#define DEVINL __device__ __forceinline__

DEVINL float bf2f(bf16 v) { return __bfloat162float(v); }
DEVINL bf16 f2bf(float v) { return __float2bfloat16(v); }
DEVINL u32 f2bfu(float f) { bf16 h = __float2bfloat16(f); return *(unsigned short*)&h; }
DEVINL float gelu_f(float x) { return 0.5f * x * (1.0f + erff(x * 0.70710678118654752f)); }

// async global->LDS, 16B per lane. LDS dest = wave-uniform base + lane*16 (ours is).
DEVINL void async16(const bf16* g, bf16* l) {
  __builtin_amdgcn_global_load_lds(
      (const __attribute__((address_space(1))) u32*)g,
      (__attribute__((address_space(3))) u32*)l, 16, 0, 0);
}

// XCD-chunked bijective block-id swizzle (m204).
DEVINL u32 xcd_swizzle(u32 id, u32 nwg) {
  u32 q = nwg >> 3, r = nwg & 7;
  u32 xcd = id & 7, pos = id >> 3;
  return xcd * q + (xcd < r ? xcd : r) + pos;
}

// ---------------------------------------------------------------- flat f32 -> bf16
__global__ __launch_bounds__(256) void cvt_f2b(const float* in, bf16* out, long n) {
  const long i = ((long)blockIdx.x * 256 + threadIdx.x) * 8;
  if (i >= n) return;
  float4 a = *(const float4*)(in + i);
  float4 b = *(const float4*)(in + i + 4);
  u32 w[4];
  w[0] = f2bfu(a.x) | (f2bfu(a.y) << 16);
  w[1] = f2bfu(a.z) | (f2bfu(a.w) << 16);
  w[2] = f2bfu(b.x) | (f2bfu(b.y) << 16);
  w[3] = f2bfu(b.z) | (f2bfu(b.w) << 16);
  *(u32x4*)(out + i) = *(u32x4*)w;
}

// ---------------------------------------------------------------- fused K+V (+Q) projection
// Blocks 0..1535: 128x128(A=tokens) x [128 K | 128 V]; blocks 1536..1559:
// 128x128(A=queries) x 128 QW (K-stream waves store; V-waves compute+discard).
// 512 threads = 8 waves; 3-slot symmetric pipeline, vmcnt(3). LDS 72KB ->
// 2 blocks/CU. T2 16B-slot read swizzle. K/Q written direct; V^T through LDS
// transpose tile -> coalesced stores.
struct GemmKVP {
  const bf16* A;      // TOKB [32768,768]
  const bf16* Bk;     // KWT layer [768,768]
  const bf16* Bv;     // VWT layer [768,768]
  bf16* Ck;           // KBUF
  bf16* Cv;           // VTB
  const float* biask; // kb[768]
  const float* biasv; // vb[768]
  const bf16* Aq;     // QB16 [512,768]
  const bf16* Bq;     // QWT layer [768,768]
  bf16* Cq;           // QBUF [512,768]
  const float* biasq; // qb[768]
};

__global__ __launch_bounds__(512, 4) void gemm_kv(GemmKVP p) {
  __shared__ __align__(16) bf16 SH[36864];  // 72KB: As[3]|Ks[3]|Vs[3] of 4096
  bf16* As = SH;
  bf16* Ks = SH + 12288;
  bf16* Vs = SH + 24576;
  const int tid = threadIdx.x;
  const int wave = tid >> 6, lane = tid & 63;

  u32 id = blockIdx.x;                       // grid 1560
  id = xcd_swizzle(id, 1560);
  const bool qblk = id >= 1536;
  const u32 rid = qblk ? id - 1536 : id;
  const int bn = rid % 6;
  const int bm = rid / 6;                    // kv: 0..255, q: 0..3

  const bf16* Ag = (qblk ? p.Aq : p.A) + (long)bm * 128 * 768;
  const bf16* Kg = (qblk ? p.Bq : p.Bk) + (long)bn * 128 * 768;
  const bf16* Vg = (qblk ? p.Bq : p.Bv) + (long)bn * 128 * 768;

  // staging (512 thr = full 128x32 tile per call): LDS slot tid (linear),
  // global row tid>>2, swizzled col chunk (tid&3) ^ ((tid>>3)&3).
  const int cq = (((tid & 3) ^ ((tid >> 3) & 3))) * 8;
  const long ro = (long)(tid >> 2) * 768 + cq;
  const bf16* ga = Ag + ro;
  const bf16* gk = Kg + ro;
  const bf16* gv = Vg + ro;

  const int m_in = lane & 15, q = lane >> 4;
  const int wstream = wave >> 2;            // 0 = K(/Q), 1 = V
  const int wq = wave & 3;
  const int wm = (wq & 1) * 64, wn = (wq >> 1) * 64;
  const int sw3 = (q ^ ((m_in >> 1) & 3)) << 3;  // read slot offset (elems)
  f32x4 acc[4][4] = {};
  const int nk = 24;  // K=768

  auto stage = [&](int s, int ko) {
    async16(ga + ko, As + s * 4096 + tid * 8);
    async16(gk + ko, Ks + s * 4096 + tid * 8);
    async16(gv + ko, Vs + s * 4096 + tid * 8);
  };
  stage(0, 0);
  stage(1, 32);

  for (int k = 0; k < nk; ++k) {
    // retire tile k (oldest 3 loads); keep tile k+1 in flight (T4)
    if (k + 1 < nk) asm volatile("s_waitcnt vmcnt(3)" ::: "memory");
    else            asm volatile("s_waitcnt vmcnt(0)" ::: "memory");
    __builtin_amdgcn_s_barrier();
    if (k + 2 < nk) stage((k + 2) % 3, (k + 2) * 32);
    const bf16* Ac = As + (k % 3) * 4096;
    const bf16* Bc = (wstream == 0 ? Ks : Vs) + (k % 3) * 4096;
    bf16x8 af[4], bfr[4];
#pragma unroll
    for (int i = 0; i < 4; i++)
      af[i] = *(const bf16x8*)(Ac + (wm + i * 16 + m_in) * 32 + sw3);
#pragma unroll
    for (int j = 0; j < 4; j++)
      bfr[j] = *(const bf16x8*)(Bc + (wn + j * 16 + m_in) * 32 + sw3);
#pragma unroll
    for (int i = 0; i < 4; i++)
#pragma unroll
      for (int j = 0; j < 4; j++)
        acc[i][j] = __builtin_amdgcn_mfma_f32_16x16x32_bf16(af[i], bfr[j], acc[i][j], 0, 0, 0);
  }

  if (qblk) {
    // q-projection epilogue: K-stream waves store to Cq; V-waves discard.
    if (wstream == 0) {
      const long row0 = (long)bm * 128 + wm + q * 4;
      const long col0 = (long)bn * 128 + wn + m_in;
#pragma unroll
      for (int i = 0; i < 4; i++)
#pragma unroll
        for (int j = 0; j < 4; j++) {
          long r = row0 + i * 16;
          long c = col0 + j * 16;
          float bq_ = p.biasq[c];
#pragma unroll
          for (int t = 0; t < 4; t++)
            p.Cq[(r + t) * 768 + c] = f2bf(acc[i][j][t] + bq_);
        }
    }
    return;  // block-uniform: no further barriers executed
  }

  const int bb = (bm * 128) >> 12;
  const int nn0 = (bm * 128) & 4095;
  __syncthreads();  // all waves done with K-loop LDS before SH reuse
  if (wstream == 0) {
    // ---- K: direct stores
    const long row0 = (long)bm * 128 + wm + q * 4;
    const long col0 = (long)bn * 128 + wn + m_in;
#pragma unroll
    for (int i = 0; i < 4; i++)
#pragma unroll
      for (int j = 0; j < 4; j++) {
        long r = row0 + i * 16;
        long c = col0 + j * 16;
        float bk_ = p.biask[c];
#pragma unroll
        for (int t = 0; t < 4; t++)
          p.Ck[(r + t) * 768 + c] = f2bf(acc[i][j][t] + bk_);
      }
  } else {
    // ---- V: transpose into LDS tile VT [128 e][128 n], slots XOR (e&15)
    bf16* VT = SH;
#pragma unroll
    for (int i = 0; i < 4; i++) {
      const int nb = wm + q * 4 + i * 16;  // n_local base (t in 0..3)
      const int sl = nb >> 3;
      const int of = nb & 7;
#pragma unroll
      for (int j = 0; j < 4; j++) {
        const int e = wn + j * 16 + m_in;
        const float bv_ = p.biasv[bn * 128 + e];
        u32 w0 = f2bfu(acc[i][j][0] + bv_) | (f2bfu(acc[i][j][1] + bv_) << 16);
        u32 w1 = f2bfu(acc[i][j][2] + bv_) | (f2bfu(acc[i][j][3] + bv_) << 16);
        uint2 pk; pk.x = w0; pk.y = w1;
        *(uint2*)(VT + e * 128 + ((sl ^ (e & 15)) << 3) + of) = pk;
      }
    }
  }
  __syncthreads();
  bf16* CvB = p.Cv + (long)bb * 3145728;
  const bf16* VT = SH;
#pragma unroll
  for (int k2 = 0; k2 < 4; k2++) {
    int g = tid + k2 * 512;
    int e = g >> 4, sc = g & 15;
    u32x4 vv = *(const u32x4*)(VT + e * 128 + ((sc ^ (e & 15)) << 3));
    *(u32x4*)(CvB + (long)(bn * 128 + e) * 4096 + nn0 + sc * 8) = vv;
  }
}

// ---------------------------------------------------------------- small GEMM
// 64x64 tile, BK=32, 3-slot counted-vmcnt pipeline, 2-level batch, XCD swizzle,
// T2 read-swizzle (pre-swizzled source + XOR'd read slot).
struct GemmSmP {
  const bf16* A; const bf16* B; void* C; const float* bias; const float* res;
  long sA1, sA2, sB1, sB2, sC1, sC2, sBias2;
  int nb2, lda, ldb, ldc, K;
  int bias_mode;  // 0 none, 1 per-col
  int out_mode;   // 0 f32 (+res), 1 bf16, 2 gelu->bf16
  float scale;
};

__global__ __launch_bounds__(256, 4) void gemm_sm(GemmSmP p) {
  __shared__ __align__(16) bf16 As[3][64 * 32];
  __shared__ __align__(16) bf16 Bs[3][64 * 32];
  const int tid = threadIdx.x;
  const int wave = tid >> 6, lane = tid & 63;

  const u32 gx = gridDim.x, gy = gridDim.y;
  u32 id = blockIdx.x + gx * (blockIdx.y + gy * blockIdx.z);
  id = xcd_swizzle(id, gx * gy * gridDim.z);
  const int bn = id % gx;
  const u32 t2 = id / gx;
  const int bm = t2 % gy;
  const int bz = t2 / gy;

  const int z1 = bz / p.nb2, z2 = bz - z1 * p.nb2;
  const bf16* Ag = p.A + p.sA1 * z1 + p.sA2 * z2 + (long)bm * 64 * p.lda;
  const bf16* Bg = p.B + p.sB1 * z1 + p.sB2 * z2 + (long)bn * 64 * p.ldb;

  const int cq = (((tid & 3) ^ ((tid >> 3) & 3))) * 8;
  const bf16* gpa = Ag + ((long)(tid >> 2) * p.lda + cq);
  const bf16* gpb = Bg + ((long)(tid >> 2) * p.ldb + cq);

  const int m_in = lane & 15, q = lane >> 4;
  const int wm = (wave & 1) * 32, wn = (wave >> 1) * 32;
  const int sw3 = (q ^ ((m_in >> 1) & 3)) << 3;
  f32x4 acc[2][2] = {};
  const int nk = p.K >> 5;

  async16(gpa, &As[0][0] + tid * 8);
  async16(gpb, &Bs[0][0] + tid * 8);
  if (nk > 1) {
    async16(gpa + 32, &As[1][0] + tid * 8);
    async16(gpb + 32, &Bs[1][0] + tid * 8);
  }

  int slot = 0;
  for (int k = 0; k < nk; ++k) {
    if (k + 1 < nk) asm volatile("s_waitcnt vmcnt(2)" ::: "memory");
    else            asm volatile("s_waitcnt vmcnt(0)" ::: "memory");
    __builtin_amdgcn_s_barrier();
    if (k + 2 < nk) {
      int ns = slot + 2; if (ns >= 3) ns -= 3;
      const int ko = (k + 2) * 32;
      async16(gpa + ko, &As[ns][0] + tid * 8);
      async16(gpb + ko, &Bs[ns][0] + tid * 8);
    }
    const bf16* Ac = &As[slot][0];
    const bf16* Bc = &Bs[slot][0];
    bf16x8 a0 = *(const bf16x8*)(Ac + (wm + m_in) * 32 + sw3);
    bf16x8 a1 = *(const bf16x8*)(Ac + (wm + 16 + m_in) * 32 + sw3);
    bf16x8 b0 = *(const bf16x8*)(Bc + (wn + m_in) * 32 + sw3);
    bf16x8 b1 = *(const bf16x8*)(Bc + (wn + 16 + m_in) * 32 + sw3);
    acc[0][0] = __builtin_amdgcn_mfma_f32_16x16x32_bf16(a0, b0, acc[0][0], 0, 0, 0);
    acc[0][1] = __builtin_amdgcn_mfma_f32_16x16x32_bf16(a0, b1, acc[0][1], 0, 0, 0);
    acc[1][0] = __builtin_amdgcn_mfma_f32_16x16x32_bf16(a1, b0, acc[1][0], 0, 0, 0);
    acc[1][1] = __builtin_amdgcn_mfma_f32_16x16x32_bf16(a1, b1, acc[1][1], 0, 0, 0);
    slot = (slot + 1 == 3) ? 0 : slot + 1;
  }

  const long row0 = (long)bm * 64 + wm + q * 4;
  const long col0 = (long)bn * 64 + wn + m_in;
  const float* bias = p.bias + p.sBias2 * z2;
#pragma unroll
  for (int i = 0; i < 2; i++)
#pragma unroll
    for (int j = 0; j < 2; j++) {
      long r = row0 + i * 16;
      long cc = col0 + j * 16;
      float badd = (p.bias_mode == 1) ? bias[cc] : 0.f;
#pragma unroll
      for (int t = 0; t < 4; t++) {
        float v = acc[i][j][t] * p.scale + badd;
        long idx = (r + t) * p.ldc + cc;
        if (p.out_mode == 0) {
          float* Cf = (float*)p.C + p.sC1 * z1 + p.sC2 * z2;
          if (p.res) v += p.res[idx];
          Cf[idx] = v;
        } else {
          bf16* Cb = (bf16*)p.C + p.sC1 * z1 + p.sC2 * z2;
          if (p.out_mode == 2) v = gelu_f(v);
          Cb[idx] = f2bf(v);
        }
      }
    }
}

// ---------------------------------------------------------------- flash attention partial
// Block = (z=b*12+h, chunk c of 512 n). 4 waves x 16 q-rows. Online softmax per
// chunk; per-chunk (m,l) + O-partial to global; attn_hm merges 8 chunks.
// T5: setprio(1) around MFMA clusters (independent-block regime, m191).
struct AttnP {
  const bf16* Q;   // QBUF [B*M,768], head at h*64
  const bf16* K;   // KBUF [B*N,768], head at h*64
  const bf16* VT;  // VTB [B][768][4096], rows h*64+e
  float* Opart;    // [8][96][64][64]
  float* ML;       // [8][96][2][64]
};

__global__ __launch_bounds__(256, 3) void attn_part(AttnP p) {
  __shared__ __align__(16) bf16 SH[24576];
  bf16* Qs = SH;             // [64][64] swz (16B slots XOR row&7)
  bf16* Ks = SH + 4096;      // 2 bufs of [64][64]
  bf16* Vs = SH + 12288;     // 2 bufs of [64][64]
  bf16* Ps = SH + 20480;     // [64][64] swz
  const int tid = threadIdx.x;
  const int wave = tid >> 6, lane = tid & 63;
  const int z = blockIdx.x, c = blockIdx.y;
  const int b = z / 12, h = z - b * 12;
  const int n0 = c * 512;

  // staging: slot sl -> row sl>>3, phys col chunk qc = (sl&7) ^ (row&7)
  const int sl0 = tid, sl1 = tid + 256;
  const int r0 = sl0 >> 3, r1 = sl1 >> 3;
  const int q0 = (sl0 & 7) ^ (r0 & 7), q1 = (sl1 & 7) ^ (r1 & 7);

  const bf16* Qg = p.Q + ((long)b * 64) * 768 + h * 64;
  const bf16* Kg = p.K + ((long)b * 4096 + n0) * 768 + h * 64;
  const bf16* Vg = p.VT + (long)b * 3145728 + (long)(h * 64) * 4096 + n0;

  async16(Qg + (long)r0 * 768 + q0 * 8, Qs + sl0 * 8);
  async16(Qg + (long)r1 * 768 + q1 * 8, Qs + sl1 * 8);
  auto stageK = [&](int s) {
    bf16* d = Ks + (s & 1) * 4096;
    async16(Kg + (long)(s * 64 + r0) * 768 + q0 * 8, d + sl0 * 8);
    async16(Kg + (long)(s * 64 + r1) * 768 + q1 * 8, d + sl1 * 8);
  };
  auto stageV = [&](int s) {
    bf16* d = Vs + (s & 1) * 4096;
    async16(Vg + (long)r0 * 4096 + s * 64 + q0 * 8, d + sl0 * 8);
    async16(Vg + (long)r1 * 4096 + s * 64 + q1 * 8, d + sl1 * 8);
  };
  stageK(0); stageV(0); stageK(1); stageV(1);

  const int m_in = lane & 15, q = lane >> 4;
  const int wm = wave * 16;

  asm volatile("s_waitcnt vmcnt(8)" ::: "memory");  // Q landed
  __builtin_amdgcn_s_barrier();

  bf16x8 qa[2];
  {
    const int ra = wm + m_in;
#pragma unroll
    for (int kk = 0; kk < 2; kk++)
      qa[kk] = *(const bf16x8*)(Qs + ra * 64 + ((((kk * 4 + q) ^ (ra & 7))) << 3));
  }

  f32x4 accO[4] = {};
  float m_run[4] = {-1e30f, -1e30f, -1e30f, -1e30f};
  float l_run[4] = {0.f, 0.f, 0.f, 0.f};

  for (int s = 0; s < 8; ++s) {
    if (s < 7) asm volatile("s_waitcnt vmcnt(4)" ::: "memory");
    else       asm volatile("s_waitcnt vmcnt(0)" ::: "memory");
    __builtin_amdgcn_s_barrier();
    const bf16* Kc = Ks + (s & 1) * 4096;
    const bf16* Vc = Vs + (s & 1) * 4096;
    // S = Q . K^T  (rows m = wm+q*4+t, cols n = m_in+16j)
    f32x4 accS[4] = {};
    __builtin_amdgcn_s_setprio(1);
#pragma unroll
    for (int kk = 0; kk < 2; kk++) {
#pragma unroll
      for (int j = 0; j < 4; j++) {
        const int rj = j * 16 + m_in;
        bf16x8 kb = *(const bf16x8*)(Kc + rj * 64 + ((((kk * 4 + q) ^ (rj & 7))) << 3));
        accS[j] = __builtin_amdgcn_mfma_f32_16x16x32_bf16(qa[kk], kb, accS[j], 0, 0, 0);
      }
    }
    __builtin_amdgcn_s_setprio(0);
    // online softmax partial (scale 0.125)
    float pe[4][4], osc[4];
#pragma unroll
    for (int t = 0; t < 4; t++) {
      float mx = fmaxf(fmaxf(accS[0][t], accS[1][t]), fmaxf(accS[2][t], accS[3][t])) * 0.125f;
      mx = fmaxf(mx, __shfl_xor(mx, 1));
      mx = fmaxf(mx, __shfl_xor(mx, 2));
      mx = fmaxf(mx, __shfl_xor(mx, 4));
      mx = fmaxf(mx, __shfl_xor(mx, 8));
      const float mnew = fmaxf(m_run[t], mx);
      const float so = __expf(m_run[t] - mnew);
      float rs = 0.f;
#pragma unroll
      for (int j = 0; j < 4; j++) {
        float e = __expf(accS[j][t] * 0.125f - mnew);
        pe[j][t] = e; rs += e;
      }
      rs += __shfl_xor(rs, 1); rs += __shfl_xor(rs, 2);
      rs += __shfl_xor(rs, 4); rs += __shfl_xor(rs, 8);
      l_run[t] = l_run[t] * so + rs;
      m_run[t] = mnew;
      osc[t] = so;
    }
#pragma unroll
    for (int ef = 0; ef < 4; ef++)
#pragma unroll
      for (int t = 0; t < 4; t++) accO[ef][t] *= osc[t];
    // P -> LDS (wave-private rows), swizzled slots
#pragma unroll
    for (int j = 0; j < 4; j++) {
      const int pc = m_in + 16 * j;
#pragma unroll
      for (int t = 0; t < 4; t++) {
        const int pm = wm + q * 4 + t;
        Ps[pm * 64 + (((pc >> 3) ^ (pm & 7)) << 3) + (pc & 7)] = f2bf(pe[j][t]);
      }
    }
    // O += P . V  (B = V^T rows e)
    const int ra = wm + m_in;
    __builtin_amdgcn_s_setprio(1);
#pragma unroll
    for (int kk = 0; kk < 2; kk++) {
      bf16x8 pa = *(const bf16x8*)(Ps + ra * 64 + ((((kk * 4 + q) ^ (ra & 7))) << 3));
#pragma unroll
      for (int ef = 0; ef < 4; ef++) {
        const int rv = ef * 16 + m_in;
        bf16x8 vb = *(const bf16x8*)(Vc + rv * 64 + ((((kk * 4 + q) ^ (rv & 7))) << 3));
        accO[ef] = __builtin_amdgcn_mfma_f32_16x16x32_bf16(pa, vb, accO[ef], 0, 0, 0);
      }
    }
    __builtin_amdgcn_s_setprio(0);
    __builtin_amdgcn_s_barrier();  // all waves done with K(s)/V(s) buffers
    if (s < 6) { stageK(s + 2); stageV(s + 2); }
  }

  float* Og = p.Opart + ((long)c * 96 + z) * 4096;
#pragma unroll
  for (int ef = 0; ef < 4; ef++)
#pragma unroll
    for (int t = 0; t < 4; t++)
      Og[(wm + q * 4 + t) * 64 + ef * 16 + m_in] = accO[ef][t];
  if (m_in == 0) {
    float* ml = p.ML + ((long)c * 96 + z) * 128;
#pragma unroll
    for (int t = 0; t < 4; t++) {
      ml[wm + q * 4 + t] = m_run[t];
      ml[64 + wm + q * 4 + t] = l_run[t];
    }
  }
}

// ---------------------------------------------------------------- fused chunk-merge + head-mix
struct AttnHMP {
  const float* Opart;  // [8][96][64][64]
  const float* ML;     // [8][96][2][64]
  const bf16* HWT;     // layer base [12][64][64] (rows e2, cols e)
  const float* hb;     // layer base [768]
  bf16* O2;            // [512][768]
};

__global__ __launch_bounds__(256) void attn_hm(AttnHMP p) {
  __shared__ __align__(16) bf16 Os[4096];  // [64 m][64 e], 16B slots XOR (m&7)
  __shared__ __align__(16) bf16 Hs[4096];  // [64 e2][64 e], swizzled
  const int tid = threadIdx.x;
  const int z = blockIdx.x;
  const int b = z / 12, h = z - b * 12;

  // stage H (swizzled like attn staging)
  const int sl0 = tid, sl1 = tid + 256;
  const int r0 = sl0 >> 3, r1 = sl1 >> 3;
  const int q0 = (sl0 & 7) ^ (r0 & 7), q1 = (sl1 & 7) ^ (r1 & 7);
  const bf16* Hg = p.HWT + h * 4096;
  async16(Hg + r0 * 64 + q0 * 8, Hs + sl0 * 8);
  async16(Hg + r1 * 64 + q1 * 8, Hs + sl1 * 8);

  // combine 8 chunk partials: thread owns row m = tid>>2, cols e0..e0+15
  const int m = tid >> 2, e0 = (tid & 3) * 16;
  float mv[8];
  float mx = -1e30f;
#pragma unroll
  for (int c = 0; c < 8; c++) {
    mv[c] = p.ML[((long)c * 96 + z) * 128 + m];
    mx = fmaxf(mx, mv[c]);
  }
  float l = 0.f;
  float o[16] = {};
#pragma unroll
  for (int c = 0; c < 8; c++) {
    const float w = __expf(mv[c] - mx);
    l += w * p.ML[((long)c * 96 + z) * 128 + 64 + m];
    const float* Og = p.Opart + (((long)c * 96 + z) * 64 + m) * 64 + e0;
#pragma unroll
    for (int e = 0; e < 16; e++) o[e] += w * Og[e];
  }
  const float inv = 1.f / l;
#pragma unroll
  for (int half = 0; half < 2; half++) {
    u32 wbuf[4];
#pragma unroll
    for (int j = 0; j < 4; j++)
      wbuf[j] = f2bfu(o[half * 8 + 2 * j] * inv) | (f2bfu(o[half * 8 + 2 * j + 1] * inv) << 16);
    const int sl = (e0 >> 3) + half;
    *(u32x4*)(Os + m * 64 + ((sl ^ (m & 7)) << 3)) = *(u32x4*)wbuf;
  }
  asm volatile("s_waitcnt vmcnt(0)" ::: "memory");
  __syncthreads();

  // GEMM 64x64 K=64
  const int wave = tid >> 6, lane = tid & 63;
  const int m_in = lane & 15, q = lane >> 4;
  const int wm = wave * 16;
  f32x4 acc[4] = {};
#pragma unroll
  for (int kk = 0; kk < 2; kk++) {
    const int ra = wm + m_in;
    bf16x8 a = *(const bf16x8*)(Os + ra * 64 + ((((kk * 4 + q) ^ (ra & 7))) << 3));
#pragma unroll
    for (int j = 0; j < 4; j++) {
      const int rb = j * 16 + m_in;
      bf16x8 bv = *(const bf16x8*)(Hs + rb * 64 + ((((kk * 4 + q) ^ (rb & 7))) << 3));
      acc[j] = __builtin_amdgcn_mfma_f32_16x16x32_bf16(a, bv, acc[j], 0, 0, 0);
    }
  }
  bf16* O2r = p.O2 + ((long)b * 64) * 768 + h * 64;
#pragma unroll
  for (int j = 0; j < 4; j++) {
    const int e2 = j * 16 + m_in;
    const float badd = p.hb[h * 64 + e2];
#pragma unroll
    for (int t = 0; t < 4; t++)
      O2r[(wm + q * 4 + t) * 768 + e2] = f2bf(acc[j][t] + badd);
  }
}

// ---------------------------------------------------------------- transpose (f32 -> bf16)
// Optional 3-source mode: slabs grouped in 48s pick in/in2/in3 (outputs are
// contiguous, so out offset = sOut * z works across groups).
struct TrP { const float* in; bf16* out; bf16* outR; int R, C; long sIn, sOut, sOutR;
             const float* in2; const float* in3; };

__global__ __launch_bounds__(256) void transpose_f2b(TrP p) {
  __shared__ __align__(16) bf16 tile[64][80];
  const int tid = threadIdx.x;
  const int ct = blockIdx.x, rt = blockIdx.y, z = blockIdx.z;
  const float* src = p.in;
  int zz = z;
  if (p.in2) {
    const int g = z / 48;
    zz = z - g * 48;
    if (g == 1) src = p.in2;
    else if (g == 2) src = p.in3;
  }
  const float* in = src + p.sIn * zz + ((long)rt * 64) * p.C + (long)ct * 64;
  bf16* out = p.out + p.sOut * z + ((long)ct * 64) * p.R + (long)rt * 64;
  bf16* outR = p.outR ? p.outR + p.sOutR * z + ((long)rt * 64) * p.C + (long)ct * 64 : nullptr;
  const int r = tid >> 3, c8 = (tid & 7) * 8;
#pragma unroll
  for (int h = 0; h < 2; h++) {
    int rr = r + h * 32;
    float4 a = *(const float4*)(in + (long)rr * p.C + c8);
    float4 b = *(const float4*)(in + (long)rr * p.C + c8 + 4);
    u32 w[4];
    w[0] = f2bfu(a.x) | (f2bfu(a.y) << 16);
    w[1] = f2bfu(a.z) | (f2bfu(a.w) << 16);
    w[2] = f2bfu(b.x) | (f2bfu(b.y) << 16);
    w[3] = f2bfu(b.z) | (f2bfu(b.w) << 16);
    *(u32x4*)&tile[rr][c8] = *(u32x4*)w;
    if (outR) *(u32x4*)(outR + (long)rr * p.C + c8) = *(u32x4*)w;
  }
  __syncthreads();
  const int co = tid >> 3, r8 = (tid & 7) * 8;
#pragma unroll
  for (int h = 0; h < 2; h++) {
    int cc = co + h * 32;
    __align__(16) bf16 tmp[8];
#pragma unroll
    for (int j = 0; j < 8; j++) tmp[j] = tile[r8 + j][cc];
    *(u32x4*)(out + (long)cc * p.R + r8) = *(const u32x4*)tmp;
  }
}

// ---------------------------------------------------------------- softmax (rows of 4096, in-place bf16)
__global__ __launch_bounds__(256) void softmax_rows(bf16* X) {
  const long row = blockIdx.x;
  u32* x = (u32*)(X + row * 4096);
  const int tid = threadIdx.x;
  const int lane = tid & 63, wave = tid >> 6;
  u32 d[8];
  *(u32x4*)&d[0] = ((const u32x4*)x)[tid * 2];
  *(u32x4*)&d[4] = ((const u32x4*)x)[tid * 2 + 1];
  float v[16];
#pragma unroll
  for (int j = 0; j < 8; j++) {
    v[2 * j] = __uint_as_float(d[j] << 16);
    v[2 * j + 1] = __uint_as_float(d[j] & 0xffff0000u);
  }
  float m = v[0];
#pragma unroll
  for (int i = 1; i < 16; i++) m = fmaxf(m, v[i]);
  for (int off = 32; off; off >>= 1) m = fmaxf(m, __shfl_xor(m, off));
  __shared__ float sm1[4], sm2[4];
  if (lane == 0) sm1[wave] = m;
  __syncthreads();
  m = fmaxf(fmaxf(sm1[0], sm1[1]), fmaxf(sm1[2], sm1[3]));
  float s = 0.f;
#pragma unroll
  for (int i = 0; i < 16; i++) { v[i] = __expf(v[i] - m); s += v[i]; }
  for (int off = 32; off; off >>= 1) s += __shfl_xor(s, off);
  if (lane == 0) sm2[wave] = s;
  __syncthreads();
  s = sm2[0] + sm2[1] + sm2[2] + sm2[3];
  const float inv = 1.f / s;
#pragma unroll
  for (int j = 0; j < 8; j++) {
    u32 lo = f2bfu(v[2 * j] * inv);
    u32 hi = f2bfu(v[2 * j + 1] * inv);
    d[j] = lo | (hi << 16);
  }
  ((u32x4*)x)[tid * 2] = *(u32x4*)&d[0];
  ((u32x4*)x)[tid * 2 + 1] = *(u32x4*)&d[4];
}

// ---------------------------------------------------------------- fused split-K combine + layernorm
struct CombLnP {
  const float* in; int nch; const float* bias; const float* res;
  const float* g; const float* b;
  float* outf; bf16* outb;
  const float* qc; float* qf; bf16* qb16;
};

__global__ __launch_bounds__(256) void comb_ln(CombLnP p) {
  const long row = blockIdx.x;
  const long base = row * 768;
  const int tid = threadIdx.x;
  const int lane = tid & 63, wave = tid >> 6;
  float v0 = 0.f, v1 = 0.f, v2 = 0.f;
  for (int c = 0; c < p.nch; c++) {
    const float* x = p.in + (long)c * 393216 + base;
    v0 += x[tid]; v1 += x[tid + 256]; v2 += x[tid + 512];
  }
  v0 += p.bias[tid]; v1 += p.bias[tid + 256]; v2 += p.bias[tid + 512];
  if (p.res) {
    const float* r = p.res + base;
    v0 += r[tid]; v1 += r[tid + 256]; v2 += r[tid + 512];
  }
  float s = v0 + v1 + v2;
  float s2 = v0 * v0 + v1 * v1 + v2 * v2;
  for (int off = 32; off; off >>= 1) { s += __shfl_xor(s, off); s2 += __shfl_xor(s2, off); }
  __shared__ float sa[4], sb[4];
  if (lane == 0) { sa[wave] = s; sb[wave] = s2; }
  __syncthreads();
  s = sa[0] + sa[1] + sa[2] + sa[3];
  s2 = sb[0] + sb[1] + sb[2] + sb[3];
  const float mean = s * (1.f / 768.f);
  const float var = s2 * (1.f / 768.f) - mean * mean;
  const float rs = rsqrtf(var + 1e-5f);
  float o0 = (v0 - mean) * rs * p.g[tid] + p.b[tid];
  float o1 = (v1 - mean) * rs * p.g[tid + 256] + p.b[tid + 256];
  float o2 = (v2 - mean) * rs * p.g[tid + 512] + p.b[tid + 512];
  if (p.outf) { float* of = p.outf + base; of[tid] = o0; of[tid + 256] = o1; of[tid + 512] = o2; }
  if (p.outb) { bf16* ob = p.outb + base; ob[tid] = f2bf(o0); ob[tid + 256] = f2bf(o1); ob[tid + 512] = f2bf(o2); }
  if (p.qc) {
    const float* qr = p.qc + (row & 63) * 768;
    float u0 = o0 + qr[tid], u1 = o1 + qr[tid + 256], u2 = o2 + qr[tid + 512];
    float* pf = p.qf + base;
    pf[tid] = u0; pf[tid + 256] = u1; pf[tid + 512] = u2;
    bf16* pb = p.qb16 + base;
    pb[tid] = f2bf(u0); pb[tid + 256] = f2bf(u1); pb[tid + 512] = f2bf(u2);
  }
}

// ---------------------------------------------------------------- combine split-K partials (no LN)
struct CombP { const float* in; int nch; const float* bias; const float* res;
               float* outf; bf16* outb; const float* qc; float* qf; bf16* qb16; };

__global__ __launch_bounds__(256) void combine(CombP p) {
  const long i = (long)blockIdx.x * 256 + threadIdx.x;  // n = 393216
  float s = 0.f;
  for (int c = 0; c < p.nch; c++) s += p.in[(long)c * 393216 + i];
  if (p.bias) s += p.bias[i % 768];
  if (p.res) s += p.res[i];
  if (p.outf) p.outf[i] = s;
  if (p.outb) p.outb[i] = f2bf(s);
  if (p.qc) {
    float v = s + p.qc[i % 49152];
    p.qf[i] = v;
    p.qb16[i] = f2bf(v);
  }
}

// ================================================================ launcher
extern "C" void kernel_launch(void* const* d_in, const int* in_sizes, int n_in,
                              void* d_out, int out_size, void* d_ws, size_t ws_size,
                              hipStream_t stream) {
  (void)in_sizes; (void)n_in; (void)out_size; (void)ws_size;
  const float* tokens   = (const float*)d_in[0];
  const float* selector = (const float*)d_in[1];
  const float* qc  = (const float*)d_in[2];
  const float* qw  = (const float*)d_in[3];
  const float* qb  = (const float*)d_in[4];
  const float* kw  = (const float*)d_in[5];
  const float* kb  = (const float*)d_in[6];
  const float* vw  = (const float*)d_in[7];
  const float* vb  = (const float*)d_in[8];
  const float* hw  = (const float*)d_in[9];
  const float* hb  = (const float*)d_in[10];
  const float* ow  = (const float*)d_in[11];
  const float* ob  = (const float*)d_in[12];
  const float* w1  = (const float*)d_in[13];
  const float* b1  = (const float*)d_in[14];
  const float* w2  = (const float*)d_in[15];
  const float* b2  = (const float*)d_in[16];
  const float* g1  = (const float*)d_in[17];
  const float* be1 = (const float*)d_in[18];
  const float* g2  = (const float*)d_in[19];
  const float* be2 = (const float*)d_in[20];
  float* out = (float*)d_out;

  char* ws = (char*)d_ws;
  size_t off = 0;
  auto alloc = [&](size_t bytes) { char* pp = ws + off; off += (bytes + 255) & ~(size_t)255; return pp; };
  bf16* TOKT  = (bf16*)alloc(50331648);   // tokens^T [B,D,N]
  bf16* TOKB  = (bf16*)alloc(50331648);   // tokens bf16 [B,N,D]
  bf16* KBUF  = (bf16*)alloc(50331648);   // k [B,N,H,HD]
  bf16* VTB   = (bf16*)alloc(50331648);   // v^T [B,768,N]
  bf16* PLOG  = (bf16*)alloc(4194304);    // pooling logits [B,M,N]
  bf16* SELB  = (bf16*)alloc(98304);      // selector bf16 [M,D]
  bf16* QWT   = (bf16*)alloc(4718592);    // [L,H,HD,D]  (QWT/KWT/VWT contiguous!)
  bf16* KWT   = (bf16*)alloc(4718592);
  bf16* VWT   = (bf16*)alloc(4718592);
  bf16* HWT   = (bf16*)alloc(393216);     // [L,H,HD,HD]
  bf16* OWT   = (bf16*)alloc(4718592);    // [L,D,D]
  bf16* W1T   = (bf16*)alloc(18874368);   // [L,3072,768]
  bf16* W2T   = (bf16*)alloc(18874368);   // [L,768,3072]
  bf16* QBUF  = (bf16*)alloc(786432);     // q [B,M,H,HD]
  bf16* O2BUF = (bf16*)alloc(786432);     // head-mixed concat [B*M,768]
  float* QF   = (float*)alloc(1572864);   // queries f32
  bf16* QB16  = (bf16*)alloc(786432);     // queries bf16
  float* X1F  = (float*)alloc(1572864);
  bf16* X1B   = (bf16*)alloc(786432);
  bf16* H1    = (bf16*)alloc(3145728);    // gelu(mlp1) [512,3072]
  float* OPART = (float*)alloc(12582912); // split-K partials / flash O-partials
  float* MLB  = (float*)alloc(393216);    // flash (m,l) [8][96][2][64]
  (void)KWT; (void)VWT;  // addressed via QWT contiguity for the merged transpose

  auto tr = [&](const float* in, bf16* o, bf16* oR, int R, int C, long s, long sR, int slabs) {
    TrP t{in, o, oR, R, C, s, s, sR, nullptr, nullptr};
    transpose_f2b<<<dim3(C / 64, R / 64, slabs), 256, 0, stream>>>(t);
  };
  tr(tokens, TOKT, TOKB, 4096, 768, 3145728, 3145728, 8);
  cvt_f2b<<<24, 256, 0, stream>>>(selector, SELB, 49152);
  { // qw | kw | vw in one launch (outputs contiguous: QWT,KWT,VWT)
    TrP t{qw, QWT, nullptr, 768, 64, 49152, 49152, 0, kw, vw};
    transpose_f2b<<<dim3(1, 12, 144), 256, 0, stream>>>(t);
  }
  tr(hw, HWT, nullptr, 64, 64, 4096, 0, 48);
  tr(ow, OWT, nullptr, 768, 768, 589824, 0, 4);
  tr(w1, W1T, nullptr, 768, 3072, 2359296, 0, 4);
  tr(w2, W2T, nullptr, 3072, 768, 2359296, 0, 4);

  // ---- pooling
  {
    GemmSmP p{}; p.A = SELB; p.B = TOKB; p.C = PLOG;
    p.sB1 = 3145728; p.sC1 = 262144; p.nb2 = 1;
    p.lda = 768; p.ldb = 768; p.ldc = 4096; p.K = 768;
    p.bias_mode = 0; p.out_mode = 1; p.scale = 1.0f;
    gemm_sm<<<dim3(64, 1, 8), 256, 0, stream>>>(p);
  }
  softmax_rows<<<512, 256, 0, stream>>>(PLOG);
  { // x partials = P · tokens (split-K 8 over N)
    GemmSmP p{}; p.A = PLOG; p.B = TOKT; p.C = OPART;
    p.sA1 = 512; p.sA2 = 262144; p.sB1 = 512; p.sB2 = 3145728;
    p.sC1 = 393216; p.sC2 = 49152; p.nb2 = 8;
    p.lda = 4096; p.ldb = 4096; p.ldc = 768; p.K = 512;
    p.bias_mode = 0; p.out_mode = 0; p.scale = 1.0f;
    gemm_sm<<<dim3(12, 1, 64), 256, 0, stream>>>(p);
  }
  { // x -> queries(l=0) = x + qc[0]
    CombP c{}; c.in = OPART; c.nch = 8; c.qc = qc; c.qf = QF; c.qb16 = QB16;
    combine<<<1536, 256, 0, stream>>>(c);
  }

  for (int l = 0; l < 4; l++) {
    { // fused k,v,q projection (512-thread 8-wave blocks; 1536 kv + 24 q)
      GemmKVP p{TOKB, QWT + 2359296 + l * 589824, QWT + 2 * 2359296 + l * 589824,
                KBUF, VTB, kb + l * 768, vb + l * 768,
                QB16, QWT + l * 589824, QBUF, qb + l * 768};
      gemm_kv<<<1560, 512, 0, stream>>>(p);
    }
    { // flash attention partials
      AttnP p{QBUF, KBUF, VTB, OPART, MLB};
      attn_part<<<dim3(96, 8, 1), 256, 0, stream>>>(p);
    }
    { // fused chunk-merge + head-mix
      AttnHMP p{OPART, MLB, HWT + l * 49152, hb + l * 768, O2BUF};
      attn_hm<<<96, 256, 0, stream>>>(p);
    }
    { // o-proj partials (split-K 4): o2 · ow^T
      GemmSmP p{}; p.A = O2BUF; p.B = OWT + l * 589824; p.C = OPART;
      p.sA1 = 192; p.sB1 = 192; p.sC1 = 393216; p.nb2 = 1;
      p.lda = 768; p.ldb = 768; p.ldc = 768; p.K = 192;
      p.bias_mode = 0; p.out_mode = 0; p.scale = 1.0f;
      gemm_sm<<<dim3(12, 8, 4), 256, 0, stream>>>(p);
    }
    { // combine(o-proj)+residual+LN1 -> X1F (f32), X1B (bf16)
      CombLnP c{}; c.in = OPART; c.nch = 4; c.bias = ob + l * 768; c.res = QF;
      c.g = g1 + l * 768; c.b = be1 + l * 768; c.outf = X1F; c.outb = X1B;
      comb_ln<<<512, 256, 0, stream>>>(c);
    }
    { // mlp1 = gelu(x1 · w1^T + b1) bf16
      GemmSmP p{}; p.A = X1B; p.B = W1T + l * 2359296; p.C = H1; p.bias = b1 + l * 3072;
      p.nb2 = 1; p.lda = 768; p.ldb = 768; p.ldc = 3072; p.K = 768;
      p.bias_mode = 1; p.out_mode = 2; p.scale = 1.0f;
      gemm_sm<<<dim3(48, 8, 1), 256, 0, stream>>>(p);
    }
    { // mlp2 partials (split-K 8): h1 · w2^T
      GemmSmP p{}; p.A = H1; p.B = W2T + l * 2359296; p.C = OPART;
      p.sA1 = 384; p.sB1 = 384; p.sC1 = 393216; p.nb2 = 1;
      p.lda = 3072; p.ldb = 3072; p.ldc = 768; p.K = 384;
      p.bias_mode = 0; p.out_mode = 0; p.scale = 1.0f;
      gemm_sm<<<dim3(12, 8, 8), 256, 0, stream>>>(p);
    }
    { // combine(mlp2)+residual+LN2; l<3 -> queries(l+1); l==3 -> final out
      CombLnP c{}; c.in = OPART; c.nch = 8; c.bias = b2 + l * 768; c.res = X1F;
      c.g = g2 + l * 768; c.b = be2 + l * 768;
      c.outf = (l == 3) ? out : nullptr;
      c.qc = (l < 3) ? (qc + (l + 1) * 49152) : nullptr;
      c.qf = QF; c.qb16 = QB16;
      comb_ln<<<512, 256, 0, stream>>>(c);
    }
  }
}